// Round 10
// baseline (134.521 us; speedup 1.0000x reference)
//
#include <hip/hip_runtime.h>
#include <hip/hip_bf16.h>
#include <math.h>

#define SEQ 2048
#define DM 768
#define NH 12
#define HD 64
#define NB 2
#define NT (NB*SEQ)      // 4096 tokens
#define E3 (3*DM)        // 2304

using short4v = __attribute__((ext_vector_type(4))) short;
using short8v = __attribute__((ext_vector_type(8))) short;
using floatx4 = __attribute__((ext_vector_type(4))) float;
using int4v   = __attribute__((ext_vector_type(4))) int;

#if __has_builtin(__builtin_amdgcn_exp2f)
#define EXPFN(x) __builtin_amdgcn_exp2f(x)
#define QSCALE 0.1803368801111244f   /* 0.125 * log2(e) : scores in log2 domain */
#else
#define EXPFN(x) __expf(x)
#define QSCALE 0.125f
#endif

static __device__ __forceinline__ short bfb(float f) {
  union { __hip_bfloat16 h; short s; } u;
  u.h = __float2bfloat16(f);
  return u.s;
}

// async global->LDS, 16 bytes per lane. lds must be wave-uniform.
static __device__ __forceinline__ void gload_lds16(const __hip_bfloat16* g, __hip_bfloat16* lds) {
  __builtin_amdgcn_global_load_lds(
      (const __attribute__((address_space(1))) unsigned int*)g,
      (__attribute__((address_space(3))) unsigned int*)lds, 16, 0, 0);
}

// LDS granule swizzle (16B granules, 8 per 128B row).
static __device__ __forceinline__ int swzg(int row) {
  return (((row >> 3) & 3) + 2 * (row & 3)) & 7;
}

// ---------------- fp32 -> bf16 convert (vectorized x4) ----------------
__global__ void cvt_bf16(const float* __restrict__ in, __hip_bfloat16* __restrict__ out, int n4) {
  int i = blockIdx.x * blockDim.x + threadIdx.x;
  if (i >= n4) return;
  floatx4 v = ((const floatx4*)in)[i];
  short4v o;
  o[0] = bfb(v[0]); o[1] = bfb(v[1]); o[2] = bfb(v[2]); o[3] = bfb(v[3]);
  ((short4v*)out)[i] = o;
}

// ---------------- RoPE table: (cos,sin)[pos][j] packed float2 ----------------
__global__ void rope_tab(float2* __restrict__ rcs) {
  int idx = blockIdx.x * blockDim.x + threadIdx.x;
  if (idx >= SEQ * 32) return;
  int pos = idx >> 5, j = idx & 31;
  float freq = __expf(-(float)j * (logf(10000.0f) / 32.0f));
  float ang = (float)pos * freq;
  rcs[idx] = make_float2(cosf(ang), sinf(ang));
}

// ---------------- QKV GEMM (m97 structure), C[e][t], RoPE epilogue ----------------
__global__ __launch_bounds__(256) void qkv_gemm_rope(
    const __hip_bfloat16* __restrict__ Wq,
    const __hip_bfloat16* __restrict__ Xb,
    const int* __restrict__ tpos,
    const float2* __restrict__ rcs,
    __hip_bfloat16* __restrict__ Qb, __hip_bfloat16* __restrict__ Kb,
    __hip_bfloat16* __restrict__ Vt)
{
  __shared__ __align__(16) __hip_bfloat16 As[128 * 32];
  __shared__ __align__(16) __hip_bfloat16 Bs[128 * 32];
  const int tid = threadIdx.x;
  const int lane = tid & 63, w = tid >> 6;
  const int c = lane & 15, g = lane >> 4;
  const int wr = w >> 1, wc = w & 1;
  const int bid = blockIdx.x;
  const int xcd = bid & 7, i_ = bid >> 3;
  const int nb = xcd * 4 + (i_ & 3), mb = i_ >> 2;
  const int m0 = mb * 128, n0 = nb * 128;
  const int row0 = tid >> 2, colg0 = (tid & 3) * 8;
  const int row1 = 64 + row0;
  const __hip_bfloat16* A0 = Wq + (size_t)(m0 + row0) * DM + colg0;
  const __hip_bfloat16* A1 = Wq + (size_t)(m0 + row1) * DM + colg0;
  const __hip_bfloat16* B0 = Xb + (size_t)(n0 + row0) * DM + colg0;
  const __hip_bfloat16* B1 = Xb + (size_t)(n0 + row1) * DM + colg0;
  __hip_bfloat16* AsW0 = As + w * 512;
  __hip_bfloat16* AsW1 = As + 2048 + w * 512;
  __hip_bfloat16* BsW0 = Bs + w * 512;
  __hip_bfloat16* BsW1 = Bs + 2048 + w * 512;

  floatx4 acc[4][4] = {};
#pragma unroll 2
  for (int k0 = 0; k0 < DM; k0 += 32) {
    gload_lds16(A0 + k0, AsW0);
    gload_lds16(A1 + k0, AsW1);
    gload_lds16(B0 + k0, BsW0);
    gload_lds16(B1 + k0, BsW1);
    __syncthreads();
    short8v a[4], b[4];
#pragma unroll
    for (int i = 0; i < 4; ++i)
      a[i] = *(const short8v*)&As[(wr * 64 + i * 16 + c) * 32 + g * 8];
#pragma unroll
    for (int j = 0; j < 4; ++j)
      b[j] = *(const short8v*)&Bs[(wc * 64 + j * 16 + c) * 32 + g * 8];
#pragma unroll
    for (int i = 0; i < 4; ++i)
#pragma unroll
      for (int j = 0; j < 4; ++j)
        acc[i][j] = __builtin_amdgcn_mfma_f32_16x16x32_bf16(a[i], b[j], acc[i][j], 0, 0, 0);
    __syncthreads();
  }
#pragma unroll
  for (int i = 0; i < 4; ++i) {
    const int e0 = m0 + wr * 64 + i * 16 + 4 * g;
    const int jj = (e0 & 63) >> 1;
#pragma unroll
    for (int j = 0; j < 4; ++j) {
      const int t = n0 + wc * 64 + j * 16 + c;
      const int b_ = t >> 11, s = t & (SEQ - 1);
      float v0 = acc[i][j][0], v1 = acc[i][j][1], v2 = acc[i][j][2], v3 = acc[i][j][3];
      if (e0 < 2 * DM) {
        const int pos = tpos[t];
        const float2 cs0 = rcs[pos * 32 + jj];
        const float2 cs1 = rcs[pos * 32 + jj + 1];
        const float n0v = v0 * cs0.x - v1 * cs0.y, n1v = v0 * cs0.y + v1 * cs0.x;
        const float n2v = v2 * cs1.x - v3 * cs1.y, n3v = v2 * cs1.y + v3 * cs1.x;
        v0 = n0v; v1 = n1v; v2 = n2v; v3 = n3v;
      }
      if (e0 < DM) {
        const int h = e0 >> 6, d = e0 & 63;
        short4v pk;
        pk[0] = bfb(v0 * QSCALE); pk[1] = bfb(v1 * QSCALE);
        pk[2] = bfb(v2 * QSCALE); pk[3] = bfb(v3 * QSCALE);
        *(short4v*)&Qb[(((size_t)(b_ * NH + h) * SEQ) + s) * HD + d] = pk;
      } else if (e0 < 2 * DM) {
        const int e = e0 - DM, h = e >> 6, d = e & 63;
        short4v pk;
        pk[0] = bfb(v0); pk[1] = bfb(v1); pk[2] = bfb(v2); pk[3] = bfb(v3);
        *(short4v*)&Kb[(((size_t)(b_ * NH + h) * SEQ) + s) * HD + d] = pk;
      } else {
        const int e = e0 - 2 * DM, h = e >> 6, d = e & 63;
        const size_t base = ((size_t)(b_ * NH + h) * HD + d) * SEQ + s;
        Vt[base]           = __float2bfloat16(v0);
        Vt[base + SEQ]     = __float2bfloat16(v1);
        Vt[base + 2 * SEQ] = __float2bfloat16(v2);
        Vt[base + 3 * SEQ] = __float2bfloat16(v3);
      }
    }
  }
}

// ---------------- fused causal flash attention v6: balanced schedule ----------------
// Same inner loop as v5 (counted-vmcnt double-buffered LDS K/V). New block
// decode: per XCD, 3 passes of 32 blocks with qst = {31-t, t, zigzag(t)} so
// every CU's 3 resident blocks sum to ~47+-1 iterations (was 36..68 -> 1.9x
// imbalance = the measured 9% occupancy tail). head = pass. T5 setprio
// around MFMA clusters.
__global__ __launch_bounds__(128) void attn_fused(
    const __hip_bfloat16* __restrict__ Qb,
    const __hip_bfloat16* __restrict__ Kb,
    const __hip_bfloat16* __restrict__ Vt,
    __hip_bfloat16* __restrict__ Cx)
{
  __shared__ __align__(16) __hip_bfloat16 Ks[2][64 * 64];  // 8KB each
  __shared__ __align__(16) __hip_bfloat16 Vs[2][64 * 64];  // V^T: [d][kt]
  const int tid = threadIdx.x;
  const int lane = tid & 63, w = tid >> 6;
  const int c = lane & 15, g = lane >> 4;
  const int bid = blockIdx.x;
  const int xcd = bid & 7, i_ = bid >> 3;          // 96 per XCD
  const int p = i_ >> 5, t_ = i_ & 31;             // pass 0..2, slot 0..31
  // balanced qst: pass0 descending, pass1 ascending (pair-sum = 31),
  // pass2 zigzag around 16 (bijective on 0..31)
  const int qst = (p == 0) ? (31 - t_)
                : (p == 1) ? t_
                : ((t_ & 1) ? 15 - (t_ >> 1) : 16 + (t_ >> 1));
  const int bh = xcd + 8 * p;
  const int qt_w = qst * 2 + w;                    // this wave's 32-row q-tile
  const int KBmax = qst;                           // block iterates kb=0..KBmax
  const __hip_bfloat16* Qh = Qb + (size_t)bh * SEQ * HD;
  const __hip_bfloat16* Kh = Kb + (size_t)bh * SEQ * HD;
  const __hip_bfloat16* Vh = Vt + (size_t)bh * HD * SEQ;
  const int q1 = qt_w * 32 + c, q2 = q1 + 16;
  const short8v qf10 = *(const short8v*)&Qh[(size_t)(qt_w * 32 + c) * HD + g * 8];
  const short8v qf11 = *(const short8v*)&Qh[(size_t)(qt_w * 32 + c) * HD + 32 + g * 8];
  const short8v qf20 = *(const short8v*)&Qh[(size_t)(qt_w * 32 + 16 + c) * HD + g * 8];
  const short8v qf21 = *(const short8v*)&Qh[(size_t)(qt_w * 32 + 16 + c) * HD + 32 + g * 8];
  floatx4 o1[4] = {}, o2[4] = {};
  float l1 = 0.0f, l2 = 0.0f;
  const int kr1 = 8 * (c >> 2) + (c & 3);          // permuted A-row -> kt_local

  const int sr = tid >> 3, sq = tid & 7;

#define STAGE_KV(KB_, KSD, VSD)                                                   \
  do {                                                                            \
    _Pragma("unroll")                                                             \
    for (int j = 0; j < 4; ++j) {                                                 \
      const int row = j * 16 + sr;                                                \
      const int g2 = (sq ^ swzg(row)) * 8;                                        \
      gload_lds16(Kh + (size_t)((KB_) * 64 + row) * HD + g2, (KSD) + j * 1024 + w * 512); \
      gload_lds16(Vh + (size_t)row * SEQ + (KB_) * 64 + g2,  (VSD) + j * 1024 + w * 512); \
    }                                                                             \
  } while (0)

  STAGE_KV(0, Ks[0], Vs[0]);
  int cb = 0;
  for (int kb = 0; kb <= KBmax; ++kb) {
    if (kb < KBmax) {
      STAGE_KV(kb + 1, Ks[cb ^ 1], Vs[cb ^ 1]);
      asm volatile("s_waitcnt vmcnt(8)" ::: "memory");
    } else {
      asm volatile("s_waitcnt vmcnt(0)" ::: "memory");
    }
    __builtin_amdgcn_s_barrier();   // both waves' stage(kb) visible in LDS
    {
      const __hip_bfloat16* Kt = Ks[cb];
      const __hip_bfloat16* Vb = Vs[cb];
#pragma unroll
      for (int s = 0; s < 2; ++s) {
        const int kidx = 2 * kb + s;
        if (kidx <= qt_w) {
          const int r0 = s * 32 + kr1, r1 = r0 + 4;
          const int z0 = swzg(r0), z1 = swzg(r1);
          const short8v a00 = *(const short8v*)&Kt[r0 * 64 + ((g) ^ z0) * 8];
          const short8v a01 = *(const short8v*)&Kt[r0 * 64 + ((4 + g) ^ z0) * 8];
          const short8v a10 = *(const short8v*)&Kt[r1 * 64 + ((g) ^ z1) * 8];
          const short8v a11 = *(const short8v*)&Kt[r1 * 64 + ((4 + g) ^ z1) * 8];
          short8v vf[4];
#pragma unroll
          for (int f = 0; f < 4; ++f) {
            const int rv = f * 16 + c;
            vf[f] = *(const short8v*)&Vb[rv * 64 + ((s * 4 + g) ^ swzg(rv)) * 8];
          }
          floatx4 s1a = {}, s1b = {}, s2a = {}, s2b = {};
          __builtin_amdgcn_s_setprio(1);
          s1a = __builtin_amdgcn_mfma_f32_16x16x32_bf16(a00, qf10, s1a, 0, 0, 0);
          s1a = __builtin_amdgcn_mfma_f32_16x16x32_bf16(a01, qf11, s1a, 0, 0, 0);
          s1b = __builtin_amdgcn_mfma_f32_16x16x32_bf16(a10, qf10, s1b, 0, 0, 0);
          s1b = __builtin_amdgcn_mfma_f32_16x16x32_bf16(a11, qf11, s1b, 0, 0, 0);
          s2a = __builtin_amdgcn_mfma_f32_16x16x32_bf16(a00, qf20, s2a, 0, 0, 0);
          s2a = __builtin_amdgcn_mfma_f32_16x16x32_bf16(a01, qf21, s2a, 0, 0, 0);
          s2b = __builtin_amdgcn_mfma_f32_16x16x32_bf16(a10, qf20, s2b, 0, 0, 0);
          s2b = __builtin_amdgcn_mfma_f32_16x16x32_bf16(a11, qf21, s2b, 0, 0, 0);
          __builtin_amdgcn_s_setprio(0);
          if (kidx == qt_w) {
            const int ktb = kidx * 32;
#pragma unroll
            for (int r = 0; r < 4; ++r) {
              const int kt = ktb + 8 * g + r;
              if (kt > q1) s1a[r] = -INFINITY;
              if (kt + 4 > q1) s1b[r] = -INFINITY;
              if (kt > q2) s2a[r] = -INFINITY;
              if (kt + 4 > q2) s2b[r] = -INFINITY;
            }
          }
          short8v pf1, pf2;
#pragma unroll
          for (int r = 0; r < 4; ++r) {
            float p_;
            p_ = EXPFN(s1a[r]); l1 += p_; pf1[r] = bfb(p_);
            p_ = EXPFN(s1b[r]); l1 += p_; pf1[r + 4] = bfb(p_);
            p_ = EXPFN(s2a[r]); l2 += p_; pf2[r] = bfb(p_);
            p_ = EXPFN(s2b[r]); l2 += p_; pf2[r + 4] = bfb(p_);
          }
          __builtin_amdgcn_s_setprio(1);
          o1[0] = __builtin_amdgcn_mfma_f32_16x16x32_bf16(vf[0], pf1, o1[0], 0, 0, 0);
          o1[1] = __builtin_amdgcn_mfma_f32_16x16x32_bf16(vf[1], pf1, o1[1], 0, 0, 0);
          o1[2] = __builtin_amdgcn_mfma_f32_16x16x32_bf16(vf[2], pf1, o1[2], 0, 0, 0);
          o1[3] = __builtin_amdgcn_mfma_f32_16x16x32_bf16(vf[3], pf1, o1[3], 0, 0, 0);
          o2[0] = __builtin_amdgcn_mfma_f32_16x16x32_bf16(vf[0], pf2, o2[0], 0, 0, 0);
          o2[1] = __builtin_amdgcn_mfma_f32_16x16x32_bf16(vf[1], pf2, o2[1], 0, 0, 0);
          o2[2] = __builtin_amdgcn_mfma_f32_16x16x32_bf16(vf[2], pf2, o2[2], 0, 0, 0);
          o2[3] = __builtin_amdgcn_mfma_f32_16x16x32_bf16(vf[3], pf2, o2[3], 0, 0, 0);
          __builtin_amdgcn_s_setprio(0);
        }
      }
    }
    __builtin_amdgcn_s_barrier();   // buf[cb] consumed by both waves -> reusable
    cb ^= 1;
  }
#undef STAGE_KV

  l1 += __shfl_xor(l1, 16); l1 += __shfl_xor(l1, 32);
  l2 += __shfl_xor(l2, 16); l2 += __shfl_xor(l2, 32);
  const float inv1 = 1.0f / l1, inv2 = 1.0f / l2;
  const int bb = bh / NH, h = bh - bb * NH;
  const size_t trow1 = ((size_t)bb * SEQ + q1) * DM + (size_t)h * HD;
  const size_t trow2 = trow1 + (size_t)16 * DM;
#pragma unroll
  for (int f = 0; f < 4; ++f) {
    short4v pk1, pk2;
#pragma unroll
    for (int r = 0; r < 4; ++r) {
      pk1[r] = bfb(o1[f][r] * inv1);
      pk2[r] = bfb(o2[f][r] * inv2);
    }
    *(short4v*)&Cx[trow1 + f * 16 + 4 * g] = pk1;
    *(short4v*)&Cx[trow2 + f * 16 + 4 * g] = pk2;
  }
}

// ---------------- output GEMM: out[t][e] = sum_d ctx[t][d] * Wo[e][d] ----------------
__global__ __launch_bounds__(256) void out_gemm(
    const __hip_bfloat16* __restrict__ Cx,
    const float* __restrict__ Wo,
    float* __restrict__ out)
{
  __shared__ __align__(16) __hip_bfloat16 As[64][40];
  __shared__ __align__(16) __hip_bfloat16 Bs[64][40];
  const int tid = threadIdx.x;
  const int lane = tid & 63, w = tid >> 6;
  const int c = lane & 15, g = lane >> 4;
  const int m0 = blockIdx.x * 64, n0 = blockIdx.y * 64;
  const int lr = tid >> 2, lk = (tid & 3) * 8;
  const __hip_bfloat16* Ap = Cx + (size_t)(m0 + lr) * DM + lk;
  const float* Bp = Wo + (size_t)(n0 + lr) * DM + lk;
  floatx4 acc[4] = {};
  for (int k0 = 0; k0 < DM; k0 += 32) {
    int4v av = *(const int4v*)(Ap + k0);
    floatx4 b0 = *(const floatx4*)(Bp + k0);
    floatx4 b1 = *(const floatx4*)(Bp + k0 + 4);
    short8v bv;
#pragma unroll
    for (int j = 0; j < 4; ++j) { bv[j] = bfb(b0[j]); bv[j + 4] = bfb(b1[j]); }
    *(int4v*)&As[lr][lk] = av;
    *(short8v*)&Bs[lr][lk] = bv;
    __syncthreads();
    short8v af = *(const short8v*)&As[w * 16 + c][g * 8];
#pragma unroll
    for (int f = 0; f < 4; ++f) {
      short8v bf_ = *(const short8v*)&Bs[f * 16 + c][g * 8];
      acc[f] = __builtin_amdgcn_mfma_f32_16x16x32_bf16(af, bf_, acc[f], 0, 0, 0);
    }
    __syncthreads();
  }
  const int row = m0 + w * 16 + 4 * g;
#pragma unroll
  for (int f = 0; f < 4; ++f) {
    const int col = n0 + f * 16 + c;
#pragma unroll
    for (int r = 0; r < 4; ++r)
      out[(size_t)(row + r) * DM + col] = acc[f][r];
  }
}

extern "C" void kernel_launch(void* const* d_in, const int* in_sizes, int n_in,
                              void* d_out, int out_size, void* d_ws, size_t ws_size,
                              hipStream_t stream) {
  const float* x    = (const float*)d_in[0];
  const int*   tpos = (const int*)d_in[1];
  const float* Wq   = (const float*)d_in[2];
  const float* Wo   = (const float*)d_in[3];
  float* out = (float*)d_out;

  const size_t QKV_BYTES = (size_t)NB * NH * SEQ * HD * 2;  // 6,291,456
  const size_t REQUIRED = 4 * QKV_BYTES;                    // 25,165,824
  if (ws_size < REQUIRED) return;

  char* ws = (char*)d_ws;
  __hip_bfloat16* Qb = (__hip_bfloat16*)(ws);
  __hip_bfloat16* Kb = (__hip_bfloat16*)(ws + QKV_BYTES);
  __hip_bfloat16* Vt = (__hip_bfloat16*)(ws + 2 * QKV_BYTES);
  __hip_bfloat16* Cx = (__hip_bfloat16*)(ws + 3 * QKV_BYTES);
  __hip_bfloat16* xb = (__hip_bfloat16*)(ws + 3 * QKV_BYTES);   // aliases Cx (dead before attn)
  char* ob = (char*)d_out;
  float2* rcs = (float2*)(ob);                                  // d_out-head scratch
  __hip_bfloat16* wqb = (__hip_bfloat16*)(ob + (size_t)SEQ * 32 * 8);

  cvt_bf16<<<dim3(NT * DM / 4 / 256), dim3(256), 0, stream>>>(x, xb, NT * DM / 4);
  cvt_bf16<<<dim3(E3 * DM / 4 / 256), dim3(256), 0, stream>>>(Wq, wqb, E3 * DM / 4);
  rope_tab<<<dim3(SEQ * 32 / 256), dim3(256), 0, stream>>>(rcs);
  qkv_gemm_rope<<<dim3(576), dim3(256), 0, stream>>>(wqb, xb, tpos, rcs, Qb, Kb, Vt);
  attn_fused<<<dim3(768), dim3(128), 0, stream>>>(Qb, Kb, Vt, Cx);
  out_gemm<<<dim3(NT / 64, DM / 64), dim3(256), 0, stream>>>(Cx, Wo, out);
}

// Round 11
// 123.882 us; speedup vs baseline: 1.0859x; 1.0859x over previous
//
#include <hip/hip_runtime.h>
#include <hip/hip_bf16.h>
#include <math.h>

#define SEQ 2048
#define DM 768
#define NH 12
#define HD 64
#define NB 2
#define NT (NB*SEQ)      // 4096 tokens
#define E3 (3*DM)        // 2304

using short4v = __attribute__((ext_vector_type(4))) short;
using short8v = __attribute__((ext_vector_type(8))) short;
using floatx4 = __attribute__((ext_vector_type(4))) float;
using int4v   = __attribute__((ext_vector_type(4))) int;

#if __has_builtin(__builtin_amdgcn_exp2f)
#define EXPFN(x) __builtin_amdgcn_exp2f(x)
#define QSCALE 0.1803368801111244f   /* 0.125 * log2(e) : scores in log2 domain */
#else
#define EXPFN(x) __expf(x)
#define QSCALE 0.125f
#endif

static __device__ __forceinline__ short bfb(float f) {
  union { __hip_bfloat16 h; short s; } u;
  u.h = __float2bfloat16(f);
  return u.s;
}

// async global->LDS, 16 bytes per lane. lds must be wave-uniform.
static __device__ __forceinline__ void gload_lds16(const __hip_bfloat16* g, __hip_bfloat16* lds) {
  __builtin_amdgcn_global_load_lds(
      (const __attribute__((address_space(1))) unsigned int*)g,
      (__attribute__((address_space(3))) unsigned int*)lds, 16, 0, 0);
}

// LDS granule swizzle (16B granules, 8 per 128B row).
static __device__ __forceinline__ int swzg(int row) {
  return (((row >> 3) & 3) + 2 * (row & 3)) & 7;
}

// ---------------- fused fp32 -> bf16 convert: x, Wq, Wo in one dispatch ----------------
#define XN4 (NT * DM / 4)          // 786432
#define WQN4 (E3 * DM / 4)         // 442368
#define WON4 (DM * DM / 4)         // 147456
__global__ void cvt3_bf16(const float* __restrict__ x, const float* __restrict__ wq,
                          const float* __restrict__ wo,
                          __hip_bfloat16* __restrict__ xb, __hip_bfloat16* __restrict__ wqb,
                          __hip_bfloat16* __restrict__ wob) {
  int i = blockIdx.x * blockDim.x + threadIdx.x;
  const float* src;
  __hip_bfloat16* dst;
  int k;
  if (i < XN4) { src = x; dst = xb; k = i; }
  else if (i < XN4 + WQN4) { src = wq; dst = wqb; k = i - XN4; }
  else if (i < XN4 + WQN4 + WON4) { src = wo; dst = wob; k = i - XN4 - WQN4; }
  else return;
  floatx4 v = ((const floatx4*)src)[k];
  short4v o;
  o[0] = bfb(v[0]); o[1] = bfb(v[1]); o[2] = bfb(v[2]); o[3] = bfb(v[3]);
  ((short4v*)dst)[k] = o;
}

// ---------------- RoPE table: (cos,sin)[pos][j] packed float2 ----------------
__global__ void rope_tab(float2* __restrict__ rcs) {
  int idx = blockIdx.x * blockDim.x + threadIdx.x;
  if (idx >= SEQ * 32) return;
  int pos = idx >> 5, j = idx & 31;
  float freq = __expf(-(float)j * (logf(10000.0f) / 32.0f));
  float ang = (float)pos * freq;
  rcs[idx] = make_float2(cosf(ang), sinf(ang));
}

// ---------------- QKV GEMM (m97 structure), C[e][t], RoPE epilogue ----------------
__global__ __launch_bounds__(256) void qkv_gemm_rope(
    const __hip_bfloat16* __restrict__ Wq,
    const __hip_bfloat16* __restrict__ Xb,
    const int* __restrict__ tpos,
    const float2* __restrict__ rcs,
    __hip_bfloat16* __restrict__ Qb, __hip_bfloat16* __restrict__ Kb,
    __hip_bfloat16* __restrict__ Vt)
{
  __shared__ __align__(16) __hip_bfloat16 As[128 * 32];
  __shared__ __align__(16) __hip_bfloat16 Bs[128 * 32];
  const int tid = threadIdx.x;
  const int lane = tid & 63, w = tid >> 6;
  const int c = lane & 15, g = lane >> 4;
  const int wr = w >> 1, wc = w & 1;
  const int bid = blockIdx.x;
  const int xcd = bid & 7, i_ = bid >> 3;
  const int nb = xcd * 4 + (i_ & 3), mb = i_ >> 2;
  const int m0 = mb * 128, n0 = nb * 128;
  const int row0 = tid >> 2, colg0 = (tid & 3) * 8;
  const int row1 = 64 + row0;
  const __hip_bfloat16* A0 = Wq + (size_t)(m0 + row0) * DM + colg0;
  const __hip_bfloat16* A1 = Wq + (size_t)(m0 + row1) * DM + colg0;
  const __hip_bfloat16* B0 = Xb + (size_t)(n0 + row0) * DM + colg0;
  const __hip_bfloat16* B1 = Xb + (size_t)(n0 + row1) * DM + colg0;
  __hip_bfloat16* AsW0 = As + w * 512;
  __hip_bfloat16* AsW1 = As + 2048 + w * 512;
  __hip_bfloat16* BsW0 = Bs + w * 512;
  __hip_bfloat16* BsW1 = Bs + 2048 + w * 512;

  floatx4 acc[4][4] = {};
#pragma unroll 2
  for (int k0 = 0; k0 < DM; k0 += 32) {
    gload_lds16(A0 + k0, AsW0);
    gload_lds16(A1 + k0, AsW1);
    gload_lds16(B0 + k0, BsW0);
    gload_lds16(B1 + k0, BsW1);
    __syncthreads();
    short8v a[4], b[4];
#pragma unroll
    for (int i = 0; i < 4; ++i)
      a[i] = *(const short8v*)&As[(wr * 64 + i * 16 + c) * 32 + g * 8];
#pragma unroll
    for (int j = 0; j < 4; ++j)
      b[j] = *(const short8v*)&Bs[(wc * 64 + j * 16 + c) * 32 + g * 8];
#pragma unroll
    for (int i = 0; i < 4; ++i)
#pragma unroll
      for (int j = 0; j < 4; ++j)
        acc[i][j] = __builtin_amdgcn_mfma_f32_16x16x32_bf16(a[i], b[j], acc[i][j], 0, 0, 0);
    __syncthreads();
  }
#pragma unroll
  for (int i = 0; i < 4; ++i) {
    const int e0 = m0 + wr * 64 + i * 16 + 4 * g;
    const int jj = (e0 & 63) >> 1;
#pragma unroll
    for (int j = 0; j < 4; ++j) {
      const int t = n0 + wc * 64 + j * 16 + c;
      const int b_ = t >> 11, s = t & (SEQ - 1);
      float v0 = acc[i][j][0], v1 = acc[i][j][1], v2 = acc[i][j][2], v3 = acc[i][j][3];
      if (e0 < 2 * DM) {
        const int pos = tpos[t];
        const float2 cs0 = rcs[pos * 32 + jj];
        const float2 cs1 = rcs[pos * 32 + jj + 1];
        const float n0v = v0 * cs0.x - v1 * cs0.y, n1v = v0 * cs0.y + v1 * cs0.x;
        const float n2v = v2 * cs1.x - v3 * cs1.y, n3v = v2 * cs1.y + v3 * cs1.x;
        v0 = n0v; v1 = n1v; v2 = n2v; v3 = n3v;
      }
      if (e0 < DM) {
        const int h = e0 >> 6, d = e0 & 63;
        short4v pk;
        pk[0] = bfb(v0 * QSCALE); pk[1] = bfb(v1 * QSCALE);
        pk[2] = bfb(v2 * QSCALE); pk[3] = bfb(v3 * QSCALE);
        *(short4v*)&Qb[(((size_t)(b_ * NH + h) * SEQ) + s) * HD + d] = pk;
      } else if (e0 < 2 * DM) {
        const int e = e0 - DM, h = e >> 6, d = e & 63;
        short4v pk;
        pk[0] = bfb(v0); pk[1] = bfb(v1); pk[2] = bfb(v2); pk[3] = bfb(v3);
        *(short4v*)&Kb[(((size_t)(b_ * NH + h) * SEQ) + s) * HD + d] = pk;
      } else {
        const int e = e0 - 2 * DM, h = e >> 6, d = e & 63;
        const size_t base = ((size_t)(b_ * NH + h) * HD + d) * SEQ + s;
        Vt[base]           = __float2bfloat16(v0);
        Vt[base + SEQ]     = __float2bfloat16(v1);
        Vt[base + 2 * SEQ] = __float2bfloat16(v2);
        Vt[base + 3 * SEQ] = __float2bfloat16(v3);
      }
    }
  }
}

// ---------------- fused causal flash attention (R8 v4, best-known: 52.3us) ----------------
__global__ __launch_bounds__(128) void attn_fused(
    const __hip_bfloat16* __restrict__ Qb,
    const __hip_bfloat16* __restrict__ Kb,
    const __hip_bfloat16* __restrict__ Vt,
    __hip_bfloat16* __restrict__ Cx)
{
  __shared__ __align__(16) __hip_bfloat16 Ks[2][64 * 64];  // 8KB each
  __shared__ __align__(16) __hip_bfloat16 Vs[2][64 * 64];  // V^T: [d][kt]
  const int tid = threadIdx.x;
  const int lane = tid & 63, w = tid >> 6;
  const int c = lane & 15, g = lane >> 4;
  const int bid = blockIdx.x;
  const int xcd = bid & 7, i_ = bid >> 3;          // 96 per XCD
  const int bh = xcd + 8 * (i_ % 3);
  const int qst = 31 - i_ / 3;                     // descending: big blocks first
  const int qt_w = qst * 2 + w;                    // this wave's 32-row q-tile
  const int KBmax = qst;                           // block iterates kb=0..KBmax
  const __hip_bfloat16* Qh = Qb + (size_t)bh * SEQ * HD;
  const __hip_bfloat16* Kh = Kb + (size_t)bh * SEQ * HD;
  const __hip_bfloat16* Vh = Vt + (size_t)bh * HD * SEQ;
  const int q1 = qt_w * 32 + c, q2 = q1 + 16;
  const short8v qf10 = *(const short8v*)&Qh[(size_t)(qt_w * 32 + c) * HD + g * 8];
  const short8v qf11 = *(const short8v*)&Qh[(size_t)(qt_w * 32 + c) * HD + 32 + g * 8];
  const short8v qf20 = *(const short8v*)&Qh[(size_t)(qt_w * 32 + 16 + c) * HD + g * 8];
  const short8v qf21 = *(const short8v*)&Qh[(size_t)(qt_w * 32 + 16 + c) * HD + 32 + g * 8];
  floatx4 o1[4] = {}, o2[4] = {};
  float l1 = 0.0f, l2 = 0.0f;
  const int kr1 = 8 * (c >> 2) + (c & 3);          // permuted A-row -> kt_local

  const int sr = tid >> 3, sq = tid & 7;

#define STAGE_KV(KB_, KSD, VSD)                                                   \
  do {                                                                            \
    _Pragma("unroll")                                                             \
    for (int j = 0; j < 4; ++j) {                                                 \
      const int row = j * 16 + sr;                                                \
      const int g2 = (sq ^ swzg(row)) * 8;                                        \
      gload_lds16(Kh + (size_t)((KB_) * 64 + row) * HD + g2, (KSD) + j * 1024 + w * 512); \
      gload_lds16(Vh + (size_t)row * SEQ + (KB_) * 64 + g2,  (VSD) + j * 1024 + w * 512); \
    }                                                                             \
  } while (0)

  STAGE_KV(0, Ks[0], Vs[0]);
  __syncthreads();
  int cb = 0;
  for (int kb = 0; kb <= KBmax; ++kb) {
    if (kb < KBmax) STAGE_KV(kb + 1, Ks[cb ^ 1], Vs[cb ^ 1]);
    {
      const __hip_bfloat16* Kt = Ks[cb];
      const __hip_bfloat16* Vb = Vs[cb];
#pragma unroll
      for (int s = 0; s < 2; ++s) {
        const int kidx = 2 * kb + s;
        if (kidx <= qt_w) {
          const int r0 = s * 32 + kr1, r1 = r0 + 4;
          const int z0 = swzg(r0), z1 = swzg(r1);
          const short8v a00 = *(const short8v*)&Kt[r0 * 64 + ((g) ^ z0) * 8];
          const short8v a01 = *(const short8v*)&Kt[r0 * 64 + ((4 + g) ^ z0) * 8];
          const short8v a10 = *(const short8v*)&Kt[r1 * 64 + ((g) ^ z1) * 8];
          const short8v a11 = *(const short8v*)&Kt[r1 * 64 + ((4 + g) ^ z1) * 8];
          short8v vf[4];
#pragma unroll
          for (int f = 0; f < 4; ++f) {
            const int rv = f * 16 + c;
            vf[f] = *(const short8v*)&Vb[rv * 64 + ((s * 4 + g) ^ swzg(rv)) * 8];
          }
          floatx4 s1a = {}, s1b = {}, s2a = {}, s2b = {};
          s1a = __builtin_amdgcn_mfma_f32_16x16x32_bf16(a00, qf10, s1a, 0, 0, 0);
          s1a = __builtin_amdgcn_mfma_f32_16x16x32_bf16(a01, qf11, s1a, 0, 0, 0);
          s1b = __builtin_amdgcn_mfma_f32_16x16x32_bf16(a10, qf10, s1b, 0, 0, 0);
          s1b = __builtin_amdgcn_mfma_f32_16x16x32_bf16(a11, qf11, s1b, 0, 0, 0);
          s2a = __builtin_amdgcn_mfma_f32_16x16x32_bf16(a00, qf20, s2a, 0, 0, 0);
          s2a = __builtin_amdgcn_mfma_f32_16x16x32_bf16(a01, qf21, s2a, 0, 0, 0);
          s2b = __builtin_amdgcn_mfma_f32_16x16x32_bf16(a10, qf20, s2b, 0, 0, 0);
          s2b = __builtin_amdgcn_mfma_f32_16x16x32_bf16(a11, qf21, s2b, 0, 0, 0);
          if (kidx == qt_w) {
            const int ktb = kidx * 32;
#pragma unroll
            for (int r = 0; r < 4; ++r) {
              const int kt = ktb + 8 * g + r;
              if (kt > q1) s1a[r] = -INFINITY;
              if (kt + 4 > q1) s1b[r] = -INFINITY;
              if (kt > q2) s2a[r] = -INFINITY;
              if (kt + 4 > q2) s2b[r] = -INFINITY;
            }
          }
          short8v pf1, pf2;
#pragma unroll
          for (int r = 0; r < 4; ++r) {
            float p;
            p = EXPFN(s1a[r]); l1 += p; pf1[r] = bfb(p);
            p = EXPFN(s1b[r]); l1 += p; pf1[r + 4] = bfb(p);
            p = EXPFN(s2a[r]); l2 += p; pf2[r] = bfb(p);
            p = EXPFN(s2b[r]); l2 += p; pf2[r + 4] = bfb(p);
          }
          o1[0] = __builtin_amdgcn_mfma_f32_16x16x32_bf16(vf[0], pf1, o1[0], 0, 0, 0);
          o1[1] = __builtin_amdgcn_mfma_f32_16x16x32_bf16(vf[1], pf1, o1[1], 0, 0, 0);
          o1[2] = __builtin_amdgcn_mfma_f32_16x16x32_bf16(vf[2], pf1, o1[2], 0, 0, 0);
          o1[3] = __builtin_amdgcn_mfma_f32_16x16x32_bf16(vf[3], pf1, o1[3], 0, 0, 0);
          o2[0] = __builtin_amdgcn_mfma_f32_16x16x32_bf16(vf[0], pf2, o2[0], 0, 0, 0);
          o2[1] = __builtin_amdgcn_mfma_f32_16x16x32_bf16(vf[1], pf2, o2[1], 0, 0, 0);
          o2[2] = __builtin_amdgcn_mfma_f32_16x16x32_bf16(vf[2], pf2, o2[2], 0, 0, 0);
          o2[3] = __builtin_amdgcn_mfma_f32_16x16x32_bf16(vf[3], pf2, o2[3], 0, 0, 0);
        }
      }
    }
    __syncthreads();
    cb ^= 1;
  }
#undef STAGE_KV

  l1 += __shfl_xor(l1, 16); l1 += __shfl_xor(l1, 32);
  l2 += __shfl_xor(l2, 16); l2 += __shfl_xor(l2, 32);
  const float inv1 = 1.0f / l1, inv2 = 1.0f / l2;
  const int bb = bh / NH, h = bh - bb * NH;
  const size_t trow1 = ((size_t)bb * SEQ + q1) * DM + (size_t)h * HD;
  const size_t trow2 = trow1 + (size_t)16 * DM;
#pragma unroll
  for (int f = 0; f < 4; ++f) {
    short4v pk1, pk2;
#pragma unroll
    for (int r = 0; r < 4; ++r) {
      pk1[r] = bfb(o1[f][r] * inv1);
      pk2[r] = bfb(o2[f][r] * inv2);
    }
    *(short4v*)&Cx[trow1 + f * 16 + 4 * g] = pk1;
    *(short4v*)&Cx[trow2 + f * 16 + 4 * g] = pk2;
  }
}

// ---------------- output GEMM (m97 structure), C[e][t] orientation ----------------
// out[t][e] = sum_d Cx[t][d] * Wo[e][d]. A = wob bf16 [768][768] (e-rows),
// B = Cx bf16 [4096][768] (t-rows). acc[i][j] reg r -> e = (A-row), t = (B-col):
// epilogue = one aligned float4 store per fragment.
__global__ __launch_bounds__(256) void out_gemm(
    const __hip_bfloat16* __restrict__ Wo,
    const __hip_bfloat16* __restrict__ Cx,
    float* __restrict__ out)
{
  __shared__ __align__(16) __hip_bfloat16 As[128 * 32];
  __shared__ __align__(16) __hip_bfloat16 Bs[128 * 32];
  const int tid = threadIdx.x;
  const int lane = tid & 63, w = tid >> 6;
  const int c = lane & 15, g = lane >> 4;
  const int wr = w >> 1, wc = w & 1;
  const int m0 = blockIdx.y * 128;   // e-block (6)
  const int n0 = blockIdx.x * 128;   // t-block (32); x fastest -> A-panel L2 reuse
  const int row0 = tid >> 2, colg0 = (tid & 3) * 8;
  const int row1 = 64 + row0;
  const __hip_bfloat16* A0 = Wo + (size_t)(m0 + row0) * DM + colg0;
  const __hip_bfloat16* A1 = Wo + (size_t)(m0 + row1) * DM + colg0;
  const __hip_bfloat16* B0 = Cx + (size_t)(n0 + row0) * DM + colg0;
  const __hip_bfloat16* B1 = Cx + (size_t)(n0 + row1) * DM + colg0;
  __hip_bfloat16* AsW0 = As + w * 512;
  __hip_bfloat16* AsW1 = As + 2048 + w * 512;
  __hip_bfloat16* BsW0 = Bs + w * 512;
  __hip_bfloat16* BsW1 = Bs + 2048 + w * 512;

  floatx4 acc[4][4] = {};
#pragma unroll 2
  for (int k0 = 0; k0 < DM; k0 += 32) {
    gload_lds16(A0 + k0, AsW0);
    gload_lds16(A1 + k0, AsW1);
    gload_lds16(B0 + k0, BsW0);
    gload_lds16(B1 + k0, BsW1);
    __syncthreads();
    short8v a[4], b[4];
#pragma unroll
    for (int i = 0; i < 4; ++i)
      a[i] = *(const short8v*)&As[(wr * 64 + i * 16 + c) * 32 + g * 8];
#pragma unroll
    for (int j = 0; j < 4; ++j)
      b[j] = *(const short8v*)&Bs[(wc * 64 + j * 16 + c) * 32 + g * 8];
#pragma unroll
    for (int i = 0; i < 4; ++i)
#pragma unroll
      for (int j = 0; j < 4; ++j)
        acc[i][j] = __builtin_amdgcn_mfma_f32_16x16x32_bf16(a[i], b[j], acc[i][j], 0, 0, 0);
    __syncthreads();
  }
#pragma unroll
  for (int i = 0; i < 4; ++i) {
    const int e0 = m0 + wr * 64 + i * 16 + 4 * g;
#pragma unroll
    for (int j = 0; j < 4; ++j) {
      const int t = n0 + wc * 64 + j * 16 + c;
      *(floatx4*)&out[(size_t)t * DM + e0] = acc[i][j];
    }
  }
}

extern "C" void kernel_launch(void* const* d_in, const int* in_sizes, int n_in,
                              void* d_out, int out_size, void* d_ws, size_t ws_size,
                              hipStream_t stream) {
  const float* x    = (const float*)d_in[0];
  const int*   tpos = (const int*)d_in[1];
  const float* Wq   = (const float*)d_in[2];
  const float* Wo   = (const float*)d_in[3];
  float* out = (float*)d_out;

  const size_t QKV_BYTES = (size_t)NB * NH * SEQ * HD * 2;  // 6,291,456
  const size_t REQUIRED = 4 * QKV_BYTES;                    // 25,165,824
  if (ws_size < REQUIRED) return;

  char* ws = (char*)d_ws;
  __hip_bfloat16* Qb = (__hip_bfloat16*)(ws);
  __hip_bfloat16* Kb = (__hip_bfloat16*)(ws + QKV_BYTES);
  __hip_bfloat16* Vt = (__hip_bfloat16*)(ws + 2 * QKV_BYTES);
  __hip_bfloat16* Cx = (__hip_bfloat16*)(ws + 3 * QKV_BYTES);
  __hip_bfloat16* xb = (__hip_bfloat16*)(ws + 3 * QKV_BYTES);   // aliases Cx (dead before attn)
  // d_out-head scratch (overwritten in full by out_gemm at the end):
  char* ob = (char*)d_out;
  float2* rcs = (float2*)(ob);                                           // 512KB
  __hip_bfloat16* wqb = (__hip_bfloat16*)(ob + (size_t)SEQ * 32 * 8);    // 3.54MB
  __hip_bfloat16* wob = (__hip_bfloat16*)(ob + (size_t)SEQ * 32 * 8 + (size_t)E3 * DM * 2);  // 1.18MB

  const int CVT_N = XN4 + WQN4 + WON4;  // 1,376,256 float4 granules
  cvt3_bf16<<<dim3((CVT_N + 255) / 256), dim3(256), 0, stream>>>(x, Wq, Wo, xb, wqb, wob);
  rope_tab<<<dim3(SEQ * 32 / 256), dim3(256), 0, stream>>>(rcs);
  qkv_gemm_rope<<<dim3(576), dim3(256), 0, stream>>>(wqb, xb, tpos, rcs, Qb, Kb, Vt);
  attn_fused<<<dim3(768), dim3(128), 0, stream>>>(Qb, Kb, Vt, Cx);
  out_gemm<<<dim3(32, 6), dim3(256), 0, stream>>>(wob, Cx, out);
}

// Round 12
// 119.328 us; speedup vs baseline: 1.1273x; 1.0382x over previous
//
#include <hip/hip_runtime.h>
#include <hip/hip_bf16.h>
#include <math.h>

#define SEQ 2048
#define DM 768
#define NH 12
#define HD 64
#define NB 2
#define NT (NB*SEQ)      // 4096 tokens
#define E3 (3*DM)        // 2304

using short4v = __attribute__((ext_vector_type(4))) short;
using short8v = __attribute__((ext_vector_type(8))) short;
using floatx4 = __attribute__((ext_vector_type(4))) float;
using int4v   = __attribute__((ext_vector_type(4))) int;

#if __has_builtin(__builtin_amdgcn_exp2f)
#define EXPFN(x) __builtin_amdgcn_exp2f(x)
#define QSCALE 0.1803368801111244f   /* 0.125 * log2(e) : scores in log2 domain */
#else
#define EXPFN(x) __expf(x)
#define QSCALE 0.125f
#endif

static __device__ __forceinline__ short bfb(float f) {
  union { __hip_bfloat16 h; short s; } u;
  u.h = __float2bfloat16(f);
  return u.s;
}

// async global->LDS, 16 bytes per lane. lds must be wave-uniform.
static __device__ __forceinline__ void gload_lds16(const __hip_bfloat16* g, __hip_bfloat16* lds) {
  __builtin_amdgcn_global_load_lds(
      (const __attribute__((address_space(1))) unsigned int*)g,
      (__attribute__((address_space(3))) unsigned int*)lds, 16, 0, 0);
}

// K granule swizzle (16B granules, 8 per 128B row): rows 8a+b -> (a+2b)&7
// spreads the kr1-pattern reads to <=2-way bank aliasing.
static __device__ __forceinline__ int swzg(int row) {
  return (((row >> 3) & 3) + 2 * (row & 3)) & 7;
}

// ---------------- fused fp32 -> bf16 convert: x, Wq, Wo in one dispatch ----------------
#define XN4 (NT * DM / 4)          // 786432
#define WQN4 (E3 * DM / 4)         // 442368
#define WON4 (DM * DM / 4)         // 147456
__global__ void cvt3_bf16(const float* __restrict__ x, const float* __restrict__ wq,
                          const float* __restrict__ wo,
                          __hip_bfloat16* __restrict__ xb, __hip_bfloat16* __restrict__ wqb,
                          __hip_bfloat16* __restrict__ wob) {
  int i = blockIdx.x * blockDim.x + threadIdx.x;
  const float* src;
  __hip_bfloat16* dst;
  int k;
  if (i < XN4) { src = x; dst = xb; k = i; }
  else if (i < XN4 + WQN4) { src = wq; dst = wqb; k = i - XN4; }
  else if (i < XN4 + WQN4 + WON4) { src = wo; dst = wob; k = i - XN4 - WQN4; }
  else return;
  floatx4 v = ((const floatx4*)src)[k];
  short4v o;
  o[0] = bfb(v[0]); o[1] = bfb(v[1]); o[2] = bfb(v[2]); o[3] = bfb(v[3]);
  ((short4v*)dst)[k] = o;
}

// ---------------- RoPE table: (cos,sin)[pos][j] packed float2 ----------------
__global__ void rope_tab(float2* __restrict__ rcs) {
  int idx = blockIdx.x * blockDim.x + threadIdx.x;
  if (idx >= SEQ * 32) return;
  int pos = idx >> 5, j = idx & 31;
  float freq = __expf(-(float)j * (logf(10000.0f) / 32.0f));
  float ang = (float)pos * freq;
  rcs[idx] = make_float2(cosf(ang), sinf(ang));
}

// ---------------- QKV GEMM (m97 structure), C[e][t], RoPE epilogue ----------------
__global__ __launch_bounds__(256) void qkv_gemm_rope(
    const __hip_bfloat16* __restrict__ Wq,
    const __hip_bfloat16* __restrict__ Xb,
    const int* __restrict__ tpos,
    const float2* __restrict__ rcs,
    __hip_bfloat16* __restrict__ Qb, __hip_bfloat16* __restrict__ Kb,
    __hip_bfloat16* __restrict__ Vt)
{
  __shared__ __align__(16) __hip_bfloat16 As[128 * 32];
  __shared__ __align__(16) __hip_bfloat16 Bs[128 * 32];
  const int tid = threadIdx.x;
  const int lane = tid & 63, w = tid >> 6;
  const int c = lane & 15, g = lane >> 4;
  const int wr = w >> 1, wc = w & 1;
  const int bid = blockIdx.x;
  const int xcd = bid & 7, i_ = bid >> 3;
  const int nb = xcd * 4 + (i_ & 3), mb = i_ >> 2;
  const int m0 = mb * 128, n0 = nb * 128;
  const int row0 = tid >> 2, colg0 = (tid & 3) * 8;
  const int row1 = 64 + row0;
  const __hip_bfloat16* A0 = Wq + (size_t)(m0 + row0) * DM + colg0;
  const __hip_bfloat16* A1 = Wq + (size_t)(m0 + row1) * DM + colg0;
  const __hip_bfloat16* B0 = Xb + (size_t)(n0 + row0) * DM + colg0;
  const __hip_bfloat16* B1 = Xb + (size_t)(n0 + row1) * DM + colg0;
  __hip_bfloat16* AsW0 = As + w * 512;
  __hip_bfloat16* AsW1 = As + 2048 + w * 512;
  __hip_bfloat16* BsW0 = Bs + w * 512;
  __hip_bfloat16* BsW1 = Bs + 2048 + w * 512;

  floatx4 acc[4][4] = {};
#pragma unroll 2
  for (int k0 = 0; k0 < DM; k0 += 32) {
    gload_lds16(A0 + k0, AsW0);
    gload_lds16(A1 + k0, AsW1);
    gload_lds16(B0 + k0, BsW0);
    gload_lds16(B1 + k0, BsW1);
    __syncthreads();
    short8v a[4], b[4];
#pragma unroll
    for (int i = 0; i < 4; ++i)
      a[i] = *(const short8v*)&As[(wr * 64 + i * 16 + c) * 32 + g * 8];
#pragma unroll
    for (int j = 0; j < 4; ++j)
      b[j] = *(const short8v*)&Bs[(wc * 64 + j * 16 + c) * 32 + g * 8];
#pragma unroll
    for (int i = 0; i < 4; ++i)
#pragma unroll
      for (int j = 0; j < 4; ++j)
        acc[i][j] = __builtin_amdgcn_mfma_f32_16x16x32_bf16(a[i], b[j], acc[i][j], 0, 0, 0);
    __syncthreads();
  }
#pragma unroll
  for (int i = 0; i < 4; ++i) {
    const int e0 = m0 + wr * 64 + i * 16 + 4 * g;
    const int jj = (e0 & 63) >> 1;
#pragma unroll
    for (int j = 0; j < 4; ++j) {
      const int t = n0 + wc * 64 + j * 16 + c;
      const int b_ = t >> 11, s = t & (SEQ - 1);
      float v0 = acc[i][j][0], v1 = acc[i][j][1], v2 = acc[i][j][2], v3 = acc[i][j][3];
      if (e0 < 2 * DM) {
        const int pos = tpos[t];
        const float2 cs0 = rcs[pos * 32 + jj];
        const float2 cs1 = rcs[pos * 32 + jj + 1];
        const float n0v = v0 * cs0.x - v1 * cs0.y, n1v = v0 * cs0.y + v1 * cs0.x;
        const float n2v = v2 * cs1.x - v3 * cs1.y, n3v = v2 * cs1.y + v3 * cs1.x;
        v0 = n0v; v1 = n1v; v2 = n2v; v3 = n3v;
      }
      if (e0 < DM) {
        const int h = e0 >> 6, d = e0 & 63;
        short4v pk;
        pk[0] = bfb(v0 * QSCALE); pk[1] = bfb(v1 * QSCALE);
        pk[2] = bfb(v2 * QSCALE); pk[3] = bfb(v3 * QSCALE);
        *(short4v*)&Qb[(((size_t)(b_ * NH + h) * SEQ) + s) * HD + d] = pk;
      } else if (e0 < 2 * DM) {
        const int e = e0 - DM, h = e >> 6, d = e & 63;
        short4v pk;
        pk[0] = bfb(v0); pk[1] = bfb(v1); pk[2] = bfb(v2); pk[3] = bfb(v3);
        *(short4v*)&Kb[(((size_t)(b_ * NH + h) * SEQ) + s) * HD + d] = pk;
      } else {
        const int e = e0 - 2 * DM, h = e >> 6, d = e & 63;
        const size_t base = ((size_t)(b_ * NH + h) * HD + d) * SEQ + s;
        Vt[base]           = __float2bfloat16(v0);
        Vt[base + SEQ]     = __float2bfloat16(v1);
        Vt[base + 2 * SEQ] = __float2bfloat16(v2);
        Vt[base + 3 * SEQ] = __float2bfloat16(v3);
      }
    }
  }
}

// ---------------- fused causal flash attention v7: fine-grain waves ----------------
// Block = 32 q-rows = 2 waves x 16 rows; KVBLK=32; LDS 16KB (K[32][64] +
// V^T[64][32], double-buffered). 1536 blocks (24 bh x 64 row-groups, qg
// descending) -> ~6 blocks/CU resident (LDS cap 10) = ~3 waves/SIMD: enough
// independent wave-iters to hide the per-iter dependency chain that pinned
// v4-v6 at 52us (1.5 waves/SIMD). Same 2-phase syncthreads loop as v4.
__global__ __launch_bounds__(128) void attn_fused(
    const __hip_bfloat16* __restrict__ Qb,
    const __hip_bfloat16* __restrict__ Kb,
    const __hip_bfloat16* __restrict__ Vt,
    __hip_bfloat16* __restrict__ Cx)
{
  __shared__ __align__(16) __hip_bfloat16 Ks[2][32 * 64];  // 4KB each
  __shared__ __align__(16) __hip_bfloat16 Vs[2][64 * 32];  // V^T: [d][kt], 4KB each
  const int tid = threadIdx.x;
  const int lane = tid & 63, w = tid >> 6;
  const int c = lane & 15, g = lane >> 4;
  const int bid = blockIdx.x;
  const int xcd = bid & 7, i_ = bid >> 3;          // 192 per XCD
  const int bh = xcd + 8 * (i_ % 3);
  const int qg = 63 - i_ / 3;                      // 32-row group, descending
  const int KBmax = qg;                            // kb = 0..qg (32 keys each)
  const __hip_bfloat16* Qh = Qb + (size_t)bh * SEQ * HD;
  const __hip_bfloat16* Kh = Kb + (size_t)bh * SEQ * HD;
  const __hip_bfloat16* Vh = Vt + (size_t)bh * HD * SEQ;
  const int qrl = w * 16 + c;                      // q-row within the 32-row group
  const int q1 = qg * 32 + qrl;                    // absolute q-row
  const short8v qf10 = *(const short8v*)&Qh[(size_t)q1 * HD + g * 8];
  const short8v qf11 = *(const short8v*)&Qh[(size_t)q1 * HD + 32 + g * 8];
  floatx4 o1[4] = {};
  float l1 = 0.0f;
  const int kr1 = 8 * (c >> 2) + (c & 3);          // permuted A-row -> kt_local

  // staging: K 256 granules (32 rows x 8), V 256 granules (64 rows x 4);
  // per gload call: 64 lanes x 16B. 2 K-calls + 2 V-calls per wave.
  const int krow0 = w * 8 + (lane >> 3), kslot = lane & 7;    // K rows per call: +16*j
  const int vrow0 = w * 16 + (lane >> 2), vslot = lane & 3;   // V rows per call: +32*j

#define STAGE_KV(KB_, KSD, VSD)                                                    \
  do {                                                                             \
    _Pragma("unroll")                                                              \
    for (int j = 0; j < 2; ++j) {                                                  \
      const int kr = j * 16 + krow0;                                               \
      gload_lds16(Kh + (size_t)((KB_) * 32 + kr) * HD + ((kslot ^ swzg(kr)) * 8),  \
                  (KSD) + j * 1024 + w * 512);                                     \
      const int vr = j * 32 + vrow0;                                               \
      gload_lds16(Vh + (size_t)vr * SEQ + (KB_) * 32 + ((vslot ^ (vr & 3)) * 8),   \
                  (VSD) + j * 1024 + w * 512);                                     \
    }                                                                              \
  } while (0)

  STAGE_KV(0, Ks[0], Vs[0]);
  __syncthreads();
  int cb = 0;
  for (int kb = 0; kb <= KBmax; ++kb) {
    if (kb < KBmax) STAGE_KV(kb + 1, Ks[cb ^ 1], Vs[cb ^ 1]);
    {
      const __hip_bfloat16* Kt = Ks[cb];
      const __hip_bfloat16* Vb = Vs[cb];
      const int r0 = kr1, r1 = kr1 + 4;
      const int z0 = swzg(r0), z1 = swzg(r1);
      const short8v a00 = *(const short8v*)&Kt[r0 * 64 + ((g ^ z0) * 8)];
      const short8v a01 = *(const short8v*)&Kt[r0 * 64 + (((4 + g) ^ z0) * 8)];
      const short8v a10 = *(const short8v*)&Kt[r1 * 64 + ((g ^ z1) * 8)];
      const short8v a11 = *(const short8v*)&Kt[r1 * 64 + (((4 + g) ^ z1) * 8)];
      short8v vf[4];
#pragma unroll
      for (int f = 0; f < 4; ++f) {
        const int rv = f * 16 + c;
        vf[f] = *(const short8v*)&Vb[rv * 32 + ((g ^ (rv & 3)) * 8)];
      }
      floatx4 s1a = {}, s1b = {};
      s1a = __builtin_amdgcn_mfma_f32_16x16x32_bf16(a00, qf10, s1a, 0, 0, 0);
      s1a = __builtin_amdgcn_mfma_f32_16x16x32_bf16(a01, qf11, s1a, 0, 0, 0);
      s1b = __builtin_amdgcn_mfma_f32_16x16x32_bf16(a10, qf10, s1b, 0, 0, 0);
      s1b = __builtin_amdgcn_mfma_f32_16x16x32_bf16(a11, qf11, s1b, 0, 0, 0);
      if (kb == KBmax) {  // diagonal 32x32 block: mask keys > q
#pragma unroll
        for (int r = 0; r < 4; ++r) {
          if (8 * g + r > qrl) s1a[r] = -INFINITY;
          if (8 * g + r + 4 > qrl) s1b[r] = -INFINITY;
        }
      }
      short8v pf1;
#pragma unroll
      for (int r = 0; r < 4; ++r) {
        float p;
        p = EXPFN(s1a[r]); l1 += p; pf1[r] = bfb(p);
        p = EXPFN(s1b[r]); l1 += p; pf1[r + 4] = bfb(p);
      }
      o1[0] = __builtin_amdgcn_mfma_f32_16x16x32_bf16(vf[0], pf1, o1[0], 0, 0, 0);
      o1[1] = __builtin_amdgcn_mfma_f32_16x16x32_bf16(vf[1], pf1, o1[1], 0, 0, 0);
      o1[2] = __builtin_amdgcn_mfma_f32_16x16x32_bf16(vf[2], pf1, o1[2], 0, 0, 0);
      o1[3] = __builtin_amdgcn_mfma_f32_16x16x32_bf16(vf[3], pf1, o1[3], 0, 0, 0);
    }
    __syncthreads();
    cb ^= 1;
  }
#undef STAGE_KV

  l1 += __shfl_xor(l1, 16); l1 += __shfl_xor(l1, 32);
  const float inv1 = 1.0f / l1;
  const int bb = bh / NH, h = bh - bb * NH;
  const size_t trow1 = ((size_t)bb * SEQ + q1) * DM + (size_t)h * HD;
#pragma unroll
  for (int f = 0; f < 4; ++f) {
    short4v pk1;
#pragma unroll
    for (int r = 0; r < 4; ++r) pk1[r] = bfb(o1[f][r] * inv1);
    *(short4v*)&Cx[trow1 + f * 16 + 4 * g] = pk1;
  }
}

// ---------------- output GEMM (m97 structure), C[e][t] orientation ----------------
__global__ __launch_bounds__(256) void out_gemm(
    const __hip_bfloat16* __restrict__ Wo,
    const __hip_bfloat16* __restrict__ Cx,
    float* __restrict__ out)
{
  __shared__ __align__(16) __hip_bfloat16 As[128 * 32];
  __shared__ __align__(16) __hip_bfloat16 Bs[128 * 32];
  const int tid = threadIdx.x;
  const int lane = tid & 63, w = tid >> 6;
  const int c = lane & 15, g = lane >> 4;
  const int wr = w >> 1, wc = w & 1;
  const int m0 = blockIdx.y * 128;   // e-block (6)
  const int n0 = blockIdx.x * 128;   // t-block (32)
  const int row0 = tid >> 2, colg0 = (tid & 3) * 8;
  const int row1 = 64 + row0;
  const __hip_bfloat16* A0 = Wo + (size_t)(m0 + row0) * DM + colg0;
  const __hip_bfloat16* A1 = Wo + (size_t)(m0 + row1) * DM + colg0;
  const __hip_bfloat16* B0 = Cx + (size_t)(n0 + row0) * DM + colg0;
  const __hip_bfloat16* B1 = Cx + (size_t)(n0 + row1) * DM + colg0;
  __hip_bfloat16* AsW0 = As + w * 512;
  __hip_bfloat16* AsW1 = As + 2048 + w * 512;
  __hip_bfloat16* BsW0 = Bs + w * 512;
  __hip_bfloat16* BsW1 = Bs + 2048 + w * 512;

  floatx4 acc[4][4] = {};
#pragma unroll 2
  for (int k0 = 0; k0 < DM; k0 += 32) {
    gload_lds16(A0 + k0, AsW0);
    gload_lds16(A1 + k0, AsW1);
    gload_lds16(B0 + k0, BsW0);
    gload_lds16(B1 + k0, BsW1);
    __syncthreads();
    short8v a[4], b[4];
#pragma unroll
    for (int i = 0; i < 4; ++i)
      a[i] = *(const short8v*)&As[(wr * 64 + i * 16 + c) * 32 + g * 8];
#pragma unroll
    for (int j = 0; j < 4; ++j)
      b[j] = *(const short8v*)&Bs[(wc * 64 + j * 16 + c) * 32 + g * 8];
#pragma unroll
    for (int i = 0; i < 4; ++i)
#pragma unroll
      for (int j = 0; j < 4; ++j)
        acc[i][j] = __builtin_amdgcn_mfma_f32_16x16x32_bf16(a[i], b[j], acc[i][j], 0, 0, 0);
    __syncthreads();
  }
#pragma unroll
  for (int i = 0; i < 4; ++i) {
    const int e0 = m0 + wr * 64 + i * 16 + 4 * g;
#pragma unroll
    for (int j = 0; j < 4; ++j) {
      const int t = n0 + wc * 64 + j * 16 + c;
      *(floatx4*)&out[(size_t)t * DM + e0] = acc[i][j];
    }
  }
}

extern "C" void kernel_launch(void* const* d_in, const int* in_sizes, int n_in,
                              void* d_out, int out_size, void* d_ws, size_t ws_size,
                              hipStream_t stream) {
  const float* x    = (const float*)d_in[0];
  const int*   tpos = (const int*)d_in[1];
  const float* Wq   = (const float*)d_in[2];
  const float* Wo   = (const float*)d_in[3];
  float* out = (float*)d_out;

  const size_t QKV_BYTES = (size_t)NB * NH * SEQ * HD * 2;  // 6,291,456
  const size_t REQUIRED = 4 * QKV_BYTES;                    // 25,165,824
  if (ws_size < REQUIRED) return;

  char* ws = (char*)d_ws;
  __hip_bfloat16* Qb = (__hip_bfloat16*)(ws);
  __hip_bfloat16* Kb = (__hip_bfloat16*)(ws + QKV_BYTES);
  __hip_bfloat16* Vt = (__hip_bfloat16*)(ws + 2 * QKV_BYTES);
  __hip_bfloat16* Cx = (__hip_bfloat16*)(ws + 3 * QKV_BYTES);
  __hip_bfloat16* xb = (__hip_bfloat16*)(ws + 3 * QKV_BYTES);   // aliases Cx (dead before attn)
  char* ob = (char*)d_out;
  float2* rcs = (float2*)(ob);                                           // 512KB
  __hip_bfloat16* wqb = (__hip_bfloat16*)(ob + (size_t)SEQ * 32 * 8);    // 3.54MB
  __hip_bfloat16* wob = (__hip_bfloat16*)(ob + (size_t)SEQ * 32 * 8 + (size_t)E3 * DM * 2);  // 1.18MB

  const int CVT_N = XN4 + WQN4 + WON4;
  cvt3_bf16<<<dim3((CVT_N + 255) / 256), dim3(256), 0, stream>>>(x, Wq, Wo, xb, wqb, wob);
  rope_tab<<<dim3(SEQ * 32 / 256), dim3(256), 0, stream>>>(rcs);
  qkv_gemm_rope<<<dim3(576), dim3(256), 0, stream>>>(wqb, xb, tpos, rcs, Qb, Kb, Vt);
  attn_fused<<<dim3(1536), dim3(128), 0, stream>>>(Qb, Kb, Vt, Cx);
  out_gemm<<<dim3(32, 6), dim3(256), 0, stream>>>(wob, Cx, out);
}

// Round 13
// 110.423 us; speedup vs baseline: 1.2182x; 1.0806x over previous
//
#include <hip/hip_runtime.h>
#include <hip/hip_bf16.h>
#include <math.h>

#define SEQ 2048
#define DM 768
#define NH 12
#define HD 64
#define NB 2
#define NT (NB*SEQ)      // 4096 tokens
#define E3 (3*DM)        // 2304

using short4v = __attribute__((ext_vector_type(4))) short;
using short8v = __attribute__((ext_vector_type(8))) short;
using floatx4 = __attribute__((ext_vector_type(4))) float;
using int4v   = __attribute__((ext_vector_type(4))) int;

#if __has_builtin(__builtin_amdgcn_exp2f)
#define EXPFN(x) __builtin_amdgcn_exp2f(x)
#define QSCALE 0.1803368801111244f   /* 0.125 * log2(e) : scores in log2 domain */
#else
#define EXPFN(x) __expf(x)
#define QSCALE 0.125f
#endif

static __device__ __forceinline__ short bfb(float f) {
  union { __hip_bfloat16 h; short s; } u;
  u.h = __float2bfloat16(f);
  return u.s;
}

// async global->LDS, 16 bytes per lane. lds must be wave-uniform.
static __device__ __forceinline__ void gload_lds16(const __hip_bfloat16* g, __hip_bfloat16* lds) {
  __builtin_amdgcn_global_load_lds(
      (const __attribute__((address_space(1))) unsigned int*)g,
      (__attribute__((address_space(3))) unsigned int*)lds, 16, 0, 0);
}

// K granule swizzle (16B granules, 8 per 128B row): rows 8a+b -> (a+2b)&7
static __device__ __forceinline__ int swzg(int row) {
  return (((row >> 3) & 3) + 2 * (row & 3)) & 7;
}

// ---------------- fused fp32->bf16 convert (x, Wq, Wo) + rope table, one dispatch ----------------
#define XN4 (NT * DM / 4)          // 786432
#define WQN4 (E3 * DM / 4)         // 442368
#define WON4 (DM * DM / 4)         // 147456
#define CVT_N (XN4 + WQN4 + WON4)  // 1376256
__global__ void cvt3_rope(const float* __restrict__ x, const float* __restrict__ wq,
                          const float* __restrict__ wo,
                          __hip_bfloat16* __restrict__ xb, __hip_bfloat16* __restrict__ wqb,
                          __hip_bfloat16* __restrict__ wob, float2* __restrict__ rcs) {
  int i = blockIdx.x * blockDim.x + threadIdx.x;
  if (i >= CVT_N) {
    int idx = i - CVT_N;
    if (idx < SEQ * 32) {
      int pos = idx >> 5, j = idx & 31;
      float freq = __expf(-(float)j * (logf(10000.0f) / 32.0f));
      float ang = (float)pos * freq;
      rcs[idx] = make_float2(cosf(ang), sinf(ang));
    }
    return;
  }
  const float* src;
  __hip_bfloat16* dst;
  int k;
  if (i < XN4) { src = x; dst = xb; k = i; }
  else if (i < XN4 + WQN4) { src = wq; dst = wqb; k = i - XN4; }
  else { src = wo; dst = wob; k = i - XN4 - WQN4; }
  floatx4 v = ((const floatx4*)src)[k];
  short4v o;
  o[0] = bfb(v[0]); o[1] = bfb(v[1]); o[2] = bfb(v[2]); o[3] = bfb(v[3]);
  ((short4v*)dst)[k] = o;
}

// ---------------- QKV GEMM: m97 structure, BK=64 (half the barrier drains) ----------------
// 128x128 tile, 12 k-steps of K=64. LDS [128][64] per matrix, 16B-granule
// XOR swizzle (slot ^= row&7) applied at BOTH the global source and the read
// (rule #21) to break the 16-way conflict of 128B-stride ds_read_b128.
__global__ __launch_bounds__(256) void qkv_gemm_rope(
    const __hip_bfloat16* __restrict__ Wq,
    const __hip_bfloat16* __restrict__ Xb,
    const int* __restrict__ tpos,
    const float2* __restrict__ rcs,
    __hip_bfloat16* __restrict__ Qb, __hip_bfloat16* __restrict__ Kb,
    __hip_bfloat16* __restrict__ Vt)
{
  __shared__ __align__(16) __hip_bfloat16 As[128 * 64];  // 16KB
  __shared__ __align__(16) __hip_bfloat16 Bs[128 * 64];
  const int tid = threadIdx.x;
  const int lane = tid & 63, w = tid >> 6;
  const int c = lane & 15, g = lane >> 4;
  const int wr = w >> 1, wc = w & 1;
  const int bid = blockIdx.x;
  const int xcd = bid & 7, i_ = bid >> 3;
  const int nb = xcd * 4 + (i_ & 3), mb = i_ >> 2;
  const int m0 = mb * 128, n0 = nb * 128;
  const int srow = tid >> 3, sslot = tid & 7;   // staging: call j covers rows j*32+srow

  floatx4 acc[4][4] = {};
  for (int k0 = 0; k0 < DM; k0 += 64) {
#pragma unroll
    for (int j = 0; j < 4; ++j) {
      const int row = j * 32 + srow;
      const int gs = (sslot ^ (row & 7)) * 8;
      gload_lds16(Wq + (size_t)(m0 + row) * DM + k0 + gs, As + j * 2048 + w * 512);
      gload_lds16(Xb + (size_t)(n0 + row) * DM + k0 + gs, Bs + j * 2048 + w * 512);
    }
    __syncthreads();
#pragma unroll
    for (int kk = 0; kk < 2; ++kk) {
      short8v a[4], b[4];
#pragma unroll
      for (int i = 0; i < 4; ++i) {
        const int row = wr * 64 + i * 16 + c;
        a[i] = *(const short8v*)&As[row * 64 + (((kk * 4 + g) ^ (row & 7)) * 8)];
      }
#pragma unroll
      for (int j = 0; j < 4; ++j) {
        const int row = wc * 64 + j * 16 + c;
        b[j] = *(const short8v*)&Bs[row * 64 + (((kk * 4 + g) ^ (row & 7)) * 8)];
      }
#pragma unroll
      for (int i = 0; i < 4; ++i)
#pragma unroll
        for (int j = 0; j < 4; ++j)
          acc[i][j] = __builtin_amdgcn_mfma_f32_16x16x32_bf16(a[i], b[j], acc[i][j], 0, 0, 0);
    }
    __syncthreads();
  }
#pragma unroll
  for (int i = 0; i < 4; ++i) {
    const int e0 = m0 + wr * 64 + i * 16 + 4 * g;
    const int jj = (e0 & 63) >> 1;
#pragma unroll
    for (int j = 0; j < 4; ++j) {
      const int t = n0 + wc * 64 + j * 16 + c;
      const int b_ = t >> 11, s = t & (SEQ - 1);
      float v0 = acc[i][j][0], v1 = acc[i][j][1], v2 = acc[i][j][2], v3 = acc[i][j][3];
      if (e0 < 2 * DM) {
        const int pos = tpos[t];
        const float2 cs0 = rcs[pos * 32 + jj];
        const float2 cs1 = rcs[pos * 32 + jj + 1];
        const float n0v = v0 * cs0.x - v1 * cs0.y, n1v = v0 * cs0.y + v1 * cs0.x;
        const float n2v = v2 * cs1.x - v3 * cs1.y, n3v = v2 * cs1.y + v3 * cs1.x;
        v0 = n0v; v1 = n1v; v2 = n2v; v3 = n3v;
      }
      if (e0 < DM) {
        const int h = e0 >> 6, d = e0 & 63;
        short4v pk;
        pk[0] = bfb(v0 * QSCALE); pk[1] = bfb(v1 * QSCALE);
        pk[2] = bfb(v2 * QSCALE); pk[3] = bfb(v3 * QSCALE);
        *(short4v*)&Qb[(((size_t)(b_ * NH + h) * SEQ) + s) * HD + d] = pk;
      } else if (e0 < 2 * DM) {
        const int e = e0 - DM, h = e >> 6, d = e & 63;
        short4v pk;
        pk[0] = bfb(v0); pk[1] = bfb(v1); pk[2] = bfb(v2); pk[3] = bfb(v3);
        *(short4v*)&Kb[(((size_t)(b_ * NH + h) * SEQ) + s) * HD + d] = pk;
      } else {
        const int e = e0 - 2 * DM, h = e >> 6, d = e & 63;
        const size_t base = ((size_t)(b_ * NH + h) * HD + d) * SEQ + s;
        Vt[base]           = __float2bfloat16(v0);
        Vt[base + SEQ]     = __float2bfloat16(v1);
        Vt[base + 2 * SEQ] = __float2bfloat16(v2);
        Vt[base + 3 * SEQ] = __float2bfloat16(v3);
      }
    }
  }
}

// ---------------- fused causal flash attention v7 (R12, best-known: 47.4us) ----------------
__global__ __launch_bounds__(128) void attn_fused(
    const __hip_bfloat16* __restrict__ Qb,
    const __hip_bfloat16* __restrict__ Kb,
    const __hip_bfloat16* __restrict__ Vt,
    __hip_bfloat16* __restrict__ Cx)
{
  __shared__ __align__(16) __hip_bfloat16 Ks[2][32 * 64];  // 4KB each
  __shared__ __align__(16) __hip_bfloat16 Vs[2][64 * 32];  // V^T: [d][kt], 4KB each
  const int tid = threadIdx.x;
  const int lane = tid & 63, w = tid >> 6;
  const int c = lane & 15, g = lane >> 4;
  const int bid = blockIdx.x;
  const int xcd = bid & 7, i_ = bid >> 3;          // 192 per XCD
  const int bh = xcd + 8 * (i_ % 3);
  const int qg = 63 - i_ / 3;                      // 32-row group, descending
  const int KBmax = qg;                            // kb = 0..qg (32 keys each)
  const __hip_bfloat16* Qh = Qb + (size_t)bh * SEQ * HD;
  const __hip_bfloat16* Kh = Kb + (size_t)bh * SEQ * HD;
  const __hip_bfloat16* Vh = Vt + (size_t)bh * HD * SEQ;
  const int qrl = w * 16 + c;                      // q-row within the 32-row group
  const int q1 = qg * 32 + qrl;                    // absolute q-row
  const short8v qf10 = *(const short8v*)&Qh[(size_t)q1 * HD + g * 8];
  const short8v qf11 = *(const short8v*)&Qh[(size_t)q1 * HD + 32 + g * 8];
  floatx4 o1[4] = {};
  float l1 = 0.0f;
  const int kr1 = 8 * (c >> 2) + (c & 3);          // permuted A-row -> kt_local

  const int krow0 = w * 8 + (lane >> 3), kslot = lane & 7;
  const int vrow0 = w * 16 + (lane >> 2), vslot = lane & 3;

#define STAGE_KV(KB_, KSD, VSD)                                                    \
  do {                                                                             \
    _Pragma("unroll")                                                              \
    for (int j = 0; j < 2; ++j) {                                                  \
      const int kr = j * 16 + krow0;                                               \
      gload_lds16(Kh + (size_t)((KB_) * 32 + kr) * HD + ((kslot ^ swzg(kr)) * 8),  \
                  (KSD) + j * 1024 + w * 512);                                     \
      const int vr = j * 32 + vrow0;                                               \
      gload_lds16(Vh + (size_t)vr * SEQ + (KB_) * 32 + ((vslot ^ (vr & 3)) * 8),   \
                  (VSD) + j * 1024 + w * 512);                                     \
    }                                                                              \
  } while (0)

  STAGE_KV(0, Ks[0], Vs[0]);
  __syncthreads();
  int cb = 0;
  for (int kb = 0; kb <= KBmax; ++kb) {
    if (kb < KBmax) STAGE_KV(kb + 1, Ks[cb ^ 1], Vs[cb ^ 1]);
    {
      const __hip_bfloat16* Kt = Ks[cb];
      const __hip_bfloat16* Vb = Vs[cb];
      const int r0 = kr1, r1 = kr1 + 4;
      const int z0 = swzg(r0), z1 = swzg(r1);
      const short8v a00 = *(const short8v*)&Kt[r0 * 64 + ((g ^ z0) * 8)];
      const short8v a01 = *(const short8v*)&Kt[r0 * 64 + (((4 + g) ^ z0) * 8)];
      const short8v a10 = *(const short8v*)&Kt[r1 * 64 + ((g ^ z1) * 8)];
      const short8v a11 = *(const short8v*)&Kt[r1 * 64 + (((4 + g) ^ z1) * 8)];
      short8v vf[4];
#pragma unroll
      for (int f = 0; f < 4; ++f) {
        const int rv = f * 16 + c;
        vf[f] = *(const short8v*)&Vb[rv * 32 + ((g ^ (rv & 3)) * 8)];
      }
      floatx4 s1a = {}, s1b = {};
      s1a = __builtin_amdgcn_mfma_f32_16x16x32_bf16(a00, qf10, s1a, 0, 0, 0);
      s1a = __builtin_amdgcn_mfma_f32_16x16x32_bf16(a01, qf11, s1a, 0, 0, 0);
      s1b = __builtin_amdgcn_mfma_f32_16x16x32_bf16(a10, qf10, s1b, 0, 0, 0);
      s1b = __builtin_amdgcn_mfma_f32_16x16x32_bf16(a11, qf11, s1b, 0, 0, 0);
      if (kb == KBmax) {
#pragma unroll
        for (int r = 0; r < 4; ++r) {
          if (8 * g + r > qrl) s1a[r] = -INFINITY;
          if (8 * g + r + 4 > qrl) s1b[r] = -INFINITY;
        }
      }
      short8v pf1;
#pragma unroll
      for (int r = 0; r < 4; ++r) {
        float p;
        p = EXPFN(s1a[r]); l1 += p; pf1[r] = bfb(p);
        p = EXPFN(s1b[r]); l1 += p; pf1[r + 4] = bfb(p);
      }
      o1[0] = __builtin_amdgcn_mfma_f32_16x16x32_bf16(vf[0], pf1, o1[0], 0, 0, 0);
      o1[1] = __builtin_amdgcn_mfma_f32_16x16x32_bf16(vf[1], pf1, o1[1], 0, 0, 0);
      o1[2] = __builtin_amdgcn_mfma_f32_16x16x32_bf16(vf[2], pf1, o1[2], 0, 0, 0);
      o1[3] = __builtin_amdgcn_mfma_f32_16x16x32_bf16(vf[3], pf1, o1[3], 0, 0, 0);
    }
    __syncthreads();
    cb ^= 1;
  }
#undef STAGE_KV

  l1 += __shfl_xor(l1, 16); l1 += __shfl_xor(l1, 32);
  const float inv1 = 1.0f / l1;
  const int bb = bh / NH, h = bh - bb * NH;
  const size_t trow1 = ((size_t)bb * SEQ + q1) * DM + (size_t)h * HD;
#pragma unroll
  for (int f = 0; f < 4; ++f) {
    short4v pk1;
#pragma unroll
    for (int r = 0; r < 4; ++r) pk1[r] = bfb(o1[f][r] * inv1);
    *(short4v*)&Cx[trow1 + f * 16 + 4 * g] = pk1;
  }
}

// ---------------- output GEMM: m97 structure, BK=64 ----------------
__global__ __launch_bounds__(256) void out_gemm(
    const __hip_bfloat16* __restrict__ Wo,
    const __hip_bfloat16* __restrict__ Cx,
    float* __restrict__ out)
{
  __shared__ __align__(16) __hip_bfloat16 As[128 * 64];
  __shared__ __align__(16) __hip_bfloat16 Bs[128 * 64];
  const int tid = threadIdx.x;
  const int lane = tid & 63, w = tid >> 6;
  const int c = lane & 15, g = lane >> 4;
  const int wr = w >> 1, wc = w & 1;
  const int m0 = blockIdx.y * 128;   // e-block (6)
  const int n0 = blockIdx.x * 128;   // t-block (32)
  const int srow = tid >> 3, sslot = tid & 7;

  floatx4 acc[4][4] = {};
  for (int k0 = 0; k0 < DM; k0 += 64) {
#pragma unroll
    for (int j = 0; j < 4; ++j) {
      const int row = j * 32 + srow;
      const int gs = (sslot ^ (row & 7)) * 8;
      gload_lds16(Wo + (size_t)(m0 + row) * DM + k0 + gs, As + j * 2048 + w * 512);
      gload_lds16(Cx + (size_t)(n0 + row) * DM + k0 + gs, Bs + j * 2048 + w * 512);
    }
    __syncthreads();
#pragma unroll
    for (int kk = 0; kk < 2; ++kk) {
      short8v a[4], b[4];
#pragma unroll
      for (int i = 0; i < 4; ++i) {
        const int row = wr * 64 + i * 16 + c;
        a[i] = *(const short8v*)&As[row * 64 + (((kk * 4 + g) ^ (row & 7)) * 8)];
      }
#pragma unroll
      for (int j = 0; j < 4; ++j) {
        const int row = wc * 64 + j * 16 + c;
        b[j] = *(const short8v*)&Bs[row * 64 + (((kk * 4 + g) ^ (row & 7)) * 8)];
      }
#pragma unroll
      for (int i = 0; i < 4; ++i)
#pragma unroll
        for (int j = 0; j < 4; ++j)
          acc[i][j] = __builtin_amdgcn_mfma_f32_16x16x32_bf16(a[i], b[j], acc[i][j], 0, 0, 0);
    }
    __syncthreads();
  }
#pragma unroll
  for (int i = 0; i < 4; ++i) {
    const int e0 = m0 + wr * 64 + i * 16 + 4 * g;
#pragma unroll
    for (int j = 0; j < 4; ++j) {
      const int t = n0 + wc * 64 + j * 16 + c;
      *(floatx4*)&out[(size_t)t * DM + e0] = acc[i][j];
    }
  }
}

extern "C" void kernel_launch(void* const* d_in, const int* in_sizes, int n_in,
                              void* d_out, int out_size, void* d_ws, size_t ws_size,
                              hipStream_t stream) {
  const float* x    = (const float*)d_in[0];
  const int*   tpos = (const int*)d_in[1];
  const float* Wq   = (const float*)d_in[2];
  const float* Wo   = (const float*)d_in[3];
  float* out = (float*)d_out;

  const size_t QKV_BYTES = (size_t)NB * NH * SEQ * HD * 2;  // 6,291,456
  const size_t REQUIRED = 4 * QKV_BYTES;                    // 25,165,824
  if (ws_size < REQUIRED) return;

  char* ws = (char*)d_ws;
  __hip_bfloat16* Qb = (__hip_bfloat16*)(ws);
  __hip_bfloat16* Kb = (__hip_bfloat16*)(ws + QKV_BYTES);
  __hip_bfloat16* Vt = (__hip_bfloat16*)(ws + 2 * QKV_BYTES);
  __hip_bfloat16* Cx = (__hip_bfloat16*)(ws + 3 * QKV_BYTES);
  __hip_bfloat16* xb = (__hip_bfloat16*)(ws + 3 * QKV_BYTES);   // aliases Cx (dead before attn)
  char* ob = (char*)d_out;
  float2* rcs = (float2*)(ob);                                           // 512KB
  __hip_bfloat16* wqb = (__hip_bfloat16*)(ob + (size_t)SEQ * 32 * 8);    // 3.54MB
  __hip_bfloat16* wob = (__hip_bfloat16*)(ob + (size_t)SEQ * 32 * 8 + (size_t)E3 * DM * 2);  // 1.18MB

  const int TOT_N = CVT_N + SEQ * 32;
  cvt3_rope<<<dim3((TOT_N + 255) / 256), dim3(256), 0, stream>>>(x, Wq, Wo, xb, wqb, wob, rcs);
  qkv_gemm_rope<<<dim3(576), dim3(256), 0, stream>>>(wqb, xb, tpos, rcs, Qb, Kb, Vt);
  attn_fused<<<dim3(1536), dim3(128), 0, stream>>>(Qb, Kb, Vt, Cx);
  out_gemm<<<dim3(32, 6), dim3(256), 0, stream>>>(wob, Cx, out);
}

// Round 14
// 103.686 us; speedup vs baseline: 1.2974x; 1.0650x over previous
//
#include <hip/hip_runtime.h>
#include <hip/hip_bf16.h>
#include <math.h>

#define SEQ 2048
#define DM 768
#define NH 12
#define HD 64
#define NB 2
#define NT (NB*SEQ)      // 4096 tokens
#define E3 (3*DM)        // 2304

using short4v = __attribute__((ext_vector_type(4))) short;
using short8v = __attribute__((ext_vector_type(8))) short;
using floatx4 = __attribute__((ext_vector_type(4))) float;
using int4v   = __attribute__((ext_vector_type(4))) int;

#if __has_builtin(__builtin_amdgcn_exp2f)
#define EXPFN(x) __builtin_amdgcn_exp2f(x)
#define QSCALE 0.1803368801111244f   /* 0.125 * log2(e) : scores in log2 domain */
#else
#define EXPFN(x) __expf(x)
#define QSCALE 0.125f
#endif

static __device__ __forceinline__ short bfb(float f) {
  union { __hip_bfloat16 h; short s; } u;
  u.h = __float2bfloat16(f);
  return u.s;
}

// async global->LDS, 16 bytes per lane. lds must be wave-uniform.
static __device__ __forceinline__ void gload_lds16(const __hip_bfloat16* g, __hip_bfloat16* lds) {
  __builtin_amdgcn_global_load_lds(
      (const __attribute__((address_space(1))) unsigned int*)g,
      (__attribute__((address_space(3))) unsigned int*)lds, 16, 0, 0);
}

// K granule swizzle (16B granules, 8 per 128B row): rows 8a+b -> (a+2b)&7
static __device__ __forceinline__ int swzg(int row) {
  return (((row >> 3) & 3) + 2 * (row & 3)) & 7;
}

// ---------------- fused fp32->bf16 convert (x, Wq, Wo) + rope table, one dispatch ----------------
#define XN4 (NT * DM / 4)          // 786432
#define WQN4 (E3 * DM / 4)         // 442368
#define WON4 (DM * DM / 4)         // 147456
#define CVT_N (XN4 + WQN4 + WON4)  // 1376256
__global__ void cvt3_rope(const float* __restrict__ x, const float* __restrict__ wq,
                          const float* __restrict__ wo,
                          __hip_bfloat16* __restrict__ xb, __hip_bfloat16* __restrict__ wqb,
                          __hip_bfloat16* __restrict__ wob, float2* __restrict__ rcs) {
  int i = blockIdx.x * blockDim.x + threadIdx.x;
  if (i >= CVT_N) {
    int idx = i - CVT_N;
    if (idx < SEQ * 32) {
      int pos = idx >> 5, j = idx & 31;
      float freq = __expf(-(float)j * (logf(10000.0f) / 32.0f));
      float ang = (float)pos * freq;
      rcs[idx] = make_float2(cosf(ang), sinf(ang));
    }
    return;
  }
  const float* src;
  __hip_bfloat16* dst;
  int k;
  if (i < XN4) { src = x; dst = xb; k = i; }
  else if (i < XN4 + WQN4) { src = wq; dst = wqb; k = i - XN4; }
  else { src = wo; dst = wob; k = i - XN4 - WQN4; }
  floatx4 v = ((const floatx4*)src)[k];
  short4v o;
  o[0] = bfb(v[0]); o[1] = bfb(v[1]); o[2] = bfb(v[2]); o[3] = bfb(v[3]);
  ((short4v*)dst)[k] = o;
}

// ---------------- QKV GEMM: m97 structure, BK=64 (R13, proven) ----------------
__global__ __launch_bounds__(256) void qkv_gemm_rope(
    const __hip_bfloat16* __restrict__ Wq,
    const __hip_bfloat16* __restrict__ Xb,
    const int* __restrict__ tpos,
    const float2* __restrict__ rcs,
    __hip_bfloat16* __restrict__ Qb, __hip_bfloat16* __restrict__ Kb,
    __hip_bfloat16* __restrict__ Vt)
{
  __shared__ __align__(16) __hip_bfloat16 As[128 * 64];  // 16KB
  __shared__ __align__(16) __hip_bfloat16 Bs[128 * 64];
  const int tid = threadIdx.x;
  const int lane = tid & 63, w = tid >> 6;
  const int c = lane & 15, g = lane >> 4;
  const int wr = w >> 1, wc = w & 1;
  const int bid = blockIdx.x;
  const int xcd = bid & 7, i_ = bid >> 3;
  const int nb = xcd * 4 + (i_ & 3), mb = i_ >> 2;
  const int m0 = mb * 128, n0 = nb * 128;
  const int srow = tid >> 3, sslot = tid & 7;

  floatx4 acc[4][4] = {};
  for (int k0 = 0; k0 < DM; k0 += 64) {
#pragma unroll
    for (int j = 0; j < 4; ++j) {
      const int row = j * 32 + srow;
      const int gs = (sslot ^ (row & 7)) * 8;
      gload_lds16(Wq + (size_t)(m0 + row) * DM + k0 + gs, As + j * 2048 + w * 512);
      gload_lds16(Xb + (size_t)(n0 + row) * DM + k0 + gs, Bs + j * 2048 + w * 512);
    }
    __syncthreads();
#pragma unroll
    for (int kk = 0; kk < 2; ++kk) {
      short8v a[4], b[4];
#pragma unroll
      for (int i = 0; i < 4; ++i) {
        const int row = wr * 64 + i * 16 + c;
        a[i] = *(const short8v*)&As[row * 64 + (((kk * 4 + g) ^ (row & 7)) * 8)];
      }
#pragma unroll
      for (int j = 0; j < 4; ++j) {
        const int row = wc * 64 + j * 16 + c;
        b[j] = *(const short8v*)&Bs[row * 64 + (((kk * 4 + g) ^ (row & 7)) * 8)];
      }
#pragma unroll
      for (int i = 0; i < 4; ++i)
#pragma unroll
        for (int j = 0; j < 4; ++j)
          acc[i][j] = __builtin_amdgcn_mfma_f32_16x16x32_bf16(a[i], b[j], acc[i][j], 0, 0, 0);
    }
    __syncthreads();
  }
#pragma unroll
  for (int i = 0; i < 4; ++i) {
    const int e0 = m0 + wr * 64 + i * 16 + 4 * g;
    const int jj = (e0 & 63) >> 1;
#pragma unroll
    for (int j = 0; j < 4; ++j) {
      const int t = n0 + wc * 64 + j * 16 + c;
      const int b_ = t >> 11, s = t & (SEQ - 1);
      float v0 = acc[i][j][0], v1 = acc[i][j][1], v2 = acc[i][j][2], v3 = acc[i][j][3];
      if (e0 < 2 * DM) {
        const int pos = tpos[t];
        const float2 cs0 = rcs[pos * 32 + jj];
        const float2 cs1 = rcs[pos * 32 + jj + 1];
        const float n0v = v0 * cs0.x - v1 * cs0.y, n1v = v0 * cs0.y + v1 * cs0.x;
        const float n2v = v2 * cs1.x - v3 * cs1.y, n3v = v2 * cs1.y + v3 * cs1.x;
        v0 = n0v; v1 = n1v; v2 = n2v; v3 = n3v;
      }
      if (e0 < DM) {
        const int h = e0 >> 6, d = e0 & 63;
        short4v pk;
        pk[0] = bfb(v0 * QSCALE); pk[1] = bfb(v1 * QSCALE);
        pk[2] = bfb(v2 * QSCALE); pk[3] = bfb(v3 * QSCALE);
        *(short4v*)&Qb[(((size_t)(b_ * NH + h) * SEQ) + s) * HD + d] = pk;
      } else if (e0 < 2 * DM) {
        const int e = e0 - DM, h = e >> 6, d = e & 63;
        short4v pk;
        pk[0] = bfb(v0); pk[1] = bfb(v1); pk[2] = bfb(v2); pk[3] = bfb(v3);
        *(short4v*)&Kb[(((size_t)(b_ * NH + h) * SEQ) + s) * HD + d] = pk;
      } else {
        const int e = e0 - 2 * DM, h = e >> 6, d = e & 63;
        const size_t base = ((size_t)(b_ * NH + h) * HD + d) * SEQ + s;
        Vt[base]           = __float2bfloat16(v0);
        Vt[base + SEQ]     = __float2bfloat16(v1);
        Vt[base + 2 * SEQ] = __float2bfloat16(v2);
        Vt[base + 3 * SEQ] = __float2bfloat16(v3);
      }
    }
  }
}

// ---------------- fused causal flash attention v8: shared-stage, KVBLK=64 ----------------
// Block = 4 waves x 16 q-rows = 64 q-rows sharing ONE K/V stage (L2 traffic
// halves vs v7) with KVBLK=64 (drains per key /2 again). 768 blocks (24 bh x
// 32 groups, descending), 12 waves/CU nominal, LDS 32KB -> 3 blocks/CU.
// Wave grain stays 16 rows (v7's proven win). m==0 softmax (exact).
__global__ __launch_bounds__(256) void attn_fused(
    const __hip_bfloat16* __restrict__ Qb,
    const __hip_bfloat16* __restrict__ Kb,
    const __hip_bfloat16* __restrict__ Vt,
    __hip_bfloat16* __restrict__ Cx)
{
  __shared__ __align__(16) __hip_bfloat16 Ks[2][64 * 64];  // 8KB each
  __shared__ __align__(16) __hip_bfloat16 Vs[2][64 * 64];  // V^T: [d][kt], 8KB each
  const int tid = threadIdx.x;
  const int lane = tid & 63, w = tid >> 6;
  const int c = lane & 15, g = lane >> 4;
  const int bid = blockIdx.x;
  const int xcd = bid & 7, i_ = bid >> 3;          // 96 per XCD
  const int bh = xcd + 8 * (i_ % 3);
  const int qb = 31 - i_ / 3;                      // 64-row group, descending
  const int KBmax = qb;                            // kb = 0..qb (64 keys each)
  const __hip_bfloat16* Qh = Qb + (size_t)bh * SEQ * HD;
  const __hip_bfloat16* Kh = Kb + (size_t)bh * SEQ * HD;
  const __hip_bfloat16* Vh = Vt + (size_t)bh * HD * SEQ;
  const int q1 = qb * 64 + w * 16 + c;             // absolute q-row of this lane
  const int qt_w = 2 * qb + (w >> 1);              // wave's causal 32-key sub-block limit
  const int qrl32 = (w & 1) * 16 + c;              // row within the diagonal 32-key window
  const short8v qf10 = *(const short8v*)&Qh[(size_t)q1 * HD + g * 8];
  const short8v qf11 = *(const short8v*)&Qh[(size_t)q1 * HD + 32 + g * 8];
  floatx4 o1[4] = {};
  float l1 = 0.0f;
  const int kr1 = 8 * (c >> 2) + (c & 3);          // permuted A-row -> kt_local

  // staging: K 512 granules (64 rows x 8), V 512 granules (64 rows x 8);
  // call j covers granules j*256 + w*64 + lane -> row j*32 + w*8 + (lane>>3).
  const int srow = w * 8 + (lane >> 3), sslot = lane & 7;

#define STAGE_KV(KB_, KSD, VSD)                                                     \
  do {                                                                              \
    _Pragma("unroll")                                                               \
    for (int j = 0; j < 2; ++j) {                                                   \
      const int kr = j * 32 + srow;                                                 \
      gload_lds16(Kh + (size_t)((KB_) * 64 + kr) * HD + ((sslot ^ swzg(kr)) * 8),   \
                  (KSD) + j * 2048 + w * 512);                                      \
      gload_lds16(Vh + (size_t)kr * SEQ + (KB_) * 64 + ((sslot ^ (kr & 7)) * 8),    \
                  (VSD) + j * 2048 + w * 512);                                      \
    }                                                                               \
  } while (0)

  STAGE_KV(0, Ks[0], Vs[0]);
  __syncthreads();
  int cb = 0;
  for (int kb = 0; kb <= KBmax; ++kb) {
    if (kb < KBmax) STAGE_KV(kb + 1, Ks[cb ^ 1], Vs[cb ^ 1]);
    {
      const __hip_bfloat16* Kt = Ks[cb];
      const __hip_bfloat16* Vb = Vs[cb];
#pragma unroll
      for (int s = 0; s < 2; ++s) {
        const int kidx = 2 * kb + s;
        if (kidx <= qt_w) {
          const int r0 = s * 32 + kr1, r1 = r0 + 4;
          const int z0 = swzg(r0), z1 = swzg(r1);
          const short8v a00 = *(const short8v*)&Kt[r0 * 64 + ((g ^ z0) * 8)];
          const short8v a01 = *(const short8v*)&Kt[r0 * 64 + (((4 + g) ^ z0) * 8)];
          const short8v a10 = *(const short8v*)&Kt[r1 * 64 + ((g ^ z1) * 8)];
          const short8v a11 = *(const short8v*)&Kt[r1 * 64 + (((4 + g) ^ z1) * 8)];
          short8v vf[4];
#pragma unroll
          for (int f = 0; f < 4; ++f) {
            const int rv = f * 16 + c;
            vf[f] = *(const short8v*)&Vb[rv * 64 + (((s * 4 + g) ^ (rv & 7)) * 8)];
          }
          floatx4 s1a = {}, s1b = {};
          s1a = __builtin_amdgcn_mfma_f32_16x16x32_bf16(a00, qf10, s1a, 0, 0, 0);
          s1a = __builtin_amdgcn_mfma_f32_16x16x32_bf16(a01, qf11, s1a, 0, 0, 0);
          s1b = __builtin_amdgcn_mfma_f32_16x16x32_bf16(a10, qf10, s1b, 0, 0, 0);
          s1b = __builtin_amdgcn_mfma_f32_16x16x32_bf16(a11, qf11, s1b, 0, 0, 0);
          if (kidx == qt_w) {  // diagonal 32-key window: mask keys > own row
#pragma unroll
            for (int r = 0; r < 4; ++r) {
              if (8 * g + r > qrl32) s1a[r] = -INFINITY;
              if (8 * g + r + 4 > qrl32) s1b[r] = -INFINITY;
            }
          }
          short8v pf1;
#pragma unroll
          for (int r = 0; r < 4; ++r) {
            float p;
            p = EXPFN(s1a[r]); l1 += p; pf1[r] = bfb(p);
            p = EXPFN(s1b[r]); l1 += p; pf1[r + 4] = bfb(p);
          }
          o1[0] = __builtin_amdgcn_mfma_f32_16x16x32_bf16(vf[0], pf1, o1[0], 0, 0, 0);
          o1[1] = __builtin_amdgcn_mfma_f32_16x16x32_bf16(vf[1], pf1, o1[1], 0, 0, 0);
          o1[2] = __builtin_amdgcn_mfma_f32_16x16x32_bf16(vf[2], pf1, o1[2], 0, 0, 0);
          o1[3] = __builtin_amdgcn_mfma_f32_16x16x32_bf16(vf[3], pf1, o1[3], 0, 0, 0);
        }
      }
    }
    __syncthreads();
    cb ^= 1;
  }
#undef STAGE_KV

  l1 += __shfl_xor(l1, 16); l1 += __shfl_xor(l1, 32);
  const float inv1 = 1.0f / l1;
  const int bb = bh / NH, h = bh - bb * NH;
  const size_t trow1 = ((size_t)bb * SEQ + q1) * DM + (size_t)h * HD;
#pragma unroll
  for (int f = 0; f < 4; ++f) {
    short4v pk1;
#pragma unroll
    for (int r = 0; r < 4; ++r) pk1[r] = bfb(o1[f][r] * inv1);
    *(short4v*)&Cx[trow1 + f * 16 + 4 * g] = pk1;
  }
}

// ---------------- output GEMM: m97 structure, BK=64 (R13, proven) ----------------
__global__ __launch_bounds__(256) void out_gemm(
    const __hip_bfloat16* __restrict__ Wo,
    const __hip_bfloat16* __restrict__ Cx,
    float* __restrict__ out)
{
  __shared__ __align__(16) __hip_bfloat16 As[128 * 64];
  __shared__ __align__(16) __hip_bfloat16 Bs[128 * 64];
  const int tid = threadIdx.x;
  const int lane = tid & 63, w = tid >> 6;
  const int c = lane & 15, g = lane >> 4;
  const int wr = w >> 1, wc = w & 1;
  const int m0 = blockIdx.y * 128;   // e-block (6)
  const int n0 = blockIdx.x * 128;   // t-block (32)
  const int srow = tid >> 3, sslot = tid & 7;

  floatx4 acc[4][4] = {};
  for (int k0 = 0; k0 < DM; k0 += 64) {
#pragma unroll
    for (int j = 0; j < 4; ++j) {
      const int row = j * 32 + srow;
      const int gs = (sslot ^ (row & 7)) * 8;
      gload_lds16(Wo + (size_t)(m0 + row) * DM + k0 + gs, As + j * 2048 + w * 512);
      gload_lds16(Cx + (size_t)(n0 + row) * DM + k0 + gs, Bs + j * 2048 + w * 512);
    }
    __syncthreads();
#pragma unroll
    for (int kk = 0; kk < 2; ++kk) {
      short8v a[4], b[4];
#pragma unroll
      for (int i = 0; i < 4; ++i) {
        const int row = wr * 64 + i * 16 + c;
        a[i] = *(const short8v*)&As[row * 64 + (((kk * 4 + g) ^ (row & 7)) * 8)];
      }
#pragma unroll
      for (int j = 0; j < 4; ++j) {
        const int row = wc * 64 + j * 16 + c;
        b[j] = *(const short8v*)&Bs[row * 64 + (((kk * 4 + g) ^ (row & 7)) * 8)];
      }
#pragma unroll
      for (int i = 0; i < 4; ++i)
#pragma unroll
        for (int j = 0; j < 4; ++j)
          acc[i][j] = __builtin_amdgcn_mfma_f32_16x16x32_bf16(a[i], b[j], acc[i][j], 0, 0, 0);
    }
    __syncthreads();
  }
#pragma unroll
  for (int i = 0; i < 4; ++i) {
    const int e0 = m0 + wr * 64 + i * 16 + 4 * g;
#pragma unroll
    for (int j = 0; j < 4; ++j) {
      const int t = n0 + wc * 64 + j * 16 + c;
      *(floatx4*)&out[(size_t)t * DM + e0] = acc[i][j];
    }
  }
}

extern "C" void kernel_launch(void* const* d_in, const int* in_sizes, int n_in,
                              void* d_out, int out_size, void* d_ws, size_t ws_size,
                              hipStream_t stream) {
  const float* x    = (const float*)d_in[0];
  const int*   tpos = (const int*)d_in[1];
  const float* Wq   = (const float*)d_in[2];
  const float* Wo   = (const float*)d_in[3];
  float* out = (float*)d_out;

  const size_t QKV_BYTES = (size_t)NB * NH * SEQ * HD * 2;  // 6,291,456
  const size_t REQUIRED = 4 * QKV_BYTES;                    // 25,165,824
  if (ws_size < REQUIRED) return;

  char* ws = (char*)d_ws;
  __hip_bfloat16* Qb = (__hip_bfloat16*)(ws);
  __hip_bfloat16* Kb = (__hip_bfloat16*)(ws + QKV_BYTES);
  __hip_bfloat16* Vt = (__hip_bfloat16*)(ws + 2 * QKV_BYTES);
  __hip_bfloat16* Cx = (__hip_bfloat16*)(ws + 3 * QKV_BYTES);
  __hip_bfloat16* xb = (__hip_bfloat16*)(ws + 3 * QKV_BYTES);   // aliases Cx (dead before attn)
  char* ob = (char*)d_out;
  float2* rcs = (float2*)(ob);                                           // 512KB
  __hip_bfloat16* wqb = (__hip_bfloat16*)(ob + (size_t)SEQ * 32 * 8);    // 3.54MB
  __hip_bfloat16* wob = (__hip_bfloat16*)(ob + (size_t)SEQ * 32 * 8 + (size_t)E3 * DM * 2);  // 1.18MB

  const int TOT_N = CVT_N + SEQ * 32;
  cvt3_rope<<<dim3((TOT_N + 255) / 256), dim3(256), 0, stream>>>(x, Wq, Wo, xb, wqb, wob, rcs);
  qkv_gemm_rope<<<dim3(576), dim3(256), 0, stream>>>(wqb, xb, tpos, rcs, Qb, Kb, Vt);
  attn_fused<<<dim3(768), dim3(256), 0, stream>>>(Qb, Kb, Vt, Cx);
  out_gemm<<<dim3(32, 6), dim3(256), 0, stream>>>(wob, Cx, out);
}

// Round 15
// 98.321 us; speedup vs baseline: 1.3682x; 1.0546x over previous
//
#include <hip/hip_runtime.h>
#include <hip/hip_bf16.h>
#include <math.h>

#define SEQ 2048
#define DM 768
#define NH 12
#define HD 64
#define NB 2
#define NT (NB*SEQ)      // 4096 tokens
#define E3 (3*DM)        // 2304

using short4v = __attribute__((ext_vector_type(4))) short;
using short8v = __attribute__((ext_vector_type(8))) short;
using floatx4 = __attribute__((ext_vector_type(4))) float;
using int4v   = __attribute__((ext_vector_type(4))) int;

#if __has_builtin(__builtin_amdgcn_exp2f)
#define EXPFN(x) __builtin_amdgcn_exp2f(x)
#define QSCALE 0.1803368801111244f   /* 0.125 * log2(e) : scores in log2 domain */
#else
#define EXPFN(x) __expf(x)
#define QSCALE 0.125f
#endif

static __device__ __forceinline__ short bfb(float f) {
  union { __hip_bfloat16 h; short s; } u;
  u.h = __float2bfloat16(f);
  return u.s;
}

// async global->LDS, 16 bytes per lane. lds must be wave-uniform.
static __device__ __forceinline__ void gload_lds16(const __hip_bfloat16* g, __hip_bfloat16* lds) {
  __builtin_amdgcn_global_load_lds(
      (const __attribute__((address_space(1))) unsigned int*)g,
      (__attribute__((address_space(3))) unsigned int*)lds, 16, 0, 0);
}

// K granule swizzle (16B granules, 8 per 128B row): rows 8a+b -> (a+2b)&7
static __device__ __forceinline__ int swzg(int row) {
  return (((row >> 3) & 3) + 2 * (row & 3)) & 7;
}

// ---------------- fused fp32->bf16 convert (x, Wq, Wo) + rope table, one dispatch ----------------
#define XN4 (NT * DM / 4)          // 786432
#define WQN4 (E3 * DM / 4)         // 442368
#define WON4 (DM * DM / 4)         // 147456
#define CVT_N (XN4 + WQN4 + WON4)  // 1376256
__global__ void cvt3_rope(const float* __restrict__ x, const float* __restrict__ wq,
                          const float* __restrict__ wo,
                          __hip_bfloat16* __restrict__ xb, __hip_bfloat16* __restrict__ wqb,
                          __hip_bfloat16* __restrict__ wob, float2* __restrict__ rcs) {
  int i = blockIdx.x * blockDim.x + threadIdx.x;
  if (i >= CVT_N) {
    int idx = i - CVT_N;
    if (idx < SEQ * 32) {
      int pos = idx >> 5, j = idx & 31;
      float freq = __expf(-(float)j * (logf(10000.0f) / 32.0f));
      float ang = (float)pos * freq;
      rcs[idx] = make_float2(cosf(ang), sinf(ang));
    }
    return;
  }
  const float* src;
  __hip_bfloat16* dst;
  int k;
  if (i < XN4) { src = x; dst = xb; k = i; }
  else if (i < XN4 + WQN4) { src = wq; dst = wqb; k = i - XN4; }
  else { src = wo; dst = wob; k = i - XN4 - WQN4; }
  floatx4 v = ((const floatx4*)src)[k];
  short4v o;
  o[0] = bfb(v[0]); o[1] = bfb(v[1]); o[2] = bfb(v[2]); o[3] = bfb(v[3]);
  ((short4v*)dst)[k] = o;
}

// ---------------- QKV GEMM v2: 64x128 tile, BK=64 -> 1152 blocks (4.5/CU) ----------------
// Latency/drain-bound regime fix: double the independent barrier groups per CU
// (m102 block-count curve). Wave grid 2(M)x2(N), wave owns 32x64 = acc[2][4];
// LDS-read:MFMA ratio identical to the 128^2 tile. LDS 24KB.
__global__ __launch_bounds__(256) void qkv_gemm_rope(
    const __hip_bfloat16* __restrict__ Wq,
    const __hip_bfloat16* __restrict__ Xb,
    const int* __restrict__ tpos,
    const float2* __restrict__ rcs,
    __hip_bfloat16* __restrict__ Qb, __hip_bfloat16* __restrict__ Kb,
    __hip_bfloat16* __restrict__ Vt)
{
  __shared__ __align__(16) __hip_bfloat16 As[64 * 64];    // 8KB
  __shared__ __align__(16) __hip_bfloat16 Bs[128 * 64];   // 16KB
  const int tid = threadIdx.x;
  const int lane = tid & 63, w = tid >> 6;
  const int c = lane & 15, g = lane >> 4;
  const int wr = w >> 1, wc = w & 1;
  const int bid = blockIdx.x;
  const int xcd = bid & 7, i_ = bid >> 3;        // 144 per XCD
  const int nb = xcd * 4 + (i_ & 3), mb = i_ >> 2;  // nb 0..31, mb 0..35
  const int m0 = mb * 64, n0 = nb * 128;
  const int srow = tid >> 3, sslot = tid & 7;    // 32 rows per staging round

  floatx4 acc[2][4] = {};
  for (int k0 = 0; k0 < DM; k0 += 64) {
    // A: 64 rows = 2 rounds; B: 128 rows = 4 rounds
#pragma unroll
    for (int j = 0; j < 2; ++j) {
      const int row = j * 32 + srow;
      const int gs = (sslot ^ (row & 7)) * 8;
      gload_lds16(Wq + (size_t)(m0 + row) * DM + k0 + gs, As + j * 2048 + w * 512);
    }
#pragma unroll
    for (int j = 0; j < 4; ++j) {
      const int row = j * 32 + srow;
      const int gs = (sslot ^ (row & 7)) * 8;
      gload_lds16(Xb + (size_t)(n0 + row) * DM + k0 + gs, Bs + j * 2048 + w * 512);
    }
    __syncthreads();
#pragma unroll
    for (int kk = 0; kk < 2; ++kk) {
      short8v a[2], b[4];
#pragma unroll
      for (int i = 0; i < 2; ++i) {
        const int row = wr * 32 + i * 16 + c;
        a[i] = *(const short8v*)&As[row * 64 + (((kk * 4 + g) ^ (row & 7)) * 8)];
      }
#pragma unroll
      for (int j = 0; j < 4; ++j) {
        const int row = wc * 64 + j * 16 + c;
        b[j] = *(const short8v*)&Bs[row * 64 + (((kk * 4 + g) ^ (row & 7)) * 8)];
      }
#pragma unroll
      for (int i = 0; i < 2; ++i)
#pragma unroll
        for (int j = 0; j < 4; ++j)
          acc[i][j] = __builtin_amdgcn_mfma_f32_16x16x32_bf16(a[i], b[j], acc[i][j], 0, 0, 0);
    }
    __syncthreads();
  }
#pragma unroll
  for (int i = 0; i < 2; ++i) {
    const int e0 = m0 + wr * 32 + i * 16 + 4 * g;
    const int jj = (e0 & 63) >> 1;
#pragma unroll
    for (int j = 0; j < 4; ++j) {
      const int t = n0 + wc * 64 + j * 16 + c;
      const int b_ = t >> 11, s = t & (SEQ - 1);
      float v0 = acc[i][j][0], v1 = acc[i][j][1], v2 = acc[i][j][2], v3 = acc[i][j][3];
      if (e0 < 2 * DM) {
        const int pos = tpos[t];
        const float2 cs0 = rcs[pos * 32 + jj];
        const float2 cs1 = rcs[pos * 32 + jj + 1];
        const float n0v = v0 * cs0.x - v1 * cs0.y, n1v = v0 * cs0.y + v1 * cs0.x;
        const float n2v = v2 * cs1.x - v3 * cs1.y, n3v = v2 * cs1.y + v3 * cs1.x;
        v0 = n0v; v1 = n1v; v2 = n2v; v3 = n3v;
      }
      if (e0 < DM) {
        const int h = e0 >> 6, d = e0 & 63;
        short4v pk;
        pk[0] = bfb(v0 * QSCALE); pk[1] = bfb(v1 * QSCALE);
        pk[2] = bfb(v2 * QSCALE); pk[3] = bfb(v3 * QSCALE);
        *(short4v*)&Qb[(((size_t)(b_ * NH + h) * SEQ) + s) * HD + d] = pk;
      } else if (e0 < 2 * DM) {
        const int e = e0 - DM, h = e >> 6, d = e & 63;
        short4v pk;
        pk[0] = bfb(v0); pk[1] = bfb(v1); pk[2] = bfb(v2); pk[3] = bfb(v3);
        *(short4v*)&Kb[(((size_t)(b_ * NH + h) * SEQ) + s) * HD + d] = pk;
      } else {
        const int e = e0 - 2 * DM, h = e >> 6, d = e & 63;
        const size_t base = ((size_t)(b_ * NH + h) * HD + d) * SEQ + s;
        Vt[base]           = __float2bfloat16(v0);
        Vt[base + SEQ]     = __float2bfloat16(v1);
        Vt[base + 2 * SEQ] = __float2bfloat16(v2);
        Vt[base + 3 * SEQ] = __float2bfloat16(v3);
      }
    }
  }
}

// ---------------- fused causal flash attention v8 (R14, proven 40.3us) ----------------
__global__ __launch_bounds__(256) void attn_fused(
    const __hip_bfloat16* __restrict__ Qb,
    const __hip_bfloat16* __restrict__ Kb,
    const __hip_bfloat16* __restrict__ Vt,
    __hip_bfloat16* __restrict__ Cx)
{
  __shared__ __align__(16) __hip_bfloat16 Ks[2][64 * 64];  // 8KB each
  __shared__ __align__(16) __hip_bfloat16 Vs[2][64 * 64];  // V^T: [d][kt], 8KB each
  const int tid = threadIdx.x;
  const int lane = tid & 63, w = tid >> 6;
  const int c = lane & 15, g = lane >> 4;
  const int bid = blockIdx.x;
  const int xcd = bid & 7, i_ = bid >> 3;          // 96 per XCD
  const int bh = xcd + 8 * (i_ % 3);
  const int qb = 31 - i_ / 3;                      // 64-row group, descending
  const int KBmax = qb;                            // kb = 0..qb (64 keys each)
  const __hip_bfloat16* Qh = Qb + (size_t)bh * SEQ * HD;
  const __hip_bfloat16* Kh = Kb + (size_t)bh * SEQ * HD;
  const __hip_bfloat16* Vh = Vt + (size_t)bh * HD * SEQ;
  const int q1 = qb * 64 + w * 16 + c;             // absolute q-row of this lane
  const int qt_w = 2 * qb + (w >> 1);              // wave's causal 32-key sub-block limit
  const int qrl32 = (w & 1) * 16 + c;              // row within the diagonal 32-key window
  const short8v qf10 = *(const short8v*)&Qh[(size_t)q1 * HD + g * 8];
  const short8v qf11 = *(const short8v*)&Qh[(size_t)q1 * HD + 32 + g * 8];
  floatx4 o1[4] = {};
  float l1 = 0.0f;
  const int kr1 = 8 * (c >> 2) + (c & 3);          // permuted A-row -> kt_local

  const int srow = w * 8 + (lane >> 3), sslot = lane & 7;

#define STAGE_KV(KB_, KSD, VSD)                                                     \
  do {                                                                              \
    _Pragma("unroll")                                                               \
    for (int j = 0; j < 2; ++j) {                                                   \
      const int kr = j * 32 + srow;                                                 \
      gload_lds16(Kh + (size_t)((KB_) * 64 + kr) * HD + ((sslot ^ swzg(kr)) * 8),   \
                  (KSD) + j * 2048 + w * 512);                                      \
      gload_lds16(Vh + (size_t)kr * SEQ + (KB_) * 64 + ((sslot ^ (kr & 7)) * 8),    \
                  (VSD) + j * 2048 + w * 512);                                      \
    }                                                                               \
  } while (0)

  STAGE_KV(0, Ks[0], Vs[0]);
  __syncthreads();
  int cb = 0;
  for (int kb = 0; kb <= KBmax; ++kb) {
    if (kb < KBmax) STAGE_KV(kb + 1, Ks[cb ^ 1], Vs[cb ^ 1]);
    {
      const __hip_bfloat16* Kt = Ks[cb];
      const __hip_bfloat16* Vb = Vs[cb];
#pragma unroll
      for (int s = 0; s < 2; ++s) {
        const int kidx = 2 * kb + s;
        if (kidx <= qt_w) {
          const int r0 = s * 32 + kr1, r1 = r0 + 4;
          const int z0 = swzg(r0), z1 = swzg(r1);
          const short8v a00 = *(const short8v*)&Kt[r0 * 64 + ((g ^ z0) * 8)];
          const short8v a01 = *(const short8v*)&Kt[r0 * 64 + (((4 + g) ^ z0) * 8)];
          const short8v a10 = *(const short8v*)&Kt[r1 * 64 + ((g ^ z1) * 8)];
          const short8v a11 = *(const short8v*)&Kt[r1 * 64 + (((4 + g) ^ z1) * 8)];
          short8v vf[4];
#pragma unroll
          for (int f = 0; f < 4; ++f) {
            const int rv = f * 16 + c;
            vf[f] = *(const short8v*)&Vb[rv * 64 + (((s * 4 + g) ^ (rv & 7)) * 8)];
          }
          floatx4 s1a = {}, s1b = {};
          s1a = __builtin_amdgcn_mfma_f32_16x16x32_bf16(a00, qf10, s1a, 0, 0, 0);
          s1a = __builtin_amdgcn_mfma_f32_16x16x32_bf16(a01, qf11, s1a, 0, 0, 0);
          s1b = __builtin_amdgcn_mfma_f32_16x16x32_bf16(a10, qf10, s1b, 0, 0, 0);
          s1b = __builtin_amdgcn_mfma_f32_16x16x32_bf16(a11, qf11, s1b, 0, 0, 0);
          if (kidx == qt_w) {
#pragma unroll
            for (int r = 0; r < 4; ++r) {
              if (8 * g + r > qrl32) s1a[r] = -INFINITY;
              if (8 * g + r + 4 > qrl32) s1b[r] = -INFINITY;
            }
          }
          short8v pf1;
#pragma unroll
          for (int r = 0; r < 4; ++r) {
            float p;
            p = EXPFN(s1a[r]); l1 += p; pf1[r] = bfb(p);
            p = EXPFN(s1b[r]); l1 += p; pf1[r + 4] = bfb(p);
          }
          o1[0] = __builtin_amdgcn_mfma_f32_16x16x32_bf16(vf[0], pf1, o1[0], 0, 0, 0);
          o1[1] = __builtin_amdgcn_mfma_f32_16x16x32_bf16(vf[1], pf1, o1[1], 0, 0, 0);
          o1[2] = __builtin_amdgcn_mfma_f32_16x16x32_bf16(vf[2], pf1, o1[2], 0, 0, 0);
          o1[3] = __builtin_amdgcn_mfma_f32_16x16x32_bf16(vf[3], pf1, o1[3], 0, 0, 0);
        }
      }
    }
    __syncthreads();
    cb ^= 1;
  }
#undef STAGE_KV

  l1 += __shfl_xor(l1, 16); l1 += __shfl_xor(l1, 32);
  const float inv1 = 1.0f / l1;
  const int bb = bh / NH, h = bh - bb * NH;
  const size_t trow1 = ((size_t)bb * SEQ + q1) * DM + (size_t)h * HD;
#pragma unroll
  for (int f = 0; f < 4; ++f) {
    short4v pk1;
#pragma unroll
    for (int r = 0; r < 4; ++r) pk1[r] = bfb(o1[f][r] * inv1);
    *(short4v*)&Cx[trow1 + f * 16 + 4 * g] = pk1;
  }
}

// ---------------- output GEMM: m97 structure, BK=64 (R13, proven) ----------------
__global__ __launch_bounds__(256) void out_gemm(
    const __hip_bfloat16* __restrict__ Wo,
    const __hip_bfloat16* __restrict__ Cx,
    float* __restrict__ out)
{
  __shared__ __align__(16) __hip_bfloat16 As[128 * 64];
  __shared__ __align__(16) __hip_bfloat16 Bs[128 * 64];
  const int tid = threadIdx.x;
  const int lane = tid & 63, w = tid >> 6;
  const int c = lane & 15, g = lane >> 4;
  const int wr = w >> 1, wc = w & 1;
  const int m0 = blockIdx.y * 128;   // e-block (6)
  const int n0 = blockIdx.x * 128;   // t-block (32)
  const int srow = tid >> 3, sslot = tid & 7;

  floatx4 acc[4][4] = {};
  for (int k0 = 0; k0 < DM; k0 += 64) {
#pragma unroll
    for (int j = 0; j < 4; ++j) {
      const int row = j * 32 + srow;
      const int gs = (sslot ^ (row & 7)) * 8;
      gload_lds16(Wo + (size_t)(m0 + row) * DM + k0 + gs, As + j * 2048 + w * 512);
      gload_lds16(Cx + (size_t)(n0 + row) * DM + k0 + gs, Bs + j * 2048 + w * 512);
    }
    __syncthreads();
#pragma unroll
    for (int kk = 0; kk < 2; ++kk) {
      short8v a[4], b[4];
#pragma unroll
      for (int i = 0; i < 4; ++i) {
        const int row = wr * 64 + i * 16 + c;
        a[i] = *(const short8v*)&As[row * 64 + (((kk * 4 + g) ^ (row & 7)) * 8)];
      }
#pragma unroll
      for (int j = 0; j < 4; ++j) {
        const int row = wc * 64 + j * 16 + c;
        b[j] = *(const short8v*)&Bs[row * 64 + (((kk * 4 + g) ^ (row & 7)) * 8)];
      }
#pragma unroll
      for (int i = 0; i < 4; ++i)
#pragma unroll
        for (int j = 0; j < 4; ++j)
          acc[i][j] = __builtin_amdgcn_mfma_f32_16x16x32_bf16(a[i], b[j], acc[i][j], 0, 0, 0);
    }
    __syncthreads();
  }
#pragma unroll
  for (int i = 0; i < 4; ++i) {
    const int e0 = m0 + wr * 64 + i * 16 + 4 * g;
#pragma unroll
    for (int j = 0; j < 4; ++j) {
      const int t = n0 + wc * 64 + j * 16 + c;
      *(floatx4*)&out[(size_t)t * DM + e0] = acc[i][j];
    }
  }
}

extern "C" void kernel_launch(void* const* d_in, const int* in_sizes, int n_in,
                              void* d_out, int out_size, void* d_ws, size_t ws_size,
                              hipStream_t stream) {
  const float* x    = (const float*)d_in[0];
  const int*   tpos = (const int*)d_in[1];
  const float* Wq   = (const float*)d_in[2];
  const float* Wo   = (const float*)d_in[3];
  float* out = (float*)d_out;

  const size_t QKV_BYTES = (size_t)NB * NH * SEQ * HD * 2;  // 6,291,456
  const size_t REQUIRED = 4 * QKV_BYTES;                    // 25,165,824
  if (ws_size < REQUIRED) return;

  char* ws = (char*)d_ws;
  __hip_bfloat16* Qb = (__hip_bfloat16*)(ws);
  __hip_bfloat16* Kb = (__hip_bfloat16*)(ws + QKV_BYTES);
  __hip_bfloat16* Vt = (__hip_bfloat16*)(ws + 2 * QKV_BYTES);
  __hip_bfloat16* Cx = (__hip_bfloat16*)(ws + 3 * QKV_BYTES);
  __hip_bfloat16* xb = (__hip_bfloat16*)(ws + 3 * QKV_BYTES);   // aliases Cx (dead before attn)
  char* ob = (char*)d_out;
  float2* rcs = (float2*)(ob);                                           // 512KB
  __hip_bfloat16* wqb = (__hip_bfloat16*)(ob + (size_t)SEQ * 32 * 8);    // 3.54MB
  __hip_bfloat16* wob = (__hip_bfloat16*)(ob + (size_t)SEQ * 32 * 8 + (size_t)E3 * DM * 2);  // 1.18MB

  const int TOT_N = CVT_N + SEQ * 32;
  cvt3_rope<<<dim3((TOT_N + 255) / 256), dim3(256), 0, stream>>>(x, Wq, Wo, xb, wqb, wob, rcs);
  qkv_gemm_rope<<<dim3(1152), dim3(256), 0, stream>>>(wqb, xb, tpos, rcs, Qb, Kb, Vt);
  attn_fused<<<dim3(768), dim3(256), 0, stream>>>(Qb, Kb, Vt, Cx);
  out_gemm<<<dim3(32, 6), dim3(256), 0, stream>>>(wob, Cx, out);
}

// Round 16
// 95.734 us; speedup vs baseline: 1.4052x; 1.0270x over previous
//
#include <hip/hip_runtime.h>
#include <hip/hip_bf16.h>
#include <math.h>

#define SEQ 2048
#define DM 768
#define NH 12
#define HD 64
#define NB 2
#define NT (NB*SEQ)      // 4096 tokens
#define E3 (3*DM)        // 2304

using short4v = __attribute__((ext_vector_type(4))) short;
using short8v = __attribute__((ext_vector_type(8))) short;
using floatx4 = __attribute__((ext_vector_type(4))) float;
using int4v   = __attribute__((ext_vector_type(4))) int;

#if __has_builtin(__builtin_amdgcn_exp2f)
#define EXPFN(x) __builtin_amdgcn_exp2f(x)
#define QSCALE 0.1803368801111244f   /* 0.125 * log2(e) : scores in log2 domain */
#else
#define EXPFN(x) __expf(x)
#define QSCALE 0.125f
#endif

static __device__ __forceinline__ short bfb(float f) {
  union { __hip_bfloat16 h; short s; } u;
  u.h = __float2bfloat16(f);
  return u.s;
}

// async global->LDS, 16 bytes per lane. lds must be wave-uniform.
static __device__ __forceinline__ void gload_lds16(const __hip_bfloat16* g, __hip_bfloat16* lds) {
  __builtin_amdgcn_global_load_lds(
      (const __attribute__((address_space(1))) unsigned int*)g,
      (__attribute__((address_space(3))) unsigned int*)lds, 16, 0, 0);
}

// K granule swizzle (16B granules, 8 per 128B row): rows 8a+b -> (a+2b)&7
static __device__ __forceinline__ int swzg(int row) {
  return (((row >> 3) & 3) + 2 * (row & 3)) & 7;
}

// ---------------- fused fp32->bf16 convert (x, Wq, Wo) + rope table, one dispatch ----------------
#define XN4 (NT * DM / 4)          // 786432
#define WQN4 (E3 * DM / 4)         // 442368
#define WON4 (DM * DM / 4)         // 147456
#define CVT_N (XN4 + WQN4 + WON4)  // 1376256
__global__ void cvt3_rope(const float* __restrict__ x, const float* __restrict__ wq,
                          const float* __restrict__ wo,
                          __hip_bfloat16* __restrict__ xb, __hip_bfloat16* __restrict__ wqb,
                          __hip_bfloat16* __restrict__ wob, float2* __restrict__ rcs) {
  int i = blockIdx.x * blockDim.x + threadIdx.x;
  if (i >= CVT_N) {
    int idx = i - CVT_N;
    if (idx < SEQ * 32) {
      int pos = idx >> 5, j = idx & 31;
      float freq = __expf(-(float)j * (logf(10000.0f) / 32.0f));
      float ang = (float)pos * freq;
      rcs[idx] = make_float2(cosf(ang), sinf(ang));
    }
    return;
  }
  const float* src;
  __hip_bfloat16* dst;
  int k;
  if (i < XN4) { src = x; dst = xb; k = i; }
  else if (i < XN4 + WQN4) { src = wq; dst = wqb; k = i - XN4; }
  else { src = wo; dst = wob; k = i - XN4 - WQN4; }
  floatx4 v = ((const floatx4*)src)[k];
  short4v o;
  o[0] = bfb(v[0]); o[1] = bfb(v[1]); o[2] = bfb(v[2]); o[3] = bfb(v[3]);
  ((short4v*)dst)[k] = o;
}

// ---------------- QKV GEMM v2: 64x128 tile, BK=64, 1152 blocks (R15, proven) ----------------
__global__ __launch_bounds__(256) void qkv_gemm_rope(
    const __hip_bfloat16* __restrict__ Wq,
    const __hip_bfloat16* __restrict__ Xb,
    const int* __restrict__ tpos,
    const float2* __restrict__ rcs,
    __hip_bfloat16* __restrict__ Qb, __hip_bfloat16* __restrict__ Kb,
    __hip_bfloat16* __restrict__ Vt)
{
  __shared__ __align__(16) __hip_bfloat16 As[64 * 64];    // 8KB
  __shared__ __align__(16) __hip_bfloat16 Bs[128 * 64];   // 16KB
  const int tid = threadIdx.x;
  const int lane = tid & 63, w = tid >> 6;
  const int c = lane & 15, g = lane >> 4;
  const int wr = w >> 1, wc = w & 1;
  const int bid = blockIdx.x;
  const int xcd = bid & 7, i_ = bid >> 3;        // 144 per XCD
  const int nb = xcd * 4 + (i_ & 3), mb = i_ >> 2;  // nb 0..31, mb 0..35
  const int m0 = mb * 64, n0 = nb * 128;
  const int srow = tid >> 3, sslot = tid & 7;    // 32 rows per staging round

  floatx4 acc[2][4] = {};
  for (int k0 = 0; k0 < DM; k0 += 64) {
#pragma unroll
    for (int j = 0; j < 2; ++j) {
      const int row = j * 32 + srow;
      const int gs = (sslot ^ (row & 7)) * 8;
      gload_lds16(Wq + (size_t)(m0 + row) * DM + k0 + gs, As + j * 2048 + w * 512);
    }
#pragma unroll
    for (int j = 0; j < 4; ++j) {
      const int row = j * 32 + srow;
      const int gs = (sslot ^ (row & 7)) * 8;
      gload_lds16(Xb + (size_t)(n0 + row) * DM + k0 + gs, Bs + j * 2048 + w * 512);
    }
    __syncthreads();
#pragma unroll
    for (int kk = 0; kk < 2; ++kk) {
      short8v a[2], b[4];
#pragma unroll
      for (int i = 0; i < 2; ++i) {
        const int row = wr * 32 + i * 16 + c;
        a[i] = *(const short8v*)&As[row * 64 + (((kk * 4 + g) ^ (row & 7)) * 8)];
      }
#pragma unroll
      for (int j = 0; j < 4; ++j) {
        const int row = wc * 64 + j * 16 + c;
        b[j] = *(const short8v*)&Bs[row * 64 + (((kk * 4 + g) ^ (row & 7)) * 8)];
      }
#pragma unroll
      for (int i = 0; i < 2; ++i)
#pragma unroll
        for (int j = 0; j < 4; ++j)
          acc[i][j] = __builtin_amdgcn_mfma_f32_16x16x32_bf16(a[i], b[j], acc[i][j], 0, 0, 0);
    }
    __syncthreads();
  }
#pragma unroll
  for (int i = 0; i < 2; ++i) {
    const int e0 = m0 + wr * 32 + i * 16 + 4 * g;
    const int jj = (e0 & 63) >> 1;
#pragma unroll
    for (int j = 0; j < 4; ++j) {
      const int t = n0 + wc * 64 + j * 16 + c;
      const int b_ = t >> 11, s = t & (SEQ - 1);
      float v0 = acc[i][j][0], v1 = acc[i][j][1], v2 = acc[i][j][2], v3 = acc[i][j][3];
      if (e0 < 2 * DM) {
        const int pos = tpos[t];
        const float2 cs0 = rcs[pos * 32 + jj];
        const float2 cs1 = rcs[pos * 32 + jj + 1];
        const float n0v = v0 * cs0.x - v1 * cs0.y, n1v = v0 * cs0.y + v1 * cs0.x;
        const float n2v = v2 * cs1.x - v3 * cs1.y, n3v = v2 * cs1.y + v3 * cs1.x;
        v0 = n0v; v1 = n1v; v2 = n2v; v3 = n3v;
      }
      if (e0 < DM) {
        const int h = e0 >> 6, d = e0 & 63;
        short4v pk;
        pk[0] = bfb(v0 * QSCALE); pk[1] = bfb(v1 * QSCALE);
        pk[2] = bfb(v2 * QSCALE); pk[3] = bfb(v3 * QSCALE);
        *(short4v*)&Qb[(((size_t)(b_ * NH + h) * SEQ) + s) * HD + d] = pk;
      } else if (e0 < 2 * DM) {
        const int e = e0 - DM, h = e >> 6, d = e & 63;
        short4v pk;
        pk[0] = bfb(v0); pk[1] = bfb(v1); pk[2] = bfb(v2); pk[3] = bfb(v3);
        *(short4v*)&Kb[(((size_t)(b_ * NH + h) * SEQ) + s) * HD + d] = pk;
      } else {
        const int e = e0 - 2 * DM, h = e >> 6, d = e & 63;
        const size_t base = ((size_t)(b_ * NH + h) * HD + d) * SEQ + s;
        Vt[base]           = __float2bfloat16(v0);
        Vt[base + SEQ]     = __float2bfloat16(v1);
        Vt[base + 2 * SEQ] = __float2bfloat16(v2);
        Vt[base + 3 * SEQ] = __float2bfloat16(v3);
      }
    }
  }
}

// ---------------- fused causal flash attention v9: 8-wave shared stage ----------------
// Block = 8 waves x 16 q-rows = 128 q-rows sharing ONE K/V stage. Per-CU
// barrier-iters halve vs v8 (6528 block-iters total), staging traffic halves
// (102MB). Wave grain stays 16 rows. 384 blocks (24 bh x 16 groups, qG
// descending), LDS 32KB. m==0 softmax (exact).
__global__ __launch_bounds__(512) void attn_fused(
    const __hip_bfloat16* __restrict__ Qb,
    const __hip_bfloat16* __restrict__ Kb,
    const __hip_bfloat16* __restrict__ Vt,
    __hip_bfloat16* __restrict__ Cx)
{
  __shared__ __align__(16) __hip_bfloat16 Ks[2][64 * 64];  // 8KB each
  __shared__ __align__(16) __hip_bfloat16 Vs[2][64 * 64];  // V^T: [d][kt], 8KB each
  const int tid = threadIdx.x;
  const int lane = tid & 63, w = tid >> 6;          // 8 waves
  const int c = lane & 15, g = lane >> 4;
  const int bid = blockIdx.x;
  const int xcd = bid & 7, i_ = bid >> 3;           // 48 per XCD
  const int bh = xcd + 8 * (i_ % 3);
  const int qG = 15 - i_ / 3;                       // 128-row group, descending
  const int KBmax = 2 * qG + 1;                     // kb = 0..KBmax (64 keys each)
  const __hip_bfloat16* Qh = Qb + (size_t)bh * SEQ * HD;
  const __hip_bfloat16* Kh = Kb + (size_t)bh * SEQ * HD;
  const __hip_bfloat16* Vh = Vt + (size_t)bh * HD * SEQ;
  const int q1 = qG * 128 + w * 16 + c;             // absolute q-row of this lane
  const int qt_w = 4 * qG + (w >> 1);               // wave's causal 32-key sub-block limit
  const int qrl32 = (w & 1) * 16 + c;               // row within the diagonal 32-key window
  const short8v qf10 = *(const short8v*)&Qh[(size_t)q1 * HD + g * 8];
  const short8v qf11 = *(const short8v*)&Qh[(size_t)q1 * HD + 32 + g * 8];
  floatx4 o1[4] = {};
  float l1 = 0.0f;
  const int kr1 = 8 * (c >> 2) + (c & 3);           // permuted A-row -> kt_local

  // staging: 512 threads cover K (64 rows x 8 granules) + V (64 x 8) in one
  // call each; wave w -> rows w*8 .. w*8+7.
  const int srow = w * 8 + (lane >> 3), sslot = lane & 7;

#define STAGE_KV(KB_, KSD, VSD)                                                     \
  do {                                                                              \
    gload_lds16(Kh + (size_t)((KB_) * 64 + srow) * HD + ((sslot ^ swzg(srow)) * 8), \
                (KSD) + w * 512);                                                   \
    gload_lds16(Vh + (size_t)srow * SEQ + (KB_) * 64 + ((sslot ^ (srow & 7)) * 8),  \
                (VSD) + w * 512);                                                   \
  } while (0)

  STAGE_KV(0, Ks[0], Vs[0]);
  __syncthreads();
  int cb = 0;
  for (int kb = 0; kb <= KBmax; ++kb) {
    if (kb < KBmax) STAGE_KV(kb + 1, Ks[cb ^ 1], Vs[cb ^ 1]);
    {
      const __hip_bfloat16* Kt = Ks[cb];
      const __hip_bfloat16* Vb = Vs[cb];
#pragma unroll
      for (int s = 0; s < 2; ++s) {
        const int kidx = 2 * kb + s;
        if (kidx <= qt_w) {
          const int r0 = s * 32 + kr1, r1 = r0 + 4;
          const int z0 = swzg(r0), z1 = swzg(r1);
          const short8v a00 = *(const short8v*)&Kt[r0 * 64 + ((g ^ z0) * 8)];
          const short8v a01 = *(const short8v*)&Kt[r0 * 64 + (((4 + g) ^ z0) * 8)];
          const short8v a10 = *(const short8v*)&Kt[r1 * 64 + ((g ^ z1) * 8)];
          const short8v a11 = *(const short8v*)&Kt[r1 * 64 + (((4 + g) ^ z1) * 8)];
          short8v vf[4];
#pragma unroll
          for (int f = 0; f < 4; ++f) {
            const int rv = f * 16 + c;
            vf[f] = *(const short8v*)&Vb[rv * 64 + (((s * 4 + g) ^ (rv & 7)) * 8)];
          }
          floatx4 s1a = {}, s1b = {};
          s1a = __builtin_amdgcn_mfma_f32_16x16x32_bf16(a00, qf10, s1a, 0, 0, 0);
          s1a = __builtin_amdgcn_mfma_f32_16x16x32_bf16(a01, qf11, s1a, 0, 0, 0);
          s1b = __builtin_amdgcn_mfma_f32_16x16x32_bf16(a10, qf10, s1b, 0, 0, 0);
          s1b = __builtin_amdgcn_mfma_f32_16x16x32_bf16(a11, qf11, s1b, 0, 0, 0);
          if (kidx == qt_w) {  // diagonal 32-key window: mask keys > own row
#pragma unroll
            for (int r = 0; r < 4; ++r) {
              if (8 * g + r > qrl32) s1a[r] = -INFINITY;
              if (8 * g + r + 4 > qrl32) s1b[r] = -INFINITY;
            }
          }
          short8v pf1;
#pragma unroll
          for (int r = 0; r < 4; ++r) {
            float p;
            p = EXPFN(s1a[r]); l1 += p; pf1[r] = bfb(p);
            p = EXPFN(s1b[r]); l1 += p; pf1[r + 4] = bfb(p);
          }
          o1[0] = __builtin_amdgcn_mfma_f32_16x16x32_bf16(vf[0], pf1, o1[0], 0, 0, 0);
          o1[1] = __builtin_amdgcn_mfma_f32_16x16x32_bf16(vf[1], pf1, o1[1], 0, 0, 0);
          o1[2] = __builtin_amdgcn_mfma_f32_16x16x32_bf16(vf[2], pf1, o1[2], 0, 0, 0);
          o1[3] = __builtin_amdgcn_mfma_f32_16x16x32_bf16(vf[3], pf1, o1[3], 0, 0, 0);
        }
      }
    }
    __syncthreads();
    cb ^= 1;
  }
#undef STAGE_KV

  l1 += __shfl_xor(l1, 16); l1 += __shfl_xor(l1, 32);
  const float inv1 = 1.0f / l1;
  const int bb = bh / NH, h = bh - bb * NH;
  const size_t trow1 = ((size_t)bb * SEQ + q1) * DM + (size_t)h * HD;
#pragma unroll
  for (int f = 0; f < 4; ++f) {
    short4v pk1;
#pragma unroll
    for (int r = 0; r < 4; ++r) pk1[r] = bfb(o1[f][r] * inv1);
    *(short4v*)&Cx[trow1 + f * 16 + 4 * g] = pk1;
  }
}

// ---------------- output GEMM: m97 structure, BK=64 (R13, proven) ----------------
__global__ __launch_bounds__(256) void out_gemm(
    const __hip_bfloat16* __restrict__ Wo,
    const __hip_bfloat16* __restrict__ Cx,
    float* __restrict__ out)
{
  __shared__ __align__(16) __hip_bfloat16 As[128 * 64];
  __shared__ __align__(16) __hip_bfloat16 Bs[128 * 64];
  const int tid = threadIdx.x;
  const int lane = tid & 63, w = tid >> 6;
  const int c = lane & 15, g = lane >> 4;
  const int wr = w >> 1, wc = w & 1;
  const int m0 = blockIdx.y * 128;   // e-block (6)
  const int n0 = blockIdx.x * 128;   // t-block (32)
  const int srow = tid >> 3, sslot = tid & 7;

  floatx4 acc[4][4] = {};
  for (int k0 = 0; k0 < DM; k0 += 64) {
#pragma unroll
    for (int j = 0; j < 4; ++j) {
      const int row = j * 32 + srow;
      const int gs = (sslot ^ (row & 7)) * 8;
      gload_lds16(Wo + (size_t)(m0 + row) * DM + k0 + gs, As + j * 2048 + w * 512);
      gload_lds16(Cx + (size_t)(n0 + row) * DM + k0 + gs, Bs + j * 2048 + w * 512);
    }
    __syncthreads();
#pragma unroll
    for (int kk = 0; kk < 2; ++kk) {
      short8v a[4], b[4];
#pragma unroll
      for (int i = 0; i < 4; ++i) {
        const int row = wr * 64 + i * 16 + c;
        a[i] = *(const short8v*)&As[row * 64 + (((kk * 4 + g) ^ (row & 7)) * 8)];
      }
#pragma unroll
      for (int j = 0; j < 4; ++j) {
        const int row = wc * 64 + j * 16 + c;
        b[j] = *(const short8v*)&Bs[row * 64 + (((kk * 4 + g) ^ (row & 7)) * 8)];
      }
#pragma unroll
      for (int i = 0; i < 4; ++i)
#pragma unroll
        for (int j = 0; j < 4; ++j)
          acc[i][j] = __builtin_amdgcn_mfma_f32_16x16x32_bf16(a[i], b[j], acc[i][j], 0, 0, 0);
    }
    __syncthreads();
  }
#pragma unroll
  for (int i = 0; i < 4; ++i) {
    const int e0 = m0 + wr * 64 + i * 16 + 4 * g;
#pragma unroll
    for (int j = 0; j < 4; ++j) {
      const int t = n0 + wc * 64 + j * 16 + c;
      *(floatx4*)&out[(size_t)t * DM + e0] = acc[i][j];
    }
  }
}

extern "C" void kernel_launch(void* const* d_in, const int* in_sizes, int n_in,
                              void* d_out, int out_size, void* d_ws, size_t ws_size,
                              hipStream_t stream) {
  const float* x    = (const float*)d_in[0];
  const int*   tpos = (const int*)d_in[1];
  const float* Wq   = (const float*)d_in[2];
  const float* Wo   = (const float*)d_in[3];
  float* out = (float*)d_out;

  const size_t QKV_BYTES = (size_t)NB * NH * SEQ * HD * 2;  // 6,291,456
  const size_t REQUIRED = 4 * QKV_BYTES;                    // 25,165,824
  if (ws_size < REQUIRED) return;

  char* ws = (char*)d_ws;
  __hip_bfloat16* Qb = (__hip_bfloat16*)(ws);
  __hip_bfloat16* Kb = (__hip_bfloat16*)(ws + QKV_BYTES);
  __hip_bfloat16* Vt = (__hip_bfloat16*)(ws + 2 * QKV_BYTES);
  __hip_bfloat16* Cx = (__hip_bfloat16*)(ws + 3 * QKV_BYTES);
  __hip_bfloat16* xb = (__hip_bfloat16*)(ws + 3 * QKV_BYTES);   // aliases Cx (dead before attn)
  char* ob = (char*)d_out;
  float2* rcs = (float2*)(ob);                                           // 512KB
  __hip_bfloat16* wqb = (__hip_bfloat16*)(ob + (size_t)SEQ * 32 * 8);    // 3.54MB
  __hip_bfloat16* wob = (__hip_bfloat16*)(ob + (size_t)SEQ * 32 * 8 + (size_t)E3 * DM * 2);  // 1.18MB

  const int TOT_N = CVT_N + SEQ * 32;
  cvt3_rope<<<dim3((TOT_N + 255) / 256), dim3(256), 0, stream>>>(x, Wq, Wo, xb, wqb, wob, rcs);
  qkv_gemm_rope<<<dim3(1152), dim3(256), 0, stream>>>(wqb, xb, tpos, rcs, Qb, Kb, Vt);
  attn_fused<<<dim3(384), dim3(512), 0, stream>>>(Qb, Kb, Vt, Cx);
  out_gemm<<<dim3(32, 6), dim3(256), 0, stream>>>(wob, Cx, out);
}

// Round 17
// 88.332 us; speedup vs baseline: 1.5229x; 1.0838x over previous
//
#include <hip/hip_runtime.h>
#include <hip/hip_bf16.h>
#include <math.h>

#define SEQ 2048
#define DM 768
#define NH 12
#define HD 64
#define NB 2
#define NT (NB*SEQ)      // 4096 tokens
#define E3 (3*DM)        // 2304

using short4v = __attribute__((ext_vector_type(4))) short;
using short8v = __attribute__((ext_vector_type(8))) short;
using floatx4 = __attribute__((ext_vector_type(4))) float;
using int4v   = __attribute__((ext_vector_type(4))) int;

#if __has_builtin(__builtin_amdgcn_exp2f)
#define EXPFN(x) __builtin_amdgcn_exp2f(x)
#define QSCALE 0.1803368801111244f   /* 0.125 * log2(e) : scores in log2 domain */
#else
#define EXPFN(x) __expf(x)
#define QSCALE 0.125f
#endif

static __device__ __forceinline__ short bfb(float f) {
  union { __hip_bfloat16 h; short s; } u;
  u.h = __float2bfloat16(f);
  return u.s;
}

// async global->LDS, 16 bytes per lane. lds must be wave-uniform.
static __device__ __forceinline__ void gload_lds16(const __hip_bfloat16* g, __hip_bfloat16* lds) {
  __builtin_amdgcn_global_load_lds(
      (const __attribute__((address_space(1))) unsigned int*)g,
      (__attribute__((address_space(3))) unsigned int*)lds, 16, 0, 0);
}

// K granule swizzle (16B granules, 8 per 128B row): rows 8a+b -> (a+2b)&7
static __device__ __forceinline__ int swzg(int row) {
  return (((row >> 3) & 3) + 2 * (row & 3)) & 7;
}

// ---------------- fused fp32->bf16 convert (x, Wq, Wo) + rope table, one dispatch ----------------
#define XN4 (NT * DM / 4)          // 786432
#define WQN4 (E3 * DM / 4)         // 442368
#define WON4 (DM * DM / 4)         // 147456
#define CVT_N (XN4 + WQN4 + WON4)  // 1376256
__global__ void cvt3_rope(const float* __restrict__ x, const float* __restrict__ wq,
                          const float* __restrict__ wo,
                          __hip_bfloat16* __restrict__ xb, __hip_bfloat16* __restrict__ wqb,
                          __hip_bfloat16* __restrict__ wob, float2* __restrict__ rcs) {
  int i = blockIdx.x * blockDim.x + threadIdx.x;
  if (i >= CVT_N) {
    int idx = i - CVT_N;
    if (idx < SEQ * 32) {
      int pos = idx >> 5, j = idx & 31;
      float freq = __expf(-(float)j * (logf(10000.0f) / 32.0f));
      float ang = (float)pos * freq;
      rcs[idx] = make_float2(cosf(ang), sinf(ang));
    }
    return;
  }
  const float* src;
  __hip_bfloat16* dst;
  int k;
  if (i < XN4) { src = x; dst = xb; k = i; }
  else if (i < XN4 + WQN4) { src = wq; dst = wqb; k = i - XN4; }
  else { src = wo; dst = wob; k = i - XN4 - WQN4; }
  floatx4 v = ((const floatx4*)src)[k];
  short4v o;
  o[0] = bfb(v[0]); o[1] = bfb(v[1]); o[2] = bfb(v[2]); o[3] = bfb(v[3]);
  ((short4v*)dst)[k] = o;
}

// ---------------- QKV GEMM v3: 64x128 tile, BK=128 (6 k-steps, half the drains) ----------------
// LDS 48KB single-buffered (As 16KB + Bs 32KB) -> 3 blocks/CU. 16-slot granule
// swizzle (slot ^= row&15) on both stage-source and read (rule #21).
__global__ __launch_bounds__(256) void qkv_gemm_rope(
    const __hip_bfloat16* __restrict__ Wq,
    const __hip_bfloat16* __restrict__ Xb,
    const int* __restrict__ tpos,
    const float2* __restrict__ rcs,
    __hip_bfloat16* __restrict__ Qb, __hip_bfloat16* __restrict__ Kb,
    __hip_bfloat16* __restrict__ Vt)
{
  __shared__ __align__(16) __hip_bfloat16 As[64 * 128];    // 16KB
  __shared__ __align__(16) __hip_bfloat16 Bs[128 * 128];   // 32KB
  const int tid = threadIdx.x;
  const int lane = tid & 63, w = tid >> 6;
  const int c = lane & 15, g = lane >> 4;
  const int wr = w >> 1, wc = w & 1;
  const int bid = blockIdx.x;
  const int xcd = bid & 7, i_ = bid >> 3;        // 144 per XCD
  const int nb = xcd * 4 + (i_ & 3), mb = i_ >> 2;  // nb 0..31, mb 0..35
  const int m0 = mb * 64, n0 = nb * 128;
  const int srow = tid >> 4, sslot = tid & 15;   // 16 rows x 16 slots per call

  floatx4 acc[2][4] = {};
  for (int k0 = 0; k0 < DM; k0 += 128) {
#pragma unroll
    for (int j = 0; j < 4; ++j) {   // A: 64 rows
      const int row = j * 16 + srow;
      const int gs = (sslot ^ (row & 15)) * 8;
      gload_lds16(Wq + (size_t)(m0 + row) * DM + k0 + gs, As + j * 2048 + w * 512);
    }
#pragma unroll
    for (int j = 0; j < 8; ++j) {   // B: 128 rows
      const int row = j * 16 + srow;
      const int gs = (sslot ^ (row & 15)) * 8;
      gload_lds16(Xb + (size_t)(n0 + row) * DM + k0 + gs, Bs + j * 2048 + w * 512);
    }
    __syncthreads();
#pragma unroll
    for (int kk = 0; kk < 4; ++kk) {
      short8v a[2], b[4];
#pragma unroll
      for (int i = 0; i < 2; ++i) {
        const int row = wr * 32 + i * 16 + c;
        a[i] = *(const short8v*)&As[row * 128 + (((kk * 4 + g) ^ (row & 15)) * 8)];
      }
#pragma unroll
      for (int j = 0; j < 4; ++j) {
        const int row = wc * 64 + j * 16 + c;
        b[j] = *(const short8v*)&Bs[row * 128 + (((kk * 4 + g) ^ (row & 15)) * 8)];
      }
#pragma unroll
      for (int i = 0; i < 2; ++i)
#pragma unroll
        for (int j = 0; j < 4; ++j)
          acc[i][j] = __builtin_amdgcn_mfma_f32_16x16x32_bf16(a[i], b[j], acc[i][j], 0, 0, 0);
    }
    __syncthreads();
  }
#pragma unroll
  for (int i = 0; i < 2; ++i) {
    const int e0 = m0 + wr * 32 + i * 16 + 4 * g;
    const int jj = (e0 & 63) >> 1;
#pragma unroll
    for (int j = 0; j < 4; ++j) {
      const int t = n0 + wc * 64 + j * 16 + c;
      const int b_ = t >> 11, s = t & (SEQ - 1);
      float v0 = acc[i][j][0], v1 = acc[i][j][1], v2 = acc[i][j][2], v3 = acc[i][j][3];
      if (e0 < 2 * DM) {
        const int pos = tpos[t];
        const float2 cs0 = rcs[pos * 32 + jj];
        const float2 cs1 = rcs[pos * 32 + jj + 1];
        const float n0v = v0 * cs0.x - v1 * cs0.y, n1v = v0 * cs0.y + v1 * cs0.x;
        const float n2v = v2 * cs1.x - v3 * cs1.y, n3v = v2 * cs1.y + v3 * cs1.x;
        v0 = n0v; v1 = n1v; v2 = n2v; v3 = n3v;
      }
      if (e0 < DM) {
        const int h = e0 >> 6, d = e0 & 63;
        short4v pk;
        pk[0] = bfb(v0 * QSCALE); pk[1] = bfb(v1 * QSCALE);
        pk[2] = bfb(v2 * QSCALE); pk[3] = bfb(v3 * QSCALE);
        *(short4v*)&Qb[(((size_t)(b_ * NH + h) * SEQ) + s) * HD + d] = pk;
      } else if (e0 < 2 * DM) {
        const int e = e0 - DM, h = e >> 6, d = e & 63;
        short4v pk;
        pk[0] = bfb(v0); pk[1] = bfb(v1); pk[2] = bfb(v2); pk[3] = bfb(v3);
        *(short4v*)&Kb[(((size_t)(b_ * NH + h) * SEQ) + s) * HD + d] = pk;
      } else {
        const int e = e0 - 2 * DM, h = e >> 6, d = e & 63;
        const size_t base = ((size_t)(b_ * NH + h) * HD + d) * SEQ + s;
        Vt[base]           = __float2bfloat16(v0);
        Vt[base + SEQ]     = __float2bfloat16(v1);
        Vt[base + 2 * SEQ] = __float2bfloat16(v2);
        Vt[base + 3 * SEQ] = __float2bfloat16(v3);
      }
    }
  }
}

// ---------------- fused causal flash attention v10: 8-wave, KVBLK=128 ----------------
// Drain count halves vs v9 (3264 block-iters). K[128][64] + V^T[64][128]
// double-buffered = 64KB LDS (2 blocks/CU >= grid 1.5/CU). Wave grain stays
// 16 rows x 32-key sub-blocks (4 per kb). m==0 softmax (exact).
__global__ __launch_bounds__(512) void attn_fused(
    const __hip_bfloat16* __restrict__ Qb,
    const __hip_bfloat16* __restrict__ Kb,
    const __hip_bfloat16* __restrict__ Vt,
    __hip_bfloat16* __restrict__ Cx)
{
  __shared__ __align__(16) __hip_bfloat16 Ks[2][128 * 64];  // 16KB each
  __shared__ __align__(16) __hip_bfloat16 Vs[2][64 * 128];  // V^T: [d][kt], 16KB each
  const int tid = threadIdx.x;
  const int lane = tid & 63, w = tid >> 6;          // 8 waves
  const int c = lane & 15, g = lane >> 4;
  const int bid = blockIdx.x;
  const int xcd = bid & 7, i_ = bid >> 3;           // 48 per XCD
  const int bh = xcd + 8 * (i_ % 3);
  const int qG = 15 - i_ / 3;                       // 128-row group, descending
  const int KBmax = qG;                             // kb = 0..qG (128 keys each)
  const __hip_bfloat16* Qh = Qb + (size_t)bh * SEQ * HD;
  const __hip_bfloat16* Kh = Kb + (size_t)bh * SEQ * HD;
  const __hip_bfloat16* Vh = Vt + (size_t)bh * HD * SEQ;
  const int q1 = qG * 128 + w * 16 + c;             // absolute q-row of this lane
  const int qt_w = 4 * qG + (w >> 1);               // wave's causal 32-key sub-block limit
  const int qrl32 = (w & 1) * 16 + c;               // row within the diagonal 32-key window
  const short8v qf10 = *(const short8v*)&Qh[(size_t)q1 * HD + g * 8];
  const short8v qf11 = *(const short8v*)&Qh[(size_t)q1 * HD + 32 + g * 8];
  floatx4 o1[4] = {};
  float l1 = 0.0f;
  const int kr1 = 8 * (c >> 2) + (c & 3);           // permuted A-row -> kt_local

  // staging: K 1024 granules (128 rows x 8 slots) in 2 calls; V 1024 granules
  // (64 rows x 16 slots) in 2 calls. 512 threads.
  const int ksr = w * 8 + (lane >> 3), kss = lane & 7;     // K: rows +64*j
  const int vsr = w * 4 + (lane >> 4), vss = lane & 15;    // V: rows +32*j

#define STAGE_KV(KB_, KSD, VSD)                                                       \
  do {                                                                               \
    _Pragma("unroll")                                                                \
    for (int j = 0; j < 2; ++j) {                                                    \
      const int kr = j * 64 + ksr;                                                   \
      gload_lds16(Kh + (size_t)((KB_) * 128 + kr) * HD + ((kss ^ swzg(kr)) * 8),     \
                  (KSD) + j * 4096 + w * 512);                                       \
      const int vr = j * 32 + vsr;                                                   \
      gload_lds16(Vh + (size_t)vr * SEQ + (KB_) * 128 + ((vss ^ (vr & 15)) * 8),     \
                  (VSD) + j * 4096 + w * 512);                                       \
    }                                                                                \
  } while (0)

  STAGE_KV(0, Ks[0], Vs[0]);
  __syncthreads();
  int cb = 0;
  for (int kb = 0; kb <= KBmax; ++kb) {
    if (kb < KBmax) STAGE_KV(kb + 1, Ks[cb ^ 1], Vs[cb ^ 1]);
    {
      const __hip_bfloat16* Kt = Ks[cb];
      const __hip_bfloat16* Vb = Vs[cb];
#pragma unroll
      for (int s = 0; s < 4; ++s) {
        const int kidx = 4 * kb + s;
        if (kidx <= qt_w) {
          const int r0 = s * 32 + kr1, r1 = r0 + 4;
          const int z0 = swzg(r0), z1 = swzg(r1);
          const short8v a00 = *(const short8v*)&Kt[r0 * 64 + ((g ^ z0) * 8)];
          const short8v a01 = *(const short8v*)&Kt[r0 * 64 + (((4 + g) ^ z0) * 8)];
          const short8v a10 = *(const short8v*)&Kt[r1 * 64 + ((g ^ z1) * 8)];
          const short8v a11 = *(const short8v*)&Kt[r1 * 64 + (((4 + g) ^ z1) * 8)];
          short8v vf[4];
#pragma unroll
          for (int f = 0; f < 4; ++f) {
            const int rv = f * 16 + c;
            vf[f] = *(const short8v*)&Vb[rv * 128 + (((s * 4 + g) ^ (rv & 15)) * 8)];
          }
          floatx4 s1a = {}, s1b = {};
          s1a = __builtin_amdgcn_mfma_f32_16x16x32_bf16(a00, qf10, s1a, 0, 0, 0);
          s1a = __builtin_amdgcn_mfma_f32_16x16x32_bf16(a01, qf11, s1a, 0, 0, 0);
          s1b = __builtin_amdgcn_mfma_f32_16x16x32_bf16(a10, qf10, s1b, 0, 0, 0);
          s1b = __builtin_amdgcn_mfma_f32_16x16x32_bf16(a11, qf11, s1b, 0, 0, 0);
          if (kidx == qt_w) {  // diagonal 32-key window: mask keys > own row
#pragma unroll
            for (int r = 0; r < 4; ++r) {
              if (8 * g + r > qrl32) s1a[r] = -INFINITY;
              if (8 * g + r + 4 > qrl32) s1b[r] = -INFINITY;
            }
          }
          short8v pf1;
#pragma unroll
          for (int r = 0; r < 4; ++r) {
            float p;
            p = EXPFN(s1a[r]); l1 += p; pf1[r] = bfb(p);
            p = EXPFN(s1b[r]); l1 += p; pf1[r + 4] = bfb(p);
          }
          o1[0] = __builtin_amdgcn_mfma_f32_16x16x32_bf16(vf[0], pf1, o1[0], 0, 0, 0);
          o1[1] = __builtin_amdgcn_mfma_f32_16x16x32_bf16(vf[1], pf1, o1[1], 0, 0, 0);
          o1[2] = __builtin_amdgcn_mfma_f32_16x16x32_bf16(vf[2], pf1, o1[2], 0, 0, 0);
          o1[3] = __builtin_amdgcn_mfma_f32_16x16x32_bf16(vf[3], pf1, o1[3], 0, 0, 0);
        }
      }
    }
    __syncthreads();
    cb ^= 1;
  }
#undef STAGE_KV

  l1 += __shfl_xor(l1, 16); l1 += __shfl_xor(l1, 32);
  const float inv1 = 1.0f / l1;
  const int bb = bh / NH, h = bh - bb * NH;
  const size_t trow1 = ((size_t)bb * SEQ + q1) * DM + (size_t)h * HD;
#pragma unroll
  for (int f = 0; f < 4; ++f) {
    short4v pk1;
#pragma unroll
    for (int r = 0; r < 4; ++r) pk1[r] = bfb(o1[f][r] * inv1);
    *(short4v*)&Cx[trow1 + f * 16 + 4 * g] = pk1;
  }
}

// ---------------- output GEMM: m97 structure, BK=64 (R13, proven) ----------------
__global__ __launch_bounds__(256) void out_gemm(
    const __hip_bfloat16* __restrict__ Wo,
    const __hip_bfloat16* __restrict__ Cx,
    float* __restrict__ out)
{
  __shared__ __align__(16) __hip_bfloat16 As[128 * 64];
  __shared__ __align__(16) __hip_bfloat16 Bs[128 * 64];
  const int tid = threadIdx.x;
  const int lane = tid & 63, w = tid >> 6;
  const int c = lane & 15, g = lane >> 4;
  const int wr = w >> 1, wc = w & 1;
  const int m0 = blockIdx.y * 128;   // e-block (6)
  const int n0 = blockIdx.x * 128;   // t-block (32)
  const int srow = tid >> 3, sslot = tid & 7;

  floatx4 acc[4][4] = {};
  for (int k0 = 0; k0 < DM; k0 += 64) {
#pragma unroll
    for (int j = 0; j < 4; ++j) {
      const int row = j * 32 + srow;
      const int gs = (sslot ^ (row & 7)) * 8;
      gload_lds16(Wo + (size_t)(m0 + row) * DM + k0 + gs, As + j * 2048 + w * 512);
      gload_lds16(Cx + (size_t)(n0 + row) * DM + k0 + gs, Bs + j * 2048 + w * 512);
    }
    __syncthreads();
#pragma unroll
    for (int kk = 0; kk < 2; ++kk) {
      short8v a[4], b[4];
#pragma unroll
      for (int i = 0; i < 4; ++i) {
        const int row = wr * 64 + i * 16 + c;
        a[i] = *(const short8v*)&As[row * 64 + (((kk * 4 + g) ^ (row & 7)) * 8)];
      }
#pragma unroll
      for (int j = 0; j < 4; ++j) {
        const int row = wc * 64 + j * 16 + c;
        b[j] = *(const short8v*)&Bs[row * 64 + (((kk * 4 + g) ^ (row & 7)) * 8)];
      }
#pragma unroll
      for (int i = 0; i < 4; ++i)
#pragma unroll
        for (int j = 0; j < 4; ++j)
          acc[i][j] = __builtin_amdgcn_mfma_f32_16x16x32_bf16(a[i], b[j], acc[i][j], 0, 0, 0);
    }
    __syncthreads();
  }
#pragma unroll
  for (int i = 0; i < 4; ++i) {
    const int e0 = m0 + wr * 64 + i * 16 + 4 * g;
#pragma unroll
    for (int j = 0; j < 4; ++j) {
      const int t = n0 + wc * 64 + j * 16 + c;
      *(floatx4*)&out[(size_t)t * DM + e0] = acc[i][j];
    }
  }
}

extern "C" void kernel_launch(void* const* d_in, const int* in_sizes, int n_in,
                              void* d_out, int out_size, void* d_ws, size_t ws_size,
                              hipStream_t stream) {
  const float* x    = (const float*)d_in[0];
  const int*   tpos = (const int*)d_in[1];
  const float* Wq   = (const float*)d_in[2];
  const float* Wo   = (const float*)d_in[3];
  float* out = (float*)d_out;

  const size_t QKV_BYTES = (size_t)NB * NH * SEQ * HD * 2;  // 6,291,456
  const size_t REQUIRED = 4 * QKV_BYTES;                    // 25,165,824
  if (ws_size < REQUIRED) return;

  char* ws = (char*)d_ws;
  __hip_bfloat16* Qb = (__hip_bfloat16*)(ws);
  __hip_bfloat16* Kb = (__hip_bfloat16*)(ws + QKV_BYTES);
  __hip_bfloat16* Vt = (__hip_bfloat16*)(ws + 2 * QKV_BYTES);
  __hip_bfloat16* Cx = (__hip_bfloat16*)(ws + 3 * QKV_BYTES);
  __hip_bfloat16* xb = (__hip_bfloat16*)(ws + 3 * QKV_BYTES);   // aliases Cx (dead before attn)
  char* ob = (char*)d_out;
  float2* rcs = (float2*)(ob);                                           // 512KB
  __hip_bfloat16* wqb = (__hip_bfloat16*)(ob + (size_t)SEQ * 32 * 8);    // 3.54MB
  __hip_bfloat16* wob = (__hip_bfloat16*)(ob + (size_t)SEQ * 32 * 8 + (size_t)E3 * DM * 2);  // 1.18MB

  const int TOT_N = CVT_N + SEQ * 32;
  cvt3_rope<<<dim3((TOT_N + 255) / 256), dim3(256), 0, stream>>>(x, Wq, Wo, xb, wqb, wob, rcs);
  qkv_gemm_rope<<<dim3(1152), dim3(256), 0, stream>>>(wqb, xb, tpos, rcs, Qb, Kb, Vt);
  attn_fused<<<dim3(384), dim3(512), 0, stream>>>(Qb, Kb, Vt, Cx);
  out_gemm<<<dim3(32, 6), dim3(256), 0, stream>>>(wob, Cx, out);
}

// Round 18
// 87.185 us; speedup vs baseline: 1.5429x; 1.0132x over previous
//
#include <hip/hip_runtime.h>
#include <hip/hip_bf16.h>
#include <math.h>

#define SEQ 2048
#define DM 768
#define NH 12
#define HD 64
#define NB 2
#define NT (NB*SEQ)      // 4096 tokens
#define E3 (3*DM)        // 2304

using short4v = __attribute__((ext_vector_type(4))) short;
using short8v = __attribute__((ext_vector_type(8))) short;
using floatx4 = __attribute__((ext_vector_type(4))) float;
using int4v   = __attribute__((ext_vector_type(4))) int;

#if __has_builtin(__builtin_amdgcn_exp2f)
#define EXPFN(x) __builtin_amdgcn_exp2f(x)
#define QSCALE 0.1803368801111244f   /* 0.125 * log2(e) : scores in log2 domain */
#else
#define EXPFN(x) __expf(x)
#define QSCALE 0.125f
#endif

static __device__ __forceinline__ short bfb(float f) {
  union { __hip_bfloat16 h; short s; } u;
  u.h = __float2bfloat16(f);
  return u.s;
}

// async global->LDS, 16 bytes per lane. lds must be wave-uniform.
static __device__ __forceinline__ void gload_lds16(const __hip_bfloat16* g, __hip_bfloat16* lds) {
  __builtin_amdgcn_global_load_lds(
      (const __attribute__((address_space(1))) unsigned int*)g,
      (__attribute__((address_space(3))) unsigned int*)lds, 16, 0, 0);
}

// K granule swizzle (16B granules, 8 per 128B row): rows 8a+b -> (a+2b)&7
static __device__ __forceinline__ int swzg(int row) {
  return (((row >> 3) & 3) + 2 * (row & 3)) & 7;
}

// ---------------- fused fp32->bf16 convert (x, Wq, Wo) + rope table + queue reset ----------------
#define XN4 (NT * DM / 4)          // 786432
#define WQN4 (E3 * DM / 4)         // 442368
#define WON4 (DM * DM / 4)         // 147456
#define CVT_N (XN4 + WQN4 + WON4)  // 1376256
__global__ void cvt3_rope(const float* __restrict__ x, const float* __restrict__ wq,
                          const float* __restrict__ wo,
                          __hip_bfloat16* __restrict__ xb, __hip_bfloat16* __restrict__ wqb,
                          __hip_bfloat16* __restrict__ wob, float2* __restrict__ rcs,
                          int* __restrict__ qcnt) {
  int i = blockIdx.x * blockDim.x + threadIdx.x;
  if (blockIdx.x == 0 && threadIdx.x < 8) qcnt[threadIdx.x] = 0;  // per-XCD LPT queues
  if (i >= CVT_N) {
    int idx = i - CVT_N;
    if (idx < SEQ * 32) {
      int pos = idx >> 5, j = idx & 31;
      float freq = __expf(-(float)j * (logf(10000.0f) / 32.0f));
      float ang = (float)pos * freq;
      rcs[idx] = make_float2(cosf(ang), sinf(ang));
    }
    return;
  }
  const float* src;
  __hip_bfloat16* dst;
  int k;
  if (i < XN4) { src = x; dst = xb; k = i; }
  else if (i < XN4 + WQN4) { src = wq; dst = wqb; k = i - XN4; }
  else { src = wo; dst = wob; k = i - XN4 - WQN4; }
  floatx4 v = ((const floatx4*)src)[k];
  short4v o;
  o[0] = bfb(v[0]); o[1] = bfb(v[1]); o[2] = bfb(v[2]); o[3] = bfb(v[3]);
  ((short4v*)dst)[k] = o;
}

// ---------------- QKV GEMM v3: 64x128 tile, BK=128 (R17, proven) ----------------
__global__ __launch_bounds__(256) void qkv_gemm_rope(
    const __hip_bfloat16* __restrict__ Wq,
    const __hip_bfloat16* __restrict__ Xb,
    const int* __restrict__ tpos,
    const float2* __restrict__ rcs,
    __hip_bfloat16* __restrict__ Qb, __hip_bfloat16* __restrict__ Kb,
    __hip_bfloat16* __restrict__ Vt)
{
  __shared__ __align__(16) __hip_bfloat16 As[64 * 128];    // 16KB
  __shared__ __align__(16) __hip_bfloat16 Bs[128 * 128];   // 32KB
  const int tid = threadIdx.x;
  const int lane = tid & 63, w = tid >> 6;
  const int c = lane & 15, g = lane >> 4;
  const int wr = w >> 1, wc = w & 1;
  const int bid = blockIdx.x;
  const int xcd = bid & 7, i_ = bid >> 3;        // 144 per XCD
  const int nb = xcd * 4 + (i_ & 3), mb = i_ >> 2;  // nb 0..31, mb 0..35
  const int m0 = mb * 64, n0 = nb * 128;
  const int srow = tid >> 4, sslot = tid & 15;   // 16 rows x 16 slots per call

  floatx4 acc[2][4] = {};
  for (int k0 = 0; k0 < DM; k0 += 128) {
#pragma unroll
    for (int j = 0; j < 4; ++j) {   // A: 64 rows
      const int row = j * 16 + srow;
      const int gs = (sslot ^ (row & 15)) * 8;
      gload_lds16(Wq + (size_t)(m0 + row) * DM + k0 + gs, As + j * 2048 + w * 512);
    }
#pragma unroll
    for (int j = 0; j < 8; ++j) {   // B: 128 rows
      const int row = j * 16 + srow;
      const int gs = (sslot ^ (row & 15)) * 8;
      gload_lds16(Xb + (size_t)(n0 + row) * DM + k0 + gs, Bs + j * 2048 + w * 512);
    }
    __syncthreads();
#pragma unroll
    for (int kk = 0; kk < 4; ++kk) {
      short8v a[2], b[4];
#pragma unroll
      for (int i = 0; i < 2; ++i) {
        const int row = wr * 32 + i * 16 + c;
        a[i] = *(const short8v*)&As[row * 128 + (((kk * 4 + g) ^ (row & 15)) * 8)];
      }
#pragma unroll
      for (int j = 0; j < 4; ++j) {
        const int row = wc * 64 + j * 16 + c;
        b[j] = *(const short8v*)&Bs[row * 128 + (((kk * 4 + g) ^ (row & 15)) * 8)];
      }
#pragma unroll
      for (int i = 0; i < 2; ++i)
#pragma unroll
        for (int j = 0; j < 4; ++j)
          acc[i][j] = __builtin_amdgcn_mfma_f32_16x16x32_bf16(a[i], b[j], acc[i][j], 0, 0, 0);
    }
    __syncthreads();
  }
#pragma unroll
  for (int i = 0; i < 2; ++i) {
    const int e0 = m0 + wr * 32 + i * 16 + 4 * g;
    const int jj = (e0 & 63) >> 1;
#pragma unroll
    for (int j = 0; j < 4; ++j) {
      const int t = n0 + wc * 64 + j * 16 + c;
      const int b_ = t >> 11, s = t & (SEQ - 1);
      float v0 = acc[i][j][0], v1 = acc[i][j][1], v2 = acc[i][j][2], v3 = acc[i][j][3];
      if (e0 < 2 * DM) {
        const int pos = tpos[t];
        const float2 cs0 = rcs[pos * 32 + jj];
        const float2 cs1 = rcs[pos * 32 + jj + 1];
        const float n0v = v0 * cs0.x - v1 * cs0.y, n1v = v0 * cs0.y + v1 * cs0.x;
        const float n2v = v2 * cs1.x - v3 * cs1.y, n3v = v2 * cs1.y + v3 * cs1.x;
        v0 = n0v; v1 = n1v; v2 = n2v; v3 = n3v;
      }
      if (e0 < DM) {
        const int h = e0 >> 6, d = e0 & 63;
        short4v pk;
        pk[0] = bfb(v0 * QSCALE); pk[1] = bfb(v1 * QSCALE);
        pk[2] = bfb(v2 * QSCALE); pk[3] = bfb(v3 * QSCALE);
        *(short4v*)&Qb[(((size_t)(b_ * NH + h) * SEQ) + s) * HD + d] = pk;
      } else if (e0 < 2 * DM) {
        const int e = e0 - DM, h = e >> 6, d = e & 63;
        short4v pk;
        pk[0] = bfb(v0); pk[1] = bfb(v1); pk[2] = bfb(v2); pk[3] = bfb(v3);
        *(short4v*)&Kb[(((size_t)(b_ * NH + h) * SEQ) + s) * HD + d] = pk;
      } else {
        const int e = e0 - 2 * DM, h = e >> 6, d = e & 63;
        const size_t base = ((size_t)(b_ * NH + h) * HD + d) * SEQ + s;
        Vt[base]           = __float2bfloat16(v0);
        Vt[base + SEQ]     = __float2bfloat16(v1);
        Vt[base + 2 * SEQ] = __float2bfloat16(v2);
        Vt[base + 3 * SEQ] = __float2bfloat16(v3);
      }
    }
  }
}

// ---------------- fused causal flash attention v11: LPT work queue ----------------
// v10 inner structure (8 waves, KVBLK=128, 64KB LDS) + per-XCD atomic task
// queue: 48 tasks/XCD sorted descending (qG = 15 - task/3), grid 512 = 2
// slots/CU. Greedy grab ~= LPT scheduling -> makespan ~ max-task (16 iters)
// instead of the static-mapping ~21-iter tail. Output is assignment-invariant.
__global__ __launch_bounds__(512) void attn_fused(
    const __hip_bfloat16* __restrict__ Qb,
    const __hip_bfloat16* __restrict__ Kb,
    const __hip_bfloat16* __restrict__ Vt,
    __hip_bfloat16* __restrict__ Cx,
    int* __restrict__ qcnt)
{
  __shared__ __align__(16) __hip_bfloat16 Ks[2][128 * 64];  // 16KB each
  __shared__ __align__(16) __hip_bfloat16 Vs[2][64 * 128];  // V^T: [d][kt], 16KB each
  __shared__ int task_s;
  const int tid = threadIdx.x;
  const int lane = tid & 63, w = tid >> 6;          // 8 waves
  const int c = lane & 15, g = lane >> 4;
  const int xcd = blockIdx.x & 7;
  const int kr1 = 8 * (c >> 2) + (c & 3);           // permuted A-row -> kt_local
  const int ksr = w * 8 + (lane >> 3), kss = lane & 7;     // K stage: rows +64*j
  const int vsr = w * 4 + (lane >> 4), vss = lane & 15;    // V stage: rows +32*j

  for (;;) {
    if (tid == 0) task_s = atomicAdd(&qcnt[xcd], 1);
    __syncthreads();
    const int task = task_s;
    if (task >= 48) return;
    const int qG = 15 - task / 3;                   // descending size (LPT)
    const int bh = xcd + 8 * (task % 3);
    const int KBmax = qG;                           // kb = 0..qG (128 keys each)
    const __hip_bfloat16* Qh = Qb + (size_t)bh * SEQ * HD;
    const __hip_bfloat16* Kh = Kb + (size_t)bh * SEQ * HD;
    const __hip_bfloat16* Vh = Vt + (size_t)bh * HD * SEQ;
    const int q1 = qG * 128 + w * 16 + c;           // absolute q-row of this lane
    const int qt_w = 4 * qG + (w >> 1);             // wave's causal 32-key sub-block limit
    const int qrl32 = (w & 1) * 16 + c;             // row within the diagonal 32-key window
    const short8v qf10 = *(const short8v*)&Qh[(size_t)q1 * HD + g * 8];
    const short8v qf11 = *(const short8v*)&Qh[(size_t)q1 * HD + 32 + g * 8];
    floatx4 o1[4] = {};
    float l1 = 0.0f;

#define STAGE_KV(KB_, KSD, VSD)                                                      \
    do {                                                                             \
      _Pragma("unroll")                                                              \
      for (int j = 0; j < 2; ++j) {                                                  \
        const int kr = j * 64 + ksr;                                                 \
        gload_lds16(Kh + (size_t)((KB_) * 128 + kr) * HD + ((kss ^ swzg(kr)) * 8),   \
                    (KSD) + j * 4096 + w * 512);                                     \
        const int vr = j * 32 + vsr;                                                 \
        gload_lds16(Vh + (size_t)vr * SEQ + (KB_) * 128 + ((vss ^ (vr & 15)) * 8),   \
                    (VSD) + j * 4096 + w * 512);                                     \
      }                                                                              \
    } while (0)

    STAGE_KV(0, Ks[0], Vs[0]);
    __syncthreads();
    int cb = 0;
    for (int kb = 0; kb <= KBmax; ++kb) {
      if (kb < KBmax) STAGE_KV(kb + 1, Ks[cb ^ 1], Vs[cb ^ 1]);
      {
        const __hip_bfloat16* Kt = Ks[cb];
        const __hip_bfloat16* Vb = Vs[cb];
#pragma unroll
        for (int s = 0; s < 4; ++s) {
          const int kidx = 4 * kb + s;
          if (kidx <= qt_w) {
            const int r0 = s * 32 + kr1, r1 = r0 + 4;
            const int z0 = swzg(r0), z1 = swzg(r1);
            const short8v a00 = *(const short8v*)&Kt[r0 * 64 + ((g ^ z0) * 8)];
            const short8v a01 = *(const short8v*)&Kt[r0 * 64 + (((4 + g) ^ z0) * 8)];
            const short8v a10 = *(const short8v*)&Kt[r1 * 64 + ((g ^ z1) * 8)];
            const short8v a11 = *(const short8v*)&Kt[r1 * 64 + (((4 + g) ^ z1) * 8)];
            short8v vf[4];
#pragma unroll
            for (int f = 0; f < 4; ++f) {
              const int rv = f * 16 + c;
              vf[f] = *(const short8v*)&Vb[rv * 128 + (((s * 4 + g) ^ (rv & 15)) * 8)];
            }
            floatx4 s1a = {}, s1b = {};
            s1a = __builtin_amdgcn_mfma_f32_16x16x32_bf16(a00, qf10, s1a, 0, 0, 0);
            s1a = __builtin_amdgcn_mfma_f32_16x16x32_bf16(a01, qf11, s1a, 0, 0, 0);
            s1b = __builtin_amdgcn_mfma_f32_16x16x32_bf16(a10, qf10, s1b, 0, 0, 0);
            s1b = __builtin_amdgcn_mfma_f32_16x16x32_bf16(a11, qf11, s1b, 0, 0, 0);
            if (kidx == qt_w) {  // diagonal 32-key window: mask keys > own row
#pragma unroll
              for (int r = 0; r < 4; ++r) {
                if (8 * g + r > qrl32) s1a[r] = -INFINITY;
                if (8 * g + r + 4 > qrl32) s1b[r] = -INFINITY;
              }
            }
            short8v pf1;
#pragma unroll
            for (int r = 0; r < 4; ++r) {
              float p;
              p = EXPFN(s1a[r]); l1 += p; pf1[r] = bfb(p);
              p = EXPFN(s1b[r]); l1 += p; pf1[r + 4] = bfb(p);
            }
            o1[0] = __builtin_amdgcn_mfma_f32_16x16x32_bf16(vf[0], pf1, o1[0], 0, 0, 0);
            o1[1] = __builtin_amdgcn_mfma_f32_16x16x32_bf16(vf[1], pf1, o1[1], 0, 0, 0);
            o1[2] = __builtin_amdgcn_mfma_f32_16x16x32_bf16(vf[2], pf1, o1[2], 0, 0, 0);
            o1[3] = __builtin_amdgcn_mfma_f32_16x16x32_bf16(vf[3], pf1, o1[3], 0, 0, 0);
          }
        }
      }
      __syncthreads();
      cb ^= 1;
    }
#undef STAGE_KV

    l1 += __shfl_xor(l1, 16); l1 += __shfl_xor(l1, 32);
    const float inv1 = 1.0f / l1;
    const int bb = bh / NH, h = bh - bb * NH;
    const size_t trow1 = ((size_t)bb * SEQ + q1) * DM + (size_t)h * HD;
#pragma unroll
    for (int f = 0; f < 4; ++f) {
      short4v pk1;
#pragma unroll
      for (int r = 0; r < 4; ++r) pk1[r] = bfb(o1[f][r] * inv1);
      *(short4v*)&Cx[trow1 + f * 16 + 4 * g] = pk1;
    }
    // next task's STAGE is ordered after the task-fetch __syncthreads above
  }
}

// ---------------- output GEMM v2: 64x128 tile, BK=128 (qkv-v3 structure) ----------------
// 384 blocks (1.5/CU), 3 k-steps. A = Wo (e-rows), B = Cx (t-rows).
__global__ __launch_bounds__(256) void out_gemm(
    const __hip_bfloat16* __restrict__ Wo,
    const __hip_bfloat16* __restrict__ Cx,
    float* __restrict__ out)
{
  __shared__ __align__(16) __hip_bfloat16 As[64 * 128];    // 16KB
  __shared__ __align__(16) __hip_bfloat16 Bs[128 * 128];   // 32KB
  const int tid = threadIdx.x;
  const int lane = tid & 63, w = tid >> 6;
  const int c = lane & 15, g = lane >> 4;
  const int wr = w >> 1, wc = w & 1;
  const int bid = blockIdx.x;
  const int xcd = bid & 7, i_ = bid >> 3;        // 48 per XCD
  const int nb = xcd * 4 + (i_ & 3), mb = i_ >> 2;  // nb 0..31 (t), mb 0..11 (e)
  const int m0 = mb * 64, n0 = nb * 128;
  const int srow = tid >> 4, sslot = tid & 15;

  floatx4 acc[2][4] = {};
  for (int k0 = 0; k0 < DM; k0 += 128) {
#pragma unroll
    for (int j = 0; j < 4; ++j) {   // A: 64 rows
      const int row = j * 16 + srow;
      const int gs = (sslot ^ (row & 15)) * 8;
      gload_lds16(Wo + (size_t)(m0 + row) * DM + k0 + gs, As + j * 2048 + w * 512);
    }
#pragma unroll
    for (int j = 0; j < 8; ++j) {   // B: 128 rows
      const int row = j * 16 + srow;
      const int gs = (sslot ^ (row & 15)) * 8;
      gload_lds16(Cx + (size_t)(n0 + row) * DM + k0 + gs, Bs + j * 2048 + w * 512);
    }
    __syncthreads();
#pragma unroll
    for (int kk = 0; kk < 4; ++kk) {
      short8v a[2], b[4];
#pragma unroll
      for (int i = 0; i < 2; ++i) {
        const int row = wr * 32 + i * 16 + c;
        a[i] = *(const short8v*)&As[row * 128 + (((kk * 4 + g) ^ (row & 15)) * 8)];
      }
#pragma unroll
      for (int j = 0; j < 4; ++j) {
        const int row = wc * 64 + j * 16 + c;
        b[j] = *(const short8v*)&Bs[row * 128 + (((kk * 4 + g) ^ (row & 15)) * 8)];
      }
#pragma unroll
      for (int i = 0; i < 2; ++i)
#pragma unroll
        for (int j = 0; j < 4; ++j)
          acc[i][j] = __builtin_amdgcn_mfma_f32_16x16x32_bf16(a[i], b[j], acc[i][j], 0, 0, 0);
    }
    __syncthreads();
  }
#pragma unroll
  for (int i = 0; i < 2; ++i) {
    const int e0 = m0 + wr * 32 + i * 16 + 4 * g;
#pragma unroll
    for (int j = 0; j < 4; ++j) {
      const int t = n0 + wc * 64 + j * 16 + c;
      *(floatx4*)&out[(size_t)t * DM + e0] = acc[i][j];
    }
  }
}

extern "C" void kernel_launch(void* const* d_in, const int* in_sizes, int n_in,
                              void* d_out, int out_size, void* d_ws, size_t ws_size,
                              hipStream_t stream) {
  const float* x    = (const float*)d_in[0];
  const int*   tpos = (const int*)d_in[1];
  const float* Wq   = (const float*)d_in[2];
  const float* Wo   = (const float*)d_in[3];
  float* out = (float*)d_out;

  const size_t QKV_BYTES = (size_t)NB * NH * SEQ * HD * 2;  // 6,291,456
  const size_t REQUIRED = 4 * QKV_BYTES;                    // 25,165,824
  if (ws_size < REQUIRED) return;

  char* ws = (char*)d_ws;
  __hip_bfloat16* Qb = (__hip_bfloat16*)(ws);
  __hip_bfloat16* Kb = (__hip_bfloat16*)(ws + QKV_BYTES);
  __hip_bfloat16* Vt = (__hip_bfloat16*)(ws + 2 * QKV_BYTES);
  __hip_bfloat16* Cx = (__hip_bfloat16*)(ws + 3 * QKV_BYTES);
  __hip_bfloat16* xb = (__hip_bfloat16*)(ws + 3 * QKV_BYTES);   // aliases Cx (dead before attn)
  char* ob = (char*)d_out;   // d_out-head scratch, all dead before out_gemm overwrites
  float2* rcs = (float2*)(ob);                                           // 512KB
  __hip_bfloat16* wqb = (__hip_bfloat16*)(ob + (size_t)SEQ * 32 * 8);    // 3.54MB
  __hip_bfloat16* wob = (__hip_bfloat16*)(ob + (size_t)SEQ * 32 * 8 + (size_t)E3 * DM * 2);  // 1.18MB
  int* qcnt = (int*)(ob + (size_t)SEQ * 32 * 8 + (size_t)E3 * DM * 2 + (size_t)DM * DM * 2); // 32B

  const int TOT_N = CVT_N + SEQ * 32;
  cvt3_rope<<<dim3((TOT_N + 255) / 256), dim3(256), 0, stream>>>(x, Wq, Wo, xb, wqb, wob, rcs, qcnt);
  qkv_gemm_rope<<<dim3(1152), dim3(256), 0, stream>>>(wqb, xb, tpos, rcs, Qb, Kb, Vt);
  attn_fused<<<dim3(512), dim3(512), 0, stream>>>(Qb, Kb, Vt, Cx, qcnt);
  out_gemm<<<dim3(384), dim3(256), 0, stream>>>(wob, Cx, out);
}

// Round 19
// 87.030 us; speedup vs baseline: 1.5457x; 1.0018x over previous
//
#include <hip/hip_runtime.h>
#include <hip/hip_bf16.h>
#include <math.h>

#define SEQ 2048
#define DM 768
#define NH 12
#define HD 64
#define NB 2
#define NT (NB*SEQ)      // 4096 tokens
#define E3 (3*DM)        // 2304

using short4v = __attribute__((ext_vector_type(4))) short;
using short8v = __attribute__((ext_vector_type(8))) short;
using floatx4 = __attribute__((ext_vector_type(4))) float;
using int4v   = __attribute__((ext_vector_type(4))) int;

#if __has_builtin(__builtin_amdgcn_exp2f)
#define EXPFN(x) __builtin_amdgcn_exp2f(x)
#define QSCALE 0.1803368801111244f   /* 0.125 * log2(e) : scores in log2 domain */
#else
#define EXPFN(x) __expf(x)
#define QSCALE 0.125f
#endif

static __device__ __forceinline__ short bfb(float f) {
  union { __hip_bfloat16 h; short s; } u;
  u.h = __float2bfloat16(f);
  return u.s;
}

// async global->LDS, 16 bytes per lane. lds must be wave-uniform.
static __device__ __forceinline__ void gload_lds16(const __hip_bfloat16* g, __hip_bfloat16* lds) {
  __builtin_amdgcn_global_load_lds(
      (const __attribute__((address_space(1))) unsigned int*)g,
      (__attribute__((address_space(3))) unsigned int*)lds, 16, 0, 0);
}

// K granule swizzle (16B granules, 8 per 128B row): rows 8a+b -> (a+2b)&7
static __device__ __forceinline__ int swzg(int row) {
  return (((row >> 3) & 3) + 2 * (row & 3)) & 7;
}

// ---------------- fused fp32->bf16 convert (x, Wq, Wo) + rope table + queue reset ----------------
#define XN4 (NT * DM / 4)          // 786432
#define WQN4 (E3 * DM / 4)         // 442368
#define WON4 (DM * DM / 4)         // 147456
#define CVT_N (XN4 + WQN4 + WON4)  // 1376256
__global__ void cvt3_rope(const float* __restrict__ x, const float* __restrict__ wq,
                          const float* __restrict__ wo,
                          __hip_bfloat16* __restrict__ xb, __hip_bfloat16* __restrict__ wqb,
                          __hip_bfloat16* __restrict__ wob, float2* __restrict__ rcs,
                          int* __restrict__ qcnt) {
  int i = blockIdx.x * blockDim.x + threadIdx.x;
  if (blockIdx.x == 0 && threadIdx.x < 8) qcnt[threadIdx.x] = 0;  // per-XCD LPT queues
  if (i >= CVT_N) {
    int idx = i - CVT_N;
    if (idx < SEQ * 32) {
      int pos = idx >> 5, j = idx & 31;
      float freq = __expf(-(float)j * (logf(10000.0f) / 32.0f));
      float ang = (float)pos * freq;
      rcs[idx] = make_float2(cosf(ang), sinf(ang));
    }
    return;
  }
  const float* src;
  __hip_bfloat16* dst;
  int k;
  if (i < XN4) { src = x; dst = xb; k = i; }
  else if (i < XN4 + WQN4) { src = wq; dst = wqb; k = i - XN4; }
  else { src = wo; dst = wob; k = i - XN4 - WQN4; }
  floatx4 v = ((const floatx4*)src)[k];
  short4v o;
  o[0] = bfb(v[0]); o[1] = bfb(v[1]); o[2] = bfb(v[2]); o[3] = bfb(v[3]);
  ((short4v*)dst)[k] = o;
}

// ---------------- QKV GEMM v4: 64x128 tile, BK=64, DOUBLE-BUFFERED 2-phase ----------------
// T3 minimum: STAGE(next, buf^1) issued BEFORE compute(buf); the barrier then
// drains a stage that has had a full compute phase to hide under. LDS 2x24KB
// = 48KB -> 3 blocks/CU (same occupancy as R17's single-buffered BK=128).
__global__ __launch_bounds__(256) void qkv_gemm_rope(
    const __hip_bfloat16* __restrict__ Wq,
    const __hip_bfloat16* __restrict__ Xb,
    const int* __restrict__ tpos,
    const float2* __restrict__ rcs,
    __hip_bfloat16* __restrict__ Qb, __hip_bfloat16* __restrict__ Kb,
    __hip_bfloat16* __restrict__ Vt)
{
  __shared__ __align__(16) __hip_bfloat16 As[2][64 * 64];    // 8KB each
  __shared__ __align__(16) __hip_bfloat16 Bs[2][128 * 64];   // 16KB each
  const int tid = threadIdx.x;
  const int lane = tid & 63, w = tid >> 6;
  const int c = lane & 15, g = lane >> 4;
  const int wr = w >> 1, wc = w & 1;
  const int bid = blockIdx.x;
  const int xcd = bid & 7, i_ = bid >> 3;        // 144 per XCD
  const int nb = xcd * 4 + (i_ & 3), mb = i_ >> 2;  // nb 0..31, mb 0..35
  const int m0 = mb * 64, n0 = nb * 128;
  const int srow = tid >> 3, sslot = tid & 7;    // 32 rows x 8 slots per call

#define QKV_STAGE(K0_, AD, BD)                                                      \
  do {                                                                              \
    _Pragma("unroll")                                                               \
    for (int j = 0; j < 2; ++j) {                                                   \
      const int row = j * 32 + srow;                                                \
      const int gs = (sslot ^ (row & 7)) * 8;                                       \
      gload_lds16(Wq + (size_t)(m0 + row) * DM + (K0_) + gs, (AD) + j * 2048 + w * 512); \
    }                                                                               \
    _Pragma("unroll")                                                               \
    for (int j = 0; j < 4; ++j) {                                                   \
      const int row = j * 32 + srow;                                                \
      const int gs = (sslot ^ (row & 7)) * 8;                                       \
      gload_lds16(Xb + (size_t)(n0 + row) * DM + (K0_) + gs, (BD) + j * 2048 + w * 512); \
    }                                                                               \
  } while (0)

  floatx4 acc[2][4] = {};
  QKV_STAGE(0, As[0], Bs[0]);
  int cb = 0;
  for (int k0 = 0; k0 < DM; k0 += 64) {
    if (k0 + 64 < DM) QKV_STAGE(k0 + 64, As[cb ^ 1], Bs[cb ^ 1]);
    __syncthreads();   // drains stage(k0) — issued one full step ago
#pragma unroll
    for (int kk = 0; kk < 2; ++kk) {
      short8v a[2], b[4];
#pragma unroll
      for (int i = 0; i < 2; ++i) {
        const int row = wr * 32 + i * 16 + c;
        a[i] = *(const short8v*)&As[cb][row * 64 + (((kk * 4 + g) ^ (row & 7)) * 8)];
      }
#pragma unroll
      for (int j = 0; j < 4; ++j) {
        const int row = wc * 64 + j * 16 + c;
        b[j] = *(const short8v*)&Bs[cb][row * 64 + (((kk * 4 + g) ^ (row & 7)) * 8)];
      }
#pragma unroll
      for (int i = 0; i < 2; ++i)
#pragma unroll
        for (int j = 0; j < 4; ++j)
          acc[i][j] = __builtin_amdgcn_mfma_f32_16x16x32_bf16(a[i], b[j], acc[i][j], 0, 0, 0);
    }
    __syncthreads();   // buf[cb] consumed -> reusable for the stage in flight
    cb ^= 1;
  }
#undef QKV_STAGE
#pragma unroll
  for (int i = 0; i < 2; ++i) {
    const int e0 = m0 + wr * 32 + i * 16 + 4 * g;
    const int jj = (e0 & 63) >> 1;
#pragma unroll
    for (int j = 0; j < 4; ++j) {
      const int t = n0 + wc * 64 + j * 16 + c;
      const int b_ = t >> 11, s = t & (SEQ - 1);
      float v0 = acc[i][j][0], v1 = acc[i][j][1], v2 = acc[i][j][2], v3 = acc[i][j][3];
      if (e0 < 2 * DM) {
        const int pos = tpos[t];
        const float2 cs0 = rcs[pos * 32 + jj];
        const float2 cs1 = rcs[pos * 32 + jj + 1];
        const float n0v = v0 * cs0.x - v1 * cs0.y, n1v = v0 * cs0.y + v1 * cs0.x;
        const float n2v = v2 * cs1.x - v3 * cs1.y, n3v = v2 * cs1.y + v3 * cs1.x;
        v0 = n0v; v1 = n1v; v2 = n2v; v3 = n3v;
      }
      if (e0 < DM) {
        const int h = e0 >> 6, d = e0 & 63;
        short4v pk;
        pk[0] = bfb(v0 * QSCALE); pk[1] = bfb(v1 * QSCALE);
        pk[2] = bfb(v2 * QSCALE); pk[3] = bfb(v3 * QSCALE);
        *(short4v*)&Qb[(((size_t)(b_ * NH + h) * SEQ) + s) * HD + d] = pk;
      } else if (e0 < 2 * DM) {
        const int e = e0 - DM, h = e >> 6, d = e & 63;
        short4v pk;
        pk[0] = bfb(v0); pk[1] = bfb(v1); pk[2] = bfb(v2); pk[3] = bfb(v3);
        *(short4v*)&Kb[(((size_t)(b_ * NH + h) * SEQ) + s) * HD + d] = pk;
      } else {
        const int e = e0 - 2 * DM, h = e >> 6, d = e & 63;
        const size_t base = ((size_t)(b_ * NH + h) * HD + d) * SEQ + s;
        Vt[base]           = __float2bfloat16(v0);
        Vt[base + SEQ]     = __float2bfloat16(v1);
        Vt[base + 2 * SEQ] = __float2bfloat16(v2);
        Vt[base + 3 * SEQ] = __float2bfloat16(v3);
      }
    }
  }
}

// ---------------- fused causal flash attention v11: LPT work queue (R18) ----------------
__global__ __launch_bounds__(512) void attn_fused(
    const __hip_bfloat16* __restrict__ Qb,
    const __hip_bfloat16* __restrict__ Kb,
    const __hip_bfloat16* __restrict__ Vt,
    __hip_bfloat16* __restrict__ Cx,
    int* __restrict__ qcnt)
{
  __shared__ __align__(16) __hip_bfloat16 Ks[2][128 * 64];  // 16KB each
  __shared__ __align__(16) __hip_bfloat16 Vs[2][64 * 128];  // V^T: [d][kt], 16KB each
  __shared__ int task_s;
  const int tid = threadIdx.x;
  const int lane = tid & 63, w = tid >> 6;          // 8 waves
  const int c = lane & 15, g = lane >> 4;
  const int xcd = blockIdx.x & 7;
  const int kr1 = 8 * (c >> 2) + (c & 3);           // permuted A-row -> kt_local
  const int ksr = w * 8 + (lane >> 3), kss = lane & 7;     // K stage: rows +64*j
  const int vsr = w * 4 + (lane >> 4), vss = lane & 15;    // V stage: rows +32*j

  for (;;) {
    if (tid == 0) task_s = atomicAdd(&qcnt[xcd], 1);
    __syncthreads();
    const int task = task_s;
    if (task >= 48) return;
    const int qG = 15 - task / 3;                   // descending size (LPT)
    const int bh = xcd + 8 * (task % 3);
    const int KBmax = qG;                           // kb = 0..qG (128 keys each)
    const __hip_bfloat16* Qh = Qb + (size_t)bh * SEQ * HD;
    const __hip_bfloat16* Kh = Kb + (size_t)bh * SEQ * HD;
    const __hip_bfloat16* Vh = Vt + (size_t)bh * HD * SEQ;
    const int q1 = qG * 128 + w * 16 + c;           // absolute q-row of this lane
    const int qt_w = 4 * qG + (w >> 1);             // wave's causal 32-key sub-block limit
    const int qrl32 = (w & 1) * 16 + c;             // row within the diagonal 32-key window
    const short8v qf10 = *(const short8v*)&Qh[(size_t)q1 * HD + g * 8];
    const short8v qf11 = *(const short8v*)&Qh[(size_t)q1 * HD + 32 + g * 8];
    floatx4 o1[4] = {};
    float l1 = 0.0f;

#define STAGE_KV(KB_, KSD, VSD)                                                      \
    do {                                                                             \
      _Pragma("unroll")                                                              \
      for (int j = 0; j < 2; ++j) {                                                  \
        const int kr = j * 64 + ksr;                                                 \
        gload_lds16(Kh + (size_t)((KB_) * 128 + kr) * HD + ((kss ^ swzg(kr)) * 8),   \
                    (KSD) + j * 4096 + w * 512);                                     \
        const int vr = j * 32 + vsr;                                                 \
        gload_lds16(Vh + (size_t)vr * SEQ + (KB_) * 128 + ((vss ^ (vr & 15)) * 8),   \
                    (VSD) + j * 4096 + w * 512);                                     \
      }                                                                              \
    } while (0)

    STAGE_KV(0, Ks[0], Vs[0]);
    __syncthreads();
    int cb = 0;
    for (int kb = 0; kb <= KBmax; ++kb) {
      if (kb < KBmax) STAGE_KV(kb + 1, Ks[cb ^ 1], Vs[cb ^ 1]);
      {
        const __hip_bfloat16* Kt = Ks[cb];
        const __hip_bfloat16* Vb = Vs[cb];
#pragma unroll
        for (int s = 0; s < 4; ++s) {
          const int kidx = 4 * kb + s;
          if (kidx <= qt_w) {
            const int r0 = s * 32 + kr1, r1 = r0 + 4;
            const int z0 = swzg(r0), z1 = swzg(r1);
            const short8v a00 = *(const short8v*)&Kt[r0 * 64 + ((g ^ z0) * 8)];
            const short8v a01 = *(const short8v*)&Kt[r0 * 64 + (((4 + g) ^ z0) * 8)];
            const short8v a10 = *(const short8v*)&Kt[r1 * 64 + ((g ^ z1) * 8)];
            const short8v a11 = *(const short8v*)&Kt[r1 * 64 + (((4 + g) ^ z1) * 8)];
            short8v vf[4];
#pragma unroll
            for (int f = 0; f < 4; ++f) {
              const int rv = f * 16 + c;
              vf[f] = *(const short8v*)&Vb[rv * 128 + (((s * 4 + g) ^ (rv & 15)) * 8)];
            }
            floatx4 s1a = {}, s1b = {};
            s1a = __builtin_amdgcn_mfma_f32_16x16x32_bf16(a00, qf10, s1a, 0, 0, 0);
            s1a = __builtin_amdgcn_mfma_f32_16x16x32_bf16(a01, qf11, s1a, 0, 0, 0);
            s1b = __builtin_amdgcn_mfma_f32_16x16x32_bf16(a10, qf10, s1b, 0, 0, 0);
            s1b = __builtin_amdgcn_mfma_f32_16x16x32_bf16(a11, qf11, s1b, 0, 0, 0);
            if (kidx == qt_w) {  // diagonal 32-key window: mask keys > own row
#pragma unroll
              for (int r = 0; r < 4; ++r) {
                if (8 * g + r > qrl32) s1a[r] = -INFINITY;
                if (8 * g + r + 4 > qrl32) s1b[r] = -INFINITY;
              }
            }
            short8v pf1;
#pragma unroll
            for (int r = 0; r < 4; ++r) {
              float p;
              p = EXPFN(s1a[r]); l1 += p; pf1[r] = bfb(p);
              p = EXPFN(s1b[r]); l1 += p; pf1[r + 4] = bfb(p);
            }
            o1[0] = __builtin_amdgcn_mfma_f32_16x16x32_bf16(vf[0], pf1, o1[0], 0, 0, 0);
            o1[1] = __builtin_amdgcn_mfma_f32_16x16x32_bf16(vf[1], pf1, o1[1], 0, 0, 0);
            o1[2] = __builtin_amdgcn_mfma_f32_16x16x32_bf16(vf[2], pf1, o1[2], 0, 0, 0);
            o1[3] = __builtin_amdgcn_mfma_f32_16x16x32_bf16(vf[3], pf1, o1[3], 0, 0, 0);
          }
        }
      }
      __syncthreads();
      cb ^= 1;
    }
#undef STAGE_KV

    l1 += __shfl_xor(l1, 16); l1 += __shfl_xor(l1, 32);
    const float inv1 = 1.0f / l1;
    const int bb = bh / NH, h = bh - bb * NH;
    const size_t trow1 = ((size_t)bb * SEQ + q1) * DM + (size_t)h * HD;
#pragma unroll
    for (int f = 0; f < 4; ++f) {
      short4v pk1;
#pragma unroll
      for (int r = 0; r < 4; ++r) pk1[r] = bfb(o1[f][r] * inv1);
      *(short4v*)&Cx[trow1 + f * 16 + 4 * g] = pk1;
    }
  }
}

// ---------------- output GEMM v3: 64x128 tile, BK=64, double-buffered 2-phase ----------------
__global__ __launch_bounds__(256) void out_gemm(
    const __hip_bfloat16* __restrict__ Wo,
    const __hip_bfloat16* __restrict__ Cx,
    float* __restrict__ out)
{
  __shared__ __align__(16) __hip_bfloat16 As[2][64 * 64];    // 8KB each
  __shared__ __align__(16) __hip_bfloat16 Bs[2][128 * 64];   // 16KB each
  const int tid = threadIdx.x;
  const int lane = tid & 63, w = tid >> 6;
  const int c = lane & 15, g = lane >> 4;
  const int wr = w >> 1, wc = w & 1;
  const int bid = blockIdx.x;
  const int xcd = bid & 7, i_ = bid >> 3;        // 48 per XCD
  const int nb = xcd * 4 + (i_ & 3), mb = i_ >> 2;  // nb 0..31 (t), mb 0..11 (e)
  const int m0 = mb * 64, n0 = nb * 128;
  const int srow = tid >> 3, sslot = tid & 7;

#define OUT_STAGE(K0_, AD, BD)                                                      \
  do {                                                                              \
    _Pragma("unroll")                                                               \
    for (int j = 0; j < 2; ++j) {                                                   \
      const int row = j * 32 + srow;                                                \
      const int gs = (sslot ^ (row & 7)) * 8;                                       \
      gload_lds16(Wo + (size_t)(m0 + row) * DM + (K0_) + gs, (AD) + j * 2048 + w * 512); \
    }                                                                               \
    _Pragma("unroll")                                                               \
    for (int j = 0; j < 4; ++j) {                                                   \
      const int row = j * 32 + srow;                                                \
      const int gs = (sslot ^ (row & 7)) * 8;                                       \
      gload_lds16(Cx + (size_t)(n0 + row) * DM + (K0_) + gs, (BD) + j * 2048 + w * 512); \
    }                                                                               \
  } while (0)

  floatx4 acc[2][4] = {};
  OUT_STAGE(0, As[0], Bs[0]);
  int cb = 0;
  for (int k0 = 0; k0 < DM; k0 += 64) {
    if (k0 + 64 < DM) OUT_STAGE(k0 + 64, As[cb ^ 1], Bs[cb ^ 1]);
    __syncthreads();
#pragma unroll
    for (int kk = 0; kk < 2; ++kk) {
      short8v a[2], b[4];
#pragma unroll
      for (int i = 0; i < 2; ++i) {
        const int row = wr * 32 + i * 16 + c;
        a[i] = *(const short8v*)&As[cb][row * 64 + (((kk * 4 + g) ^ (row & 7)) * 8)];
      }
#pragma unroll
      for (int j = 0; j < 4; ++j) {
        const int row = wc * 64 + j * 16 + c;
        b[j] = *(const short8v*)&Bs[cb][row * 64 + (((kk * 4 + g) ^ (row & 7)) * 8)];
      }
#pragma unroll
      for (int i = 0; i < 2; ++i)
#pragma unroll
        for (int j = 0; j < 4; ++j)
          acc[i][j] = __builtin_amdgcn_mfma_f32_16x16x32_bf16(a[i], b[j], acc[i][j], 0, 0, 0);
    }
    __syncthreads();
    cb ^= 1;
  }
#undef OUT_STAGE
#pragma unroll
  for (int i = 0; i < 2; ++i) {
    const int e0 = m0 + wr * 32 + i * 16 + 4 * g;
#pragma unroll
    for (int j = 0; j < 4; ++j) {
      const int t = n0 + wc * 64 + j * 16 + c;
      *(floatx4*)&out[(size_t)t * DM + e0] = acc[i][j];
    }
  }
}

extern "C" void kernel_launch(void* const* d_in, const int* in_sizes, int n_in,
                              void* d_out, int out_size, void* d_ws, size_t ws_size,
                              hipStream_t stream) {
  const float* x    = (const float*)d_in[0];
  const int*   tpos = (const int*)d_in[1];
  const float* Wq   = (const float*)d_in[2];
  const float* Wo   = (const float*)d_in[3];
  float* out = (float*)d_out;

  const size_t QKV_BYTES = (size_t)NB * NH * SEQ * HD * 2;  // 6,291,456
  const size_t REQUIRED = 4 * QKV_BYTES;                    // 25,165,824
  if (ws_size < REQUIRED) return;

  char* ws = (char*)d_ws;
  __hip_bfloat16* Qb = (__hip_bfloat16*)(ws);
  __hip_bfloat16* Kb = (__hip_bfloat16*)(ws + QKV_BYTES);
  __hip_bfloat16* Vt = (__hip_bfloat16*)(ws + 2 * QKV_BYTES);
  __hip_bfloat16* Cx = (__hip_bfloat16*)(ws + 3 * QKV_BYTES);
  __hip_bfloat16* xb = (__hip_bfloat16*)(ws + 3 * QKV_BYTES);   // aliases Cx (dead before attn)
  char* ob = (char*)d_out;   // d_out-head scratch, all dead before out_gemm overwrites
  float2* rcs = (float2*)(ob);                                           // 512KB
  __hip_bfloat16* wqb = (__hip_bfloat16*)(ob + (size_t)SEQ * 32 * 8);    // 3.54MB
  __hip_bfloat16* wob = (__hip_bfloat16*)(ob + (size_t)SEQ * 32 * 8 + (size_t)E3 * DM * 2);  // 1.18MB
  int* qcnt = (int*)(ob + (size_t)SEQ * 32 * 8 + (size_t)E3 * DM * 2 + (size_t)DM * DM * 2); // 32B

  const int TOT_N = CVT_N + SEQ * 32;
  cvt3_rope<<<dim3((TOT_N + 255) / 256), dim3(256), 0, stream>>>(x, Wq, Wo, xb, wqb, wob, rcs, qcnt);
  qkv_gemm_rope<<<dim3(1152), dim3(256), 0, stream>>>(wqb, xb, tpos, rcs, Qb, Kb, Vt);
  attn_fused<<<dim3(512), dim3(512), 0, stream>>>(Qb, Kb, Vt, Cx, qcnt);
  out_gemm<<<dim3(384), dim3(256), 0, stream>>>(wob, Cx, out);
}

// Round 20
// 85.963 us; speedup vs baseline: 1.5649x; 1.0124x over previous
//
#include <hip/hip_runtime.h>
#include <hip/hip_bf16.h>
#include <math.h>

#define SEQ 2048
#define DM 768
#define NH 12
#define HD 64
#define NB 2
#define NT (NB*SEQ)      // 4096 tokens
#define E3 (3*DM)        // 2304

using short4v = __attribute__((ext_vector_type(4))) short;
using short8v = __attribute__((ext_vector_type(8))) short;
using floatx4 = __attribute__((ext_vector_type(4))) float;
using int4v   = __attribute__((ext_vector_type(4))) int;

#if __has_builtin(__builtin_amdgcn_exp2f)
#define EXPFN(x) __builtin_amdgcn_exp2f(x)
#define QSCALE 0.1803368801111244f   /* 0.125 * log2(e) : scores in log2 domain */
#else
#define EXPFN(x) __expf(x)
#define QSCALE 0.125f
#endif

static __device__ __forceinline__ short bfb(float f) {
  union { __hip_bfloat16 h; short s; } u;
  u.h = __float2bfloat16(f);
  return u.s;
}

// async global->LDS, 16 bytes per lane. lds must be wave-uniform.
static __device__ __forceinline__ void gload_lds16(const __hip_bfloat16* g, __hip_bfloat16* lds) {
  __builtin_amdgcn_global_load_lds(
      (const __attribute__((address_space(1))) unsigned int*)g,
      (__attribute__((address_space(3))) unsigned int*)lds, 16, 0, 0);
}

// K granule swizzle (16B granules, 8 per 128B row): rows 8a+b -> (a+2b)&7
static __device__ __forceinline__ int swzg(int row) {
  return (((row >> 3) & 3) + 2 * (row & 3)) & 7;
}

// ---------------- fused fp32->bf16 convert (x, Wq, Wo) + rope table + queue reset ----------------
#define XN4 (NT * DM / 4)          // 786432
#define WQN4 (E3 * DM / 4)         // 442368
#define WON4 (DM * DM / 4)         // 147456
#define CVT_N (XN4 + WQN4 + WON4)  // 1376256
__global__ void cvt3_rope(const float* __restrict__ x, const float* __restrict__ wq,
                          const float* __restrict__ wo,
                          __hip_bfloat16* __restrict__ xb, __hip_bfloat16* __restrict__ wqb,
                          __hip_bfloat16* __restrict__ wob, float2* __restrict__ rcs,
                          int* __restrict__ qcnt) {
  int i = blockIdx.x * blockDim.x + threadIdx.x;
  if (blockIdx.x == 0 && threadIdx.x < 8) qcnt[threadIdx.x] = 0;  // per-XCD LPT queues
  if (i >= CVT_N) {
    int idx = i - CVT_N;
    if (idx < SEQ * 32) {
      int pos = idx >> 5, j = idx & 31;
      float freq = __expf(-(float)j * (logf(10000.0f) / 32.0f));
      float ang = (float)pos * freq;
      rcs[idx] = make_float2(cosf(ang), sinf(ang));
    }
    return;
  }
  const float* src;
  __hip_bfloat16* dst;
  int k;
  if (i < XN4) { src = x; dst = xb; k = i; }
  else if (i < XN4 + WQN4) { src = wq; dst = wqb; k = i - XN4; }
  else { src = wo; dst = wob; k = i - XN4 - WQN4; }
  floatx4 v = ((const floatx4*)src)[k];
  short4v o;
  o[0] = bfb(v[0]); o[1] = bfb(v[1]); o[2] = bfb(v[2]); o[3] = bfb(v[3]);
  ((short4v*)dst)[k] = o;
}

// ---------------- QKV GEMM v4: 64x128 tile, BK=64, double-buffered (R19) ----------------
__global__ __launch_bounds__(256) void qkv_gemm_rope(
    const __hip_bfloat16* __restrict__ Wq,
    const __hip_bfloat16* __restrict__ Xb,
    const int* __restrict__ tpos,
    const float2* __restrict__ rcs,
    __hip_bfloat16* __restrict__ Qb, __hip_bfloat16* __restrict__ Kb,
    __hip_bfloat16* __restrict__ Vt)
{
  __shared__ __align__(16) __hip_bfloat16 As[2][64 * 64];    // 8KB each
  __shared__ __align__(16) __hip_bfloat16 Bs[2][128 * 64];   // 16KB each
  const int tid = threadIdx.x;
  const int lane = tid & 63, w = tid >> 6;
  const int c = lane & 15, g = lane >> 4;
  const int wr = w >> 1, wc = w & 1;
  const int bid = blockIdx.x;
  const int xcd = bid & 7, i_ = bid >> 3;        // 144 per XCD
  const int nb = xcd * 4 + (i_ & 3), mb = i_ >> 2;  // nb 0..31, mb 0..35
  const int m0 = mb * 64, n0 = nb * 128;
  const int srow = tid >> 3, sslot = tid & 7;    // 32 rows x 8 slots per call

#define QKV_STAGE(K0_, AD, BD)                                                      \
  do {                                                                              \
    _Pragma("unroll")                                                               \
    for (int j = 0; j < 2; ++j) {                                                   \
      const int row = j * 32 + srow;                                                \
      const int gs = (sslot ^ (row & 7)) * 8;                                       \
      gload_lds16(Wq + (size_t)(m0 + row) * DM + (K0_) + gs, (AD) + j * 2048 + w * 512); \
    }                                                                               \
    _Pragma("unroll")                                                               \
    for (int j = 0; j < 4; ++j) {                                                   \
      const int row = j * 32 + srow;                                                \
      const int gs = (sslot ^ (row & 7)) * 8;                                       \
      gload_lds16(Xb + (size_t)(n0 + row) * DM + (K0_) + gs, (BD) + j * 2048 + w * 512); \
    }                                                                               \
  } while (0)

  floatx4 acc[2][4] = {};
  QKV_STAGE(0, As[0], Bs[0]);
  int cb = 0;
  for (int k0 = 0; k0 < DM; k0 += 64) {
    if (k0 + 64 < DM) QKV_STAGE(k0 + 64, As[cb ^ 1], Bs[cb ^ 1]);
    __syncthreads();   // drains stage(k0) — issued one full step ago
#pragma unroll
    for (int kk = 0; kk < 2; ++kk) {
      short8v a[2], b[4];
#pragma unroll
      for (int i = 0; i < 2; ++i) {
        const int row = wr * 32 + i * 16 + c;
        a[i] = *(const short8v*)&As[cb][row * 64 + (((kk * 4 + g) ^ (row & 7)) * 8)];
      }
#pragma unroll
      for (int j = 0; j < 4; ++j) {
        const int row = wc * 64 + j * 16 + c;
        b[j] = *(const short8v*)&Bs[cb][row * 64 + (((kk * 4 + g) ^ (row & 7)) * 8)];
      }
#pragma unroll
      for (int i = 0; i < 2; ++i)
#pragma unroll
        for (int j = 0; j < 4; ++j)
          acc[i][j] = __builtin_amdgcn_mfma_f32_16x16x32_bf16(a[i], b[j], acc[i][j], 0, 0, 0);
    }
    __syncthreads();   // buf[cb] consumed -> reusable for the stage in flight
    cb ^= 1;
  }
#undef QKV_STAGE
#pragma unroll
  for (int i = 0; i < 2; ++i) {
    const int e0 = m0 + wr * 32 + i * 16 + 4 * g;
    const int jj = (e0 & 63) >> 1;
#pragma unroll
    for (int j = 0; j < 4; ++j) {
      const int t = n0 + wc * 64 + j * 16 + c;
      const int b_ = t >> 11, s = t & (SEQ - 1);
      float v0 = acc[i][j][0], v1 = acc[i][j][1], v2 = acc[i][j][2], v3 = acc[i][j][3];
      if (e0 < 2 * DM) {
        const int pos = tpos[t];
        const float2 cs0 = rcs[pos * 32 + jj];
        const float2 cs1 = rcs[pos * 32 + jj + 1];
        const float n0v = v0 * cs0.x - v1 * cs0.y, n1v = v0 * cs0.y + v1 * cs0.x;
        const float n2v = v2 * cs1.x - v3 * cs1.y, n3v = v2 * cs1.y + v3 * cs1.x;
        v0 = n0v; v1 = n1v; v2 = n2v; v3 = n3v;
      }
      if (e0 < DM) {
        const int h = e0 >> 6, d = e0 & 63;
        short4v pk;
        pk[0] = bfb(v0 * QSCALE); pk[1] = bfb(v1 * QSCALE);
        pk[2] = bfb(v2 * QSCALE); pk[3] = bfb(v3 * QSCALE);
        *(short4v*)&Qb[(((size_t)(b_ * NH + h) * SEQ) + s) * HD + d] = pk;
      } else if (e0 < 2 * DM) {
        const int e = e0 - DM, h = e >> 6, d = e & 63;
        short4v pk;
        pk[0] = bfb(v0); pk[1] = bfb(v1); pk[2] = bfb(v2); pk[3] = bfb(v3);
        *(short4v*)&Kb[(((size_t)(b_ * NH + h) * SEQ) + s) * HD + d] = pk;
      } else {
        const int e = e0 - 2 * DM, h = e >> 6, d = e & 63;
        const size_t base = ((size_t)(b_ * NH + h) * HD + d) * SEQ + s;
        Vt[base]           = __float2bfloat16(v0);
        Vt[base + SEQ]     = __float2bfloat16(v1);
        Vt[base + 2 * SEQ] = __float2bfloat16(v2);
        Vt[base + 3 * SEQ] = __float2bfloat16(v3);
      }
    }
  }
}

// ---------------- fused causal flash attention v12: LPT queue + T5 setprio ----------------
// R18 structure; ONLY change: s_setprio(1) around the QK and PV MFMA clusters
// (clean A/B — R10 bundled setprio with a regressing schedule, never isolated).
__global__ __launch_bounds__(512) void attn_fused(
    const __hip_bfloat16* __restrict__ Qb,
    const __hip_bfloat16* __restrict__ Kb,
    const __hip_bfloat16* __restrict__ Vt,
    __hip_bfloat16* __restrict__ Cx,
    int* __restrict__ qcnt)
{
  __shared__ __align__(16) __hip_bfloat16 Ks[2][128 * 64];  // 16KB each
  __shared__ __align__(16) __hip_bfloat16 Vs[2][64 * 128];  // V^T: [d][kt], 16KB each
  __shared__ int task_s;
  const int tid = threadIdx.x;
  const int lane = tid & 63, w = tid >> 6;          // 8 waves
  const int c = lane & 15, g = lane >> 4;
  const int xcd = blockIdx.x & 7;
  const int kr1 = 8 * (c >> 2) + (c & 3);           // permuted A-row -> kt_local
  const int ksr = w * 8 + (lane >> 3), kss = lane & 7;     // K stage: rows +64*j
  const int vsr = w * 4 + (lane >> 4), vss = lane & 15;    // V stage: rows +32*j

  for (;;) {
    if (tid == 0) task_s = atomicAdd(&qcnt[xcd], 1);
    __syncthreads();
    const int task = task_s;
    if (task >= 48) return;
    const int qG = 15 - task / 3;                   // descending size (LPT)
    const int bh = xcd + 8 * (task % 3);
    const int KBmax = qG;                           // kb = 0..qG (128 keys each)
    const __hip_bfloat16* Qh = Qb + (size_t)bh * SEQ * HD;
    const __hip_bfloat16* Kh = Kb + (size_t)bh * SEQ * HD;
    const __hip_bfloat16* Vh = Vt + (size_t)bh * HD * SEQ;
    const int q1 = qG * 128 + w * 16 + c;           // absolute q-row of this lane
    const int qt_w = 4 * qG + (w >> 1);             // wave's causal 32-key sub-block limit
    const int qrl32 = (w & 1) * 16 + c;             // row within the diagonal 32-key window
    const short8v qf10 = *(const short8v*)&Qh[(size_t)q1 * HD + g * 8];
    const short8v qf11 = *(const short8v*)&Qh[(size_t)q1 * HD + 32 + g * 8];
    floatx4 o1[4] = {};
    float l1 = 0.0f;

#define STAGE_KV(KB_, KSD, VSD)                                                      \
    do {                                                                             \
      _Pragma("unroll")                                                              \
      for (int j = 0; j < 2; ++j) {                                                  \
        const int kr = j * 64 + ksr;                                                 \
        gload_lds16(Kh + (size_t)((KB_) * 128 + kr) * HD + ((kss ^ swzg(kr)) * 8),   \
                    (KSD) + j * 4096 + w * 512);                                     \
        const int vr = j * 32 + vsr;                                                 \
        gload_lds16(Vh + (size_t)vr * SEQ + (KB_) * 128 + ((vss ^ (vr & 15)) * 8),   \
                    (VSD) + j * 4096 + w * 512);                                     \
      }                                                                              \
    } while (0)

    STAGE_KV(0, Ks[0], Vs[0]);
    __syncthreads();
    int cb = 0;
    for (int kb = 0; kb <= KBmax; ++kb) {
      if (kb < KBmax) STAGE_KV(kb + 1, Ks[cb ^ 1], Vs[cb ^ 1]);
      {
        const __hip_bfloat16* Kt = Ks[cb];
        const __hip_bfloat16* Vb = Vs[cb];
#pragma unroll
        for (int s = 0; s < 4; ++s) {
          const int kidx = 4 * kb + s;
          if (kidx <= qt_w) {
            const int r0 = s * 32 + kr1, r1 = r0 + 4;
            const int z0 = swzg(r0), z1 = swzg(r1);
            const short8v a00 = *(const short8v*)&Kt[r0 * 64 + ((g ^ z0) * 8)];
            const short8v a01 = *(const short8v*)&Kt[r0 * 64 + (((4 + g) ^ z0) * 8)];
            const short8v a10 = *(const short8v*)&Kt[r1 * 64 + ((g ^ z1) * 8)];
            const short8v a11 = *(const short8v*)&Kt[r1 * 64 + (((4 + g) ^ z1) * 8)];
            short8v vf[4];
#pragma unroll
            for (int f = 0; f < 4; ++f) {
              const int rv = f * 16 + c;
              vf[f] = *(const short8v*)&Vb[rv * 128 + (((s * 4 + g) ^ (rv & 15)) * 8)];
            }
            floatx4 s1a = {}, s1b = {};
            __builtin_amdgcn_s_setprio(1);
            s1a = __builtin_amdgcn_mfma_f32_16x16x32_bf16(a00, qf10, s1a, 0, 0, 0);
            s1a = __builtin_amdgcn_mfma_f32_16x16x32_bf16(a01, qf11, s1a, 0, 0, 0);
            s1b = __builtin_amdgcn_mfma_f32_16x16x32_bf16(a10, qf10, s1b, 0, 0, 0);
            s1b = __builtin_amdgcn_mfma_f32_16x16x32_bf16(a11, qf11, s1b, 0, 0, 0);
            __builtin_amdgcn_s_setprio(0);
            if (kidx == qt_w) {  // diagonal 32-key window: mask keys > own row
#pragma unroll
              for (int r = 0; r < 4; ++r) {
                if (8 * g + r > qrl32) s1a[r] = -INFINITY;
                if (8 * g + r + 4 > qrl32) s1b[r] = -INFINITY;
              }
            }
            short8v pf1;
#pragma unroll
            for (int r = 0; r < 4; ++r) {
              float p;
              p = EXPFN(s1a[r]); l1 += p; pf1[r] = bfb(p);
              p = EXPFN(s1b[r]); l1 += p; pf1[r + 4] = bfb(p);
            }
            __builtin_amdgcn_s_setprio(1);
            o1[0] = __builtin_amdgcn_mfma_f32_16x16x32_bf16(vf[0], pf1, o1[0], 0, 0, 0);
            o1[1] = __builtin_amdgcn_mfma_f32_16x16x32_bf16(vf[1], pf1, o1[1], 0, 0, 0);
            o1[2] = __builtin_amdgcn_mfma_f32_16x16x32_bf16(vf[2], pf1, o1[2], 0, 0, 0);
            o1[3] = __builtin_amdgcn_mfma_f32_16x16x32_bf16(vf[3], pf1, o1[3], 0, 0, 0);
            __builtin_amdgcn_s_setprio(0);
          }
        }
      }
      __syncthreads();
      cb ^= 1;
    }
#undef STAGE_KV

    l1 += __shfl_xor(l1, 16); l1 += __shfl_xor(l1, 32);
    const float inv1 = 1.0f / l1;
    const int bb = bh / NH, h = bh - bb * NH;
    const size_t trow1 = ((size_t)bb * SEQ + q1) * DM + (size_t)h * HD;
#pragma unroll
    for (int f = 0; f < 4; ++f) {
      short4v pk1;
#pragma unroll
      for (int r = 0; r < 4; ++r) pk1[r] = bfb(o1[f][r] * inv1);
      *(short4v*)&Cx[trow1 + f * 16 + 4 * g] = pk1;
    }
  }
}

// ---------------- output GEMM v3: 64x128 tile, BK=64, double-buffered (R19) ----------------
__global__ __launch_bounds__(256) void out_gemm(
    const __hip_bfloat16* __restrict__ Wo,
    const __hip_bfloat16* __restrict__ Cx,
    float* __restrict__ out)
{
  __shared__ __align__(16) __hip_bfloat16 As[2][64 * 64];    // 8KB each
  __shared__ __align__(16) __hip_bfloat16 Bs[2][128 * 64];   // 16KB each
  const int tid = threadIdx.x;
  const int lane = tid & 63, w = tid >> 6;
  const int c = lane & 15, g = lane >> 4;
  const int wr = w >> 1, wc = w & 1;
  const int bid = blockIdx.x;
  const int xcd = bid & 7, i_ = bid >> 3;        // 48 per XCD
  const int nb = xcd * 4 + (i_ & 3), mb = i_ >> 2;  // nb 0..31 (t), mb 0..11 (e)
  const int m0 = mb * 64, n0 = nb * 128;
  const int srow = tid >> 3, sslot = tid & 7;

#define OUT_STAGE(K0_, AD, BD)                                                      \
  do {                                                                              \
    _Pragma("unroll")                                                               \
    for (int j = 0; j < 2; ++j) {                                                   \
      const int row = j * 32 + srow;                                                \
      const int gs = (sslot ^ (row & 7)) * 8;                                       \
      gload_lds16(Wo + (size_t)(m0 + row) * DM + (K0_) + gs, (AD) + j * 2048 + w * 512); \
    }                                                                               \
    _Pragma("unroll")                                                               \
    for (int j = 0; j < 4; ++j) {                                                   \
      const int row = j * 32 + srow;                                                \
      const int gs = (sslot ^ (row & 7)) * 8;                                       \
      gload_lds16(Cx + (size_t)(n0 + row) * DM + (K0_) + gs, (BD) + j * 2048 + w * 512); \
    }                                                                               \
  } while (0)

  floatx4 acc[2][4] = {};
  OUT_STAGE(0, As[0], Bs[0]);
  int cb = 0;
  for (int k0 = 0; k0 < DM; k0 += 64) {
    if (k0 + 64 < DM) OUT_STAGE(k0 + 64, As[cb ^ 1], Bs[cb ^ 1]);
    __syncthreads();
#pragma unroll
    for (int kk = 0; kk < 2; ++kk) {
      short8v a[2], b[4];
#pragma unroll
      for (int i = 0; i < 2; ++i) {
        const int row = wr * 32 + i * 16 + c;
        a[i] = *(const short8v*)&As[cb][row * 64 + (((kk * 4 + g) ^ (row & 7)) * 8)];
      }
#pragma unroll
      for (int j = 0; j < 4; ++j) {
        const int row = wc * 64 + j * 16 + c;
        b[j] = *(const short8v*)&Bs[cb][row * 64 + (((kk * 4 + g) ^ (row & 7)) * 8)];
      }
#pragma unroll
      for (int i = 0; i < 2; ++i)
#pragma unroll
        for (int j = 0; j < 4; ++j)
          acc[i][j] = __builtin_amdgcn_mfma_f32_16x16x32_bf16(a[i], b[j], acc[i][j], 0, 0, 0);
    }
    __syncthreads();
    cb ^= 1;
  }
#undef OUT_STAGE
#pragma unroll
  for (int i = 0; i < 2; ++i) {
    const int e0 = m0 + wr * 32 + i * 16 + 4 * g;
#pragma unroll
    for (int j = 0; j < 4; ++j) {
      const int t = n0 + wc * 64 + j * 16 + c;
      *(floatx4*)&out[(size_t)t * DM + e0] = acc[i][j];
    }
  }
}

extern "C" void kernel_launch(void* const* d_in, const int* in_sizes, int n_in,
                              void* d_out, int out_size, void* d_ws, size_t ws_size,
                              hipStream_t stream) {
  const float* x    = (const float*)d_in[0];
  const int*   tpos = (const int*)d_in[1];
  const float* Wq   = (const float*)d_in[2];
  const float* Wo   = (const float*)d_in[3];
  float* out = (float*)d_out;

  const size_t QKV_BYTES = (size_t)NB * NH * SEQ * HD * 2;  // 6,291,456
  const size_t REQUIRED = 4 * QKV_BYTES;                    // 25,165,824
  if (ws_size < REQUIRED) return;

  char* ws = (char*)d_ws;
  __hip_bfloat16* Qb = (__hip_bfloat16*)(ws);
  __hip_bfloat16* Kb = (__hip_bfloat16*)(ws + QKV_BYTES);
  __hip_bfloat16* Vt = (__hip_bfloat16*)(ws + 2 * QKV_BYTES);
  __hip_bfloat16* Cx = (__hip_bfloat16*)(ws + 3 * QKV_BYTES);
  __hip_bfloat16* xb = (__hip_bfloat16*)(ws + 3 * QKV_BYTES);   // aliases Cx (dead before attn)
  char* ob = (char*)d_out;   // d_out-head scratch, all dead before out_gemm overwrites
  float2* rcs = (float2*)(ob);                                           // 512KB
  __hip_bfloat16* wqb = (__hip_bfloat16*)(ob + (size_t)SEQ * 32 * 8);    // 3.54MB
  __hip_bfloat16* wob = (__hip_bfloat16*)(ob + (size_t)SEQ * 32 * 8 + (size_t)E3 * DM * 2);  // 1.18MB
  int* qcnt = (int*)(ob + (size_t)SEQ * 32 * 8 + (size_t)E3 * DM * 2 + (size_t)DM * DM * 2); // 32B

  const int TOT_N = CVT_N + SEQ * 32;
  cvt3_rope<<<dim3((TOT_N + 255) / 256), dim3(256), 0, stream>>>(x, Wq, Wo, xb, wqb, wob, rcs, qcnt);
  qkv_gemm_rope<<<dim3(1152), dim3(256), 0, stream>>>(wqb, xb, tpos, rcs, Qb, Kb, Vt);
  attn_fused<<<dim3(512), dim3(512), 0, stream>>>(Qb, Kb, Vt, Cx, qcnt);
  out_gemm<<<dim3(384), dim3(256), 0, stream>>>(wob, Cx, out);
}

// Round 21
// 83.316 us; speedup vs baseline: 1.6146x; 1.0318x over previous
//
#include <hip/hip_runtime.h>
#include <hip/hip_bf16.h>
#include <math.h>

#define SEQ 2048
#define DM 768
#define NH 12
#define HD 64
#define NB 2
#define NT (NB*SEQ)      // 4096 tokens
#define E3 (3*DM)        // 2304

using short4v = __attribute__((ext_vector_type(4))) short;
using short8v = __attribute__((ext_vector_type(8))) short;
using floatx4 = __attribute__((ext_vector_type(4))) float;
using int4v   = __attribute__((ext_vector_type(4))) int;

#if __has_builtin(__builtin_amdgcn_exp2f)
#define EXPFN(x) __builtin_amdgcn_exp2f(x)
#define QSCALE 0.1803368801111244f   /* 0.125 * log2(e) : scores in log2 domain */
#else
#define EXPFN(x) __expf(x)
#define QSCALE 0.125f
#endif

static __device__ __forceinline__ short bfb(float f) {
  union { __hip_bfloat16 h; short s; } u;
  u.h = __float2bfloat16(f);
  return u.s;
}

// async global->LDS, 16 bytes per lane. lds must be wave-uniform.
static __device__ __forceinline__ void gload_lds16(const __hip_bfloat16* g, __hip_bfloat16* lds) {
  __builtin_amdgcn_global_load_lds(
      (const __attribute__((address_space(1))) unsigned int*)g,
      (__attribute__((address_space(3))) unsigned int*)lds, 16, 0, 0);
}

// K granule swizzle (16B granules, 8 per 128B row): rows 8a+b -> (a+2b)&7
static __device__ __forceinline__ int swzg(int row) {
  return (((row >> 3) & 3) + 2 * (row & 3)) & 7;
}

// ---------------- fused fp32->bf16 convert (x, Wq, Wo) + rope table + queue reset ----------------
#define XN4 (NT * DM / 4)          // 786432
#define WQN4 (E3 * DM / 4)         // 442368
#define WON4 (DM * DM / 4)         // 147456
#define CVT_N (XN4 + WQN4 + WON4)  // 1376256
__global__ void cvt3_rope(const float* __restrict__ x, const float* __restrict__ wq,
                          const float* __restrict__ wo,
                          __hip_bfloat16* __restrict__ xb, __hip_bfloat16* __restrict__ wqb,
                          __hip_bfloat16* __restrict__ wob, float2* __restrict__ rcs,
                          int* __restrict__ qcnt) {
  int i = blockIdx.x * blockDim.x + threadIdx.x;
  if (blockIdx.x == 0 && threadIdx.x < 8) qcnt[threadIdx.x] = 0;  // per-XCD LPT queues
  if (i >= CVT_N) {
    int idx = i - CVT_N;
    if (idx < SEQ * 32) {
      int pos = idx >> 5, j = idx & 31;
      float freq = __expf(-(float)j * (logf(10000.0f) / 32.0f));
      float ang = (float)pos * freq;
      rcs[idx] = make_float2(cosf(ang), sinf(ang));
    }
    return;
  }
  const float* src;
  __hip_bfloat16* dst;
  int k;
  if (i < XN4) { src = x; dst = xb; k = i; }
  else if (i < XN4 + WQN4) { src = wq; dst = wqb; k = i - XN4; }
  else { src = wo; dst = wob; k = i - XN4 - WQN4; }
  floatx4 v = ((const floatx4*)src)[k];
  short4v o;
  o[0] = bfb(v[0]); o[1] = bfb(v[1]); o[2] = bfb(v[2]); o[3] = bfb(v[3]);
  ((short4v*)dst)[k] = o;
}

// ---------------- QKV GEMM v4: 64x128 tile, BK=64, double-buffered (R19) ----------------
__global__ __launch_bounds__(256) void qkv_gemm_rope(
    const __hip_bfloat16* __restrict__ Wq,
    const __hip_bfloat16* __restrict__ Xb,
    const int* __restrict__ tpos,
    const float2* __restrict__ rcs,
    __hip_bfloat16* __restrict__ Qb, __hip_bfloat16* __restrict__ Kb,
    __hip_bfloat16* __restrict__ Vt)
{
  __shared__ __align__(16) __hip_bfloat16 As[2][64 * 64];    // 8KB each
  __shared__ __align__(16) __hip_bfloat16 Bs[2][128 * 64];   // 16KB each
  const int tid = threadIdx.x;
  const int lane = tid & 63, w = tid >> 6;
  const int c = lane & 15, g = lane >> 4;
  const int wr = w >> 1, wc = w & 1;
  const int bid = blockIdx.x;
  const int xcd = bid & 7, i_ = bid >> 3;        // 144 per XCD
  const int nb = xcd * 4 + (i_ & 3), mb = i_ >> 2;  // nb 0..31, mb 0..35
  const int m0 = mb * 64, n0 = nb * 128;
  const int srow = tid >> 3, sslot = tid & 7;    // 32 rows x 8 slots per call

#define QKV_STAGE(K0_, AD, BD)                                                      \
  do {                                                                              \
    _Pragma("unroll")                                                               \
    for (int j = 0; j < 2; ++j) {                                                   \
      const int row = j * 32 + srow;                                                \
      const int gs = (sslot ^ (row & 7)) * 8;                                       \
      gload_lds16(Wq + (size_t)(m0 + row) * DM + (K0_) + gs, (AD) + j * 2048 + w * 512); \
    }                                                                               \
    _Pragma("unroll")                                                               \
    for (int j = 0; j < 4; ++j) {                                                   \
      const int row = j * 32 + srow;                                                \
      const int gs = (sslot ^ (row & 7)) * 8;                                       \
      gload_lds16(Xb + (size_t)(n0 + row) * DM + (K0_) + gs, (BD) + j * 2048 + w * 512); \
    }                                                                               \
  } while (0)

  floatx4 acc[2][4] = {};
  QKV_STAGE(0, As[0], Bs[0]);
  int cb = 0;
  for (int k0 = 0; k0 < DM; k0 += 64) {
    if (k0 + 64 < DM) QKV_STAGE(k0 + 64, As[cb ^ 1], Bs[cb ^ 1]);
    __syncthreads();   // drains stage(k0) — issued one full step ago
#pragma unroll
    for (int kk = 0; kk < 2; ++kk) {
      short8v a[2], b[4];
#pragma unroll
      for (int i = 0; i < 2; ++i) {
        const int row = wr * 32 + i * 16 + c;
        a[i] = *(const short8v*)&As[cb][row * 64 + (((kk * 4 + g) ^ (row & 7)) * 8)];
      }
#pragma unroll
      for (int j = 0; j < 4; ++j) {
        const int row = wc * 64 + j * 16 + c;
        b[j] = *(const short8v*)&Bs[cb][row * 64 + (((kk * 4 + g) ^ (row & 7)) * 8)];
      }
#pragma unroll
      for (int i = 0; i < 2; ++i)
#pragma unroll
        for (int j = 0; j < 4; ++j)
          acc[i][j] = __builtin_amdgcn_mfma_f32_16x16x32_bf16(a[i], b[j], acc[i][j], 0, 0, 0);
    }
    __syncthreads();   // buf[cb] consumed -> reusable for the stage in flight
    cb ^= 1;
  }
#undef QKV_STAGE
#pragma unroll
  for (int i = 0; i < 2; ++i) {
    const int e0 = m0 + wr * 32 + i * 16 + 4 * g;
    const int jj = (e0 & 63) >> 1;
#pragma unroll
    for (int j = 0; j < 4; ++j) {
      const int t = n0 + wc * 64 + j * 16 + c;
      const int b_ = t >> 11, s = t & (SEQ - 1);
      float v0 = acc[i][j][0], v1 = acc[i][j][1], v2 = acc[i][j][2], v3 = acc[i][j][3];
      if (e0 < 2 * DM) {
        const int pos = tpos[t];
        const float2 cs0 = rcs[pos * 32 + jj];
        const float2 cs1 = rcs[pos * 32 + jj + 1];
        const float n0v = v0 * cs0.x - v1 * cs0.y, n1v = v0 * cs0.y + v1 * cs0.x;
        const float n2v = v2 * cs1.x - v3 * cs1.y, n3v = v2 * cs1.y + v3 * cs1.x;
        v0 = n0v; v1 = n1v; v2 = n2v; v3 = n3v;
      }
      if (e0 < DM) {
        const int h = e0 >> 6, d = e0 & 63;
        short4v pk;
        pk[0] = bfb(v0 * QSCALE); pk[1] = bfb(v1 * QSCALE);
        pk[2] = bfb(v2 * QSCALE); pk[3] = bfb(v3 * QSCALE);
        *(short4v*)&Qb[(((size_t)(b_ * NH + h) * SEQ) + s) * HD + d] = pk;
      } else if (e0 < 2 * DM) {
        const int e = e0 - DM, h = e >> 6, d = e & 63;
        short4v pk;
        pk[0] = bfb(v0); pk[1] = bfb(v1); pk[2] = bfb(v2); pk[3] = bfb(v3);
        *(short4v*)&Kb[(((size_t)(b_ * NH + h) * SEQ) + s) * HD + d] = pk;
      } else {
        const int e = e0 - 2 * DM, h = e >> 6, d = e & 63;
        const size_t base = ((size_t)(b_ * NH + h) * HD + d) * SEQ + s;
        Vt[base]           = __float2bfloat16(v0);
        Vt[base + SEQ]     = __float2bfloat16(v1);
        Vt[base + 2 * SEQ] = __float2bfloat16(v2);
        Vt[base + 3 * SEQ] = __float2bfloat16(v3);
      }
    }
  }
}

// ---------------- fused causal flash attention v13: peeled fast path ----------------
// R20 structure (8-wave, KVBLK=128, LPT queue, setprio); change: for kb <
// KBmax every wave's 4 sub-blocks are provably unguarded and unmasked
// (diagonal lives in kb == KBmax), so they run as ONE branch-free region —
// the scheduler can interleave 4 independent sub-block chains (16 MFMA,
// 24 LDS reads, 32 exp). kb == KBmax keeps the guarded+masked tail.
__global__ __launch_bounds__(512) void attn_fused(
    const __hip_bfloat16* __restrict__ Qb,
    const __hip_bfloat16* __restrict__ Kb,
    const __hip_bfloat16* __restrict__ Vt,
    __hip_bfloat16* __restrict__ Cx,
    int* __restrict__ qcnt)
{
  __shared__ __align__(16) __hip_bfloat16 Ks[2][128 * 64];  // 16KB each
  __shared__ __align__(16) __hip_bfloat16 Vs[2][64 * 128];  // V^T: [d][kt], 16KB each
  __shared__ int task_s;
  const int tid = threadIdx.x;
  const int lane = tid & 63, w = tid >> 6;          // 8 waves
  const int c = lane & 15, g = lane >> 4;
  const int xcd = blockIdx.x & 7;
  const int kr1 = 8 * (c >> 2) + (c & 3);           // permuted A-row -> kt_local
  const int ksr = w * 8 + (lane >> 3), kss = lane & 7;     // K stage: rows +64*j
  const int vsr = w * 4 + (lane >> 4), vss = lane & 15;    // V stage: rows +32*j

  for (;;) {
    if (tid == 0) task_s = atomicAdd(&qcnt[xcd], 1);
    __syncthreads();
    const int task = task_s;
    if (task >= 48) return;
    const int qG = 15 - task / 3;                   // descending size (LPT)
    const int bh = xcd + 8 * (task % 3);
    const int KBmax = qG;                           // kb = 0..qG (128 keys each)
    const __hip_bfloat16* Qh = Qb + (size_t)bh * SEQ * HD;
    const __hip_bfloat16* Kh = Kb + (size_t)bh * SEQ * HD;
    const __hip_bfloat16* Vh = Vt + (size_t)bh * HD * SEQ;
    const int q1 = qG * 128 + w * 16 + c;           // absolute q-row of this lane
    const int qrl32 = (w & 1) * 16 + c;             // row within the diagonal 32-key window
    const int sdiag = w >> 1;                       // wave's diagonal sub-block (in kb==KBmax)
    const short8v qf10 = *(const short8v*)&Qh[(size_t)q1 * HD + g * 8];
    const short8v qf11 = *(const short8v*)&Qh[(size_t)q1 * HD + 32 + g * 8];
    floatx4 o1[4] = {};
    float l1 = 0.0f;

#define STAGE_KV(KB_, KSD, VSD)                                                      \
    do {                                                                             \
      _Pragma("unroll")                                                              \
      for (int j = 0; j < 2; ++j) {                                                  \
        const int kr = j * 64 + ksr;                                                 \
        gload_lds16(Kh + (size_t)((KB_) * 128 + kr) * HD + ((kss ^ swzg(kr)) * 8),   \
                    (KSD) + j * 4096 + w * 512);                                     \
        const int vr = j * 32 + vsr;                                                 \
        gload_lds16(Vh + (size_t)vr * SEQ + (KB_) * 128 + ((vss ^ (vr & 15)) * 8),   \
                    (VSD) + j * 4096 + w * 512);                                     \
      }                                                                              \
    } while (0)

// one 32-key sub-block: QK (setprio-wrapped), optional mask, exp, PV
#define SUBBLK(S_, DO_MASK)                                                          \
    do {                                                                             \
      const int r0 = (S_) * 32 + kr1, r1 = r0 + 4;                                   \
      const int z0 = swzg(r0), z1 = swzg(r1);                                        \
      const short8v a00 = *(const short8v*)&Kt[r0 * 64 + ((g ^ z0) * 8)];            \
      const short8v a01 = *(const short8v*)&Kt[r0 * 64 + (((4 + g) ^ z0) * 8)];      \
      const short8v a10 = *(const short8v*)&Kt[r1 * 64 + ((g ^ z1) * 8)];            \
      const short8v a11 = *(const short8v*)&Kt[r1 * 64 + (((4 + g) ^ z1) * 8)];      \
      short8v vf[4];                                                                 \
      _Pragma("unroll")                                                              \
      for (int f = 0; f < 4; ++f) {                                                  \
        const int rv = f * 16 + c;                                                   \
        vf[f] = *(const short8v*)&Vb[rv * 128 + ((((S_) * 4 + g) ^ (rv & 15)) * 8)]; \
      }                                                                              \
      floatx4 s1a = {}, s1b = {};                                                    \
      __builtin_amdgcn_s_setprio(1);                                                 \
      s1a = __builtin_amdgcn_mfma_f32_16x16x32_bf16(a00, qf10, s1a, 0, 0, 0);        \
      s1a = __builtin_amdgcn_mfma_f32_16x16x32_bf16(a01, qf11, s1a, 0, 0, 0);        \
      s1b = __builtin_amdgcn_mfma_f32_16x16x32_bf16(a10, qf10, s1b, 0, 0, 0);        \
      s1b = __builtin_amdgcn_mfma_f32_16x16x32_bf16(a11, qf11, s1b, 0, 0, 0);        \
      __builtin_amdgcn_s_setprio(0);                                                 \
      if (DO_MASK) {                                                                 \
        _Pragma("unroll")                                                            \
        for (int r = 0; r < 4; ++r) {                                                \
          if (8 * g + r > qrl32) s1a[r] = -INFINITY;                                 \
          if (8 * g + r + 4 > qrl32) s1b[r] = -INFINITY;                             \
        }                                                                            \
      }                                                                              \
      short8v pf1;                                                                   \
      _Pragma("unroll")                                                              \
      for (int r = 0; r < 4; ++r) {                                                  \
        float p;                                                                     \
        p = EXPFN(s1a[r]); l1 += p; pf1[r] = bfb(p);                                 \
        p = EXPFN(s1b[r]); l1 += p; pf1[r + 4] = bfb(p);                             \
      }                                                                              \
      __builtin_amdgcn_s_setprio(1);                                                 \
      o1[0] = __builtin_amdgcn_mfma_f32_16x16x32_bf16(vf[0], pf1, o1[0], 0, 0, 0);   \
      o1[1] = __builtin_amdgcn_mfma_f32_16x16x32_bf16(vf[1], pf1, o1[1], 0, 0, 0);   \
      o1[2] = __builtin_amdgcn_mfma_f32_16x16x32_bf16(vf[2], pf1, o1[2], 0, 0, 0);   \
      o1[3] = __builtin_amdgcn_mfma_f32_16x16x32_bf16(vf[3], pf1, o1[3], 0, 0, 0);   \
      __builtin_amdgcn_s_setprio(0);                                                 \
    } while (0)

    STAGE_KV(0, Ks[0], Vs[0]);
    __syncthreads();
    int cb = 0;
    for (int kb = 0; kb <= KBmax; ++kb) {
      if (kb < KBmax) STAGE_KV(kb + 1, Ks[cb ^ 1], Vs[cb ^ 1]);
      {
        const __hip_bfloat16* Kt = Ks[cb];
        const __hip_bfloat16* Vb = Vs[cb];
        if (kb < KBmax) {
          // fast path: every sub-block fully causal for every wave
          // (4kb+3 < 4*KBmax <= qt_w) — branch-free, mask-free.
          SUBBLK(0, false);
          SUBBLK(1, false);
          SUBBLK(2, false);
          SUBBLK(3, false);
        } else {
          // tail: wave w computes sub-blocks s < sdiag unmasked, s == sdiag masked.
#pragma unroll
          for (int s = 0; s < 4; ++s) {
            if (s < sdiag) SUBBLK(s, false);
            else if (s == sdiag) SUBBLK(s, true);
          }
        }
      }
      __syncthreads();
      cb ^= 1;
    }
#undef SUBBLK
#undef STAGE_KV

    l1 += __shfl_xor(l1, 16); l1 += __shfl_xor(l1, 32);
    const float inv1 = 1.0f / l1;
    const int bb = bh / NH, h = bh - bb * NH;
    const size_t trow1 = ((size_t)bb * SEQ + q1) * DM + (size_t)h * HD;
#pragma unroll
    for (int f = 0; f < 4; ++f) {
      short4v pk1;
#pragma unroll
      for (int r = 0; r < 4; ++r) pk1[r] = bfb(o1[f][r] * inv1);
      *(short4v*)&Cx[trow1 + f * 16 + 4 * g] = pk1;
    }
  }
}

// ---------------- output GEMM v3: 64x128 tile, BK=64, double-buffered (R19) ----------------
__global__ __launch_bounds__(256) void out_gemm(
    const __hip_bfloat16* __restrict__ Wo,
    const __hip_bfloat16* __restrict__ Cx,
    float* __restrict__ out)
{
  __shared__ __align__(16) __hip_bfloat16 As[2][64 * 64];    // 8KB each
  __shared__ __align__(16) __hip_bfloat16 Bs[2][128 * 64];   // 16KB each
  const int tid = threadIdx.x;
  const int lane = tid & 63, w = tid >> 6;
  const int c = lane & 15, g = lane >> 4;
  const int wr = w >> 1, wc = w & 1;
  const int bid = blockIdx.x;
  const int xcd = bid & 7, i_ = bid >> 3;        // 48 per XCD
  const int nb = xcd * 4 + (i_ & 3), mb = i_ >> 2;  // nb 0..31 (t), mb 0..11 (e)
  const int m0 = mb * 64, n0 = nb * 128;
  const int srow = tid >> 3, sslot = tid & 7;

#define OUT_STAGE(K0_, AD, BD)                                                      \
  do {                                                                              \
    _Pragma("unroll")                                                               \
    for (int j = 0; j < 2; ++j) {                                                   \
      const int row = j * 32 + srow;                                                \
      const int gs = (sslot ^ (row & 7)) * 8;                                       \
      gload_lds16(Wo + (size_t)(m0 + row) * DM + (K0_) + gs, (AD) + j * 2048 + w * 512); \
    }                                                                               \
    _Pragma("unroll")                                                               \
    for (int j = 0; j < 4; ++j) {                                                   \
      const int row = j * 32 + srow;                                                \
      const int gs = (sslot ^ (row & 7)) * 8;                                       \
      gload_lds16(Cx + (size_t)(n0 + row) * DM + (K0_) + gs, (BD) + j * 2048 + w * 512); \
    }                                                                               \
  } while (0)

  floatx4 acc[2][4] = {};
  OUT_STAGE(0, As[0], Bs[0]);
  int cb = 0;
  for (int k0 = 0; k0 < DM; k0 += 64) {
    if (k0 + 64 < DM) OUT_STAGE(k0 + 64, As[cb ^ 1], Bs[cb ^ 1]);
    __syncthreads();
#pragma unroll
    for (int kk = 0; kk < 2; ++kk) {
      short8v a[2], b[4];
#pragma unroll
      for (int i = 0; i < 2; ++i) {
        const int row = wr * 32 + i * 16 + c;
        a[i] = *(const short8v*)&As[cb][row * 64 + (((kk * 4 + g) ^ (row & 7)) * 8)];
      }
#pragma unroll
      for (int j = 0; j < 4; ++j) {
        const int row = wc * 64 + j * 16 + c;
        b[j] = *(const short8v*)&Bs[cb][row * 64 + (((kk * 4 + g) ^ (row & 7)) * 8)];
      }
#pragma unroll
      for (int i = 0; i < 2; ++i)
#pragma unroll
        for (int j = 0; j < 4; ++j)
          acc[i][j] = __builtin_amdgcn_mfma_f32_16x16x32_bf16(a[i], b[j], acc[i][j], 0, 0, 0);
    }
    __syncthreads();
    cb ^= 1;
  }
#undef OUT_STAGE
#pragma unroll
  for (int i = 0; i < 2; ++i) {
    const int e0 = m0 + wr * 32 + i * 16 + 4 * g;
#pragma unroll
    for (int j = 0; j < 4; ++j) {
      const int t = n0 + wc * 64 + j * 16 + c;
      *(floatx4*)&out[(size_t)t * DM + e0] = acc[i][j];
    }
  }
}

extern "C" void kernel_launch(void* const* d_in, const int* in_sizes, int n_in,
                              void* d_out, int out_size, void* d_ws, size_t ws_size,
                              hipStream_t stream) {
  const float* x    = (const float*)d_in[0];
  const int*   tpos = (const int*)d_in[1];
  const float* Wq   = (const float*)d_in[2];
  const float* Wo   = (const float*)d_in[3];
  float* out = (float*)d_out;

  const size_t QKV_BYTES = (size_t)NB * NH * SEQ * HD * 2;  // 6,291,456
  const size_t REQUIRED = 4 * QKV_BYTES;                    // 25,165,824
  if (ws_size < REQUIRED) return;

  char* ws = (char*)d_ws;
  __hip_bfloat16* Qb = (__hip_bfloat16*)(ws);
  __hip_bfloat16* Kb = (__hip_bfloat16*)(ws + QKV_BYTES);
  __hip_bfloat16* Vt = (__hip_bfloat16*)(ws + 2 * QKV_BYTES);
  __hip_bfloat16* Cx = (__hip_bfloat16*)(ws + 3 * QKV_BYTES);
  __hip_bfloat16* xb = (__hip_bfloat16*)(ws + 3 * QKV_BYTES);   // aliases Cx (dead before attn)
  char* ob = (char*)d_out;   // d_out-head scratch, all dead before out_gemm overwrites
  float2* rcs = (float2*)(ob);                                           // 512KB
  __hip_bfloat16* wqb = (__hip_bfloat16*)(ob + (size_t)SEQ * 32 * 8);    // 3.54MB
  __hip_bfloat16* wob = (__hip_bfloat16*)(ob + (size_t)SEQ * 32 * 8 + (size_t)E3 * DM * 2);  // 1.18MB
  int* qcnt = (int*)(ob + (size_t)SEQ * 32 * 8 + (size_t)E3 * DM * 2 + (size_t)DM * DM * 2); // 32B

  const int TOT_N = CVT_N + SEQ * 32;
  cvt3_rope<<<dim3((TOT_N + 255) / 256), dim3(256), 0, stream>>>(x, Wq, Wo, xb, wqb, wob, rcs, qcnt);
  qkv_gemm_rope<<<dim3(1152), dim3(256), 0, stream>>>(wqb, xb, tpos, rcs, Qb, Kb, Vt);
  attn_fused<<<dim3(512), dim3(512), 0, stream>>>(Qb, Kb, Vt, Cx, qcnt);
  out_gemm<<<dim3(384), dim3(256), 0, stream>>>(wob, Cx, out);
}